// Round 1
// baseline (1123.257 us; speedup 1.0000x reference)
//
#include <hip/hip_runtime.h>
#include <math.h>

// Problem constants: N=8, C=128, H=64, W=64, B=N*W=512, ADJ=33, G=8, GP=16
constexpr float EPSV = 1e-5f;

// ---------------- workspace layout (offsets in floats) ----------------
constexpr size_t F_W127  = 0;                      // 33*127 = 4191 (padded 4224)
constexpr size_t F_W64   = F_W127 + 4224;          // 33*64 = 2112
constexpr size_t F_QKVST = F_W64  + 2112;          // float2[256] -> 512 floats
constexpr size_t F_SIMST = F_QKVST+ 512;           // float2[192] -> 384
constexpr size_t F_SOST  = F_SIMST+ 384;           // float2[256] -> 512
constexpr size_t F_INST  = F_SOST + 512;           // float2[1024]-> 2048
constexpr size_t F_POSTMP= F_INST + 2048;          // 32*33*127 = 134112
constexpr size_t F_POS   = F_POSTMP + 134112;      // 32*33*33 = 34848
constexpr size_t F_QKV   = F_POS  + 34848;         // 512*256*64 = 8388608 (alias: SO)
constexpr size_t F_QKVR  = F_QKV  + 8388608;       // 512*256*33 = 4325376
constexpr size_t F_SIM   = F_QKVR + 4325376;       // 512*24*1089 = 13381632 (alias: XN, H1)
constexpr size_t F_SIMSUM= F_SIM  + 13381632;      // 512*8*1089 = 4460544
constexpr size_t F_VB    = F_SIMSUM + 4460544;     // 512*8*16*64 = 4194304
constexpr size_t F_VEH   = F_VB   + 4194304;       // 16*64*64 = 65536
constexpr size_t F_SO    = F_QKV;                  // qkv dead after k_qkvr
constexpr size_t F_XN    = F_SIM;                  // sim dead after k_simsum
constexpr size_t F_H1    = F_SIM + 4194304;        // 16777216 floats; spans dead sim/simsum/vb

// ---------------- resize weight tables (jax.image.resize, antialias=True) ----------------
__global__ void k_tables(float* __restrict__ W127, float* __restrict__ W64){
  int i = threadIdx.x;
  if (i < 33){
    const float inv = 127.0f/33.0f;          // kernel_scale for downsample (antialias)
    float x = ((float)i + 0.5f)*inv - 0.5f;  // half-pixel sample position
    float s = 0.f;
    for (int j=0;j<127;++j){ float w = 1.0f - fabsf((float)j - x)/inv; w = fmaxf(w,0.f); W127[i*127+j]=w; s+=w; }
    float r = 1.0f/s;
    for (int j=0;j<127;++j) W127[i*127+j] *= r;
  } else if (i < 66){
    int ii = i-33;
    const float inv = 64.0f/33.0f;
    float x = ((float)ii + 0.5f)*inv - 0.5f;
    float s=0.f;
    for (int j=0;j<64;++j){ float w = 1.0f - fabsf((float)j - x)/inv; w=fmaxf(w,0.f); W64[ii*64+j]=w; s+=w; }
    float r=1.0f/s;
    for (int j=0;j<64;++j) W64[ii*64+j]*=r;
  }
}

// up-sample 33->64: clamp + 2-tap lerp (matches jax normalized edge weights)
__device__ __forceinline__ void upfac(int o, int& j0, float& f){
  float x = ((float)o + 0.5f)*0.515625f - 0.5f;   // 33/64 = 0.515625 exact
  x = fminf(fmaxf(x, 0.f), 32.f);
  int j = (int)x; j = j < 31 ? j : 31;
  j0 = j; f = x - (float)j;
}

// ---------------- QKV projection: qkv[b,o,l] = sum_c w[o,c]*x[n,c,l,w], b=n*64+w ----------------
__global__ __launch_bounds__(256) void k_qkv(const float* __restrict__ x, const float* __restrict__ qkv_w,
                                             float* __restrict__ qkv){
  int b = blockIdx.x, o0 = blockIdx.y*64;
  int n = b>>6, w = b&63;
  __shared__ float lx[8192];   // x slice [128 c][64 l]
  __shared__ float lw[4096];   // w chunk transposed [64 c][64 o]
  int tid = threadIdx.x;
  for (int e=tid;e<8192;e+=256){ int c=e>>6, l=e&63; lx[e] = x[((n*128+c)*64+l)*64 + w]; }
  int l = tid&63, ow = tid>>6;
  float acc[16];
  #pragma unroll
  for (int i=0;i<16;++i) acc[i]=0.f;
  for (int half=0;half<2;++half){
    int c0 = half*64;
    __syncthreads();
    for (int e=tid;e<4096;e+=256){ int cc=e>>6, ol=e&63; lw[e] = qkv_w[(o0+ol)*128 + c0+cc]; }
    __syncthreads();
    for (int cc=0;cc<64;++cc){
      float xv = lx[(c0+cc)*64 + l];
      const float* wr = &lw[cc*64 + ow*16];
      #pragma unroll
      for (int i=0;i<16;++i) acc[i] += wr[i]*xv;
    }
  }
  #pragma unroll
  for (int i=0;i<16;++i) qkv[b*16384 + (o0 + ow*16 + i)*64 + l] = acc[i];
}

// ---------------- BN stats over [512][256][64], per channel (used for qkv and so) ----------------
__global__ __launch_bounds__(256) void k_bnstats(const float* __restrict__ src, const float* __restrict__ g,
                                                 const float* __restrict__ bta, float2* __restrict__ st){
  int ch = blockIdx.x, t = threadIdx.x;
  float s=0.f, s2=0.f;
  for (int e=t; e<512*64; e+=256){
    int r=e>>6, l=e&63;
    float v = src[(r*256+ch)*64 + l];
    s+=v; s2+=v*v;
  }
  __shared__ float rs[256], rq[256];
  rs[t]=s; rq[t]=s2; __syncthreads();
  for (int o=128;o>0;o>>=1){ if(t<o){ rs[t]+=rs[t+o]; rq[t]+=rq[t+o]; } __syncthreads(); }
  if (t==0){
    float m = rs[0]*(1.0f/32768.0f);
    float var = rq[0]*(1.0f/32768.0f) - m*m;
    float sc = g[ch]/sqrtf(var + EPSV);
    st[ch] = make_float2(sc, bta[ch] - m*sc);
  }
}

// ---------------- qkv: BN fold + resize 64->33 along l ----------------
__global__ void k_qkvr(const float* __restrict__ qkv, const float* __restrict__ W64,
                       const float2* __restrict__ st, float* __restrict__ qkvr){
  int id = blockIdx.x*256 + threadIdx.x;       // 512*256*33
  int b = id / 8448; int r = id - b*8448; int ch = r / 33; int i = r - ch*33;
  const float* row = qkv + (b*256 + ch)*64;
  const float* wr = W64 + i*64;
  float a=0.f;
  #pragma unroll 16
  for (int t=0;t<64;++t) a += wr[t]*row[t];
  float2 sb = st[ch];
  qkvr[id] = a*sb.x + sb.y;
}

// ---------------- pos = resize(base_relative, (32,33,33)) separable ----------------
__global__ void k_pos1(const float* __restrict__ base, const float* __restrict__ W127, float* __restrict__ tmp){
  int id = blockIdx.x*256 + threadIdx.x;
  if (id >= 32*33*127) return;
  int c = id / 4191; int r = id - c*4191; int i = r / 127; int xx = r - i*127;
  const float* wr = W127 + i*127;
  const float* bc = base + c*16129 + xx;
  float a=0.f;
  for (int y=0;y<127;++y) a += wr[y]*bc[y*127];
  tmp[id] = a;
}
__global__ void k_pos2(const float* __restrict__ tmp, const float* __restrict__ W127, float* __restrict__ pos){
  int id = blockIdx.x*256 + threadIdx.x;
  if (id >= 32*33*33) return;
  int c = id / 1089; int r = id - c*1089; int i = r / 33; int j = r - i*33;
  const float* wr = W127 + j*127;
  const float* tc = tmp + c*4191 + i*127;
  float a=0.f;
  for (int xx=0;xx<127;++xx) a += wr[xx]*tc[xx];
  pos[id] = a;
}

// ---------------- sim = concat([qk, qr, kr]) for each (b,g) ----------------
__global__ __launch_bounds__(256) void k_sim(const float* __restrict__ qkvr, const float* __restrict__ pos,
                                             float* __restrict__ sim){
  int b = blockIdx.x, g = blockIdx.y;
  __shared__ float lqa[264], lka[264];  // [8 c][33 i]
  int tid = threadIdx.x;
  for (int e=tid;e<528;e+=256){
    int half = (e < 264) ? 0 : 1;
    int e2 = e - half*264;
    int c = e2/33, i = e2 - c*33;
    float v = qkvr[(b*256 + g*32 + half*8 + c)*33 + i];
    if (half==0) lqa[e2]=v; else lka[e2]=v;
  }
  __syncthreads();
  for (int p=tid;p<1089;p+=256){
    int i = p/33, j = p - i*33;
    float qk=0.f, qr=0.f, kr=0.f;
    #pragma unroll
    for (int c=0;c<8;++c){
      float qa_ = lqa[c*33+i];
      float ka_ = lka[c*33+j];
      qk += qa_*ka_;
      qr += qa_*pos[c*1089 + i*33 + j];          // q_e = pos[0:8]
      kr += ka_*pos[(8+c)*1089 + j*33 + i];      // k_e = pos[8:16], transposed use
    }
    sim[(b*24 + g)*1089 + p] = qk;
    sim[(b*24 + 8 + g)*1089 + p] = qr;
    sim[(b*24 + 16 + g)*1089 + p] = kr;
  }
}

// ---------------- per-(n, ch24) stats over (W, i, j) ----------------
__global__ __launch_bounds__(256) void k_simstats(const float* __restrict__ sim, const float* __restrict__ g,
                                                  const float* __restrict__ bta, float2* __restrict__ st){
  int nb = blockIdx.x; int n = nb/24, ch = nb - n*24;
  int t = threadIdx.x;
  float s=0.f, s2=0.f;
  for (int e=t; e<64*1089; e+=256){
    int w = e/1089, p = e - w*1089;
    float v = sim[((n*64+w)*24 + ch)*1089 + p];
    s+=v; s2+=v*v;
  }
  __shared__ float rs[256], rq[256];
  rs[t]=s; rq[t]=s2; __syncthreads();
  for (int o=128;o>0;o>>=1){ if(t<o){ rs[t]+=rs[t+o]; rq[t]+=rq[t+o]; } __syncthreads(); }
  if (t==0){
    float m = rs[0]*(1.0f/69696.0f);
    float var = rq[0]*(1.0f/69696.0f) - m*m;
    float sc = g[ch]/sqrtf(var + EPSV);
    st[nb] = make_float2(sc, bta[ch] - m*sc);
  }
}

// ---------------- normalize + sum over the 3 groups ----------------
__global__ void k_simsum(const float* __restrict__ sim, const float2* __restrict__ st, float* __restrict__ ss){
  int id = blockIdx.x*256 + threadIdx.x;      // 512*8*1089
  int b = id / 8712; int r = id - b*8712; int g = r / 1089; int p = r - g*1089;
  int n = b>>6;
  float a = 0.f;
  #pragma unroll
  for (int t3=0;t3<3;++t3){
    float2 sb = st[n*24 + t3*8 + g];
    a += sim[(b*24 + t3*8 + g)*1089 + p]*sb.x + sb.y;
  }
  ss[id] = a;
}

// ---------------- vb: resize va (33) back to 64 along last dim ----------------
__global__ void k_vb(const float* __restrict__ qkvr, float* __restrict__ vb){
  int id = blockIdx.x*256 + threadIdx.x;      // (b*8+g)*16+c)*64 + j
  int j = id & 63; int r = id >> 6;
  int b = r >> 7; int rem = r & 127; int g = rem >> 4; int c = rem & 15;
  const float* row = qkvr + (b*256 + g*32 + 16 + c)*33;
  int j0; float f; upfac(j, j0, f);
  vb[id] = (1.f-f)*row[j0] + f*row[j0+1];
}

// ---------------- v_eH: resize v_e (16,33,33) -> (16,64,64) ----------------
__global__ void k_veH(const float* __restrict__ pos, float* __restrict__ veH){
  int id = blockIdx.x*256 + threadIdx.x;  // 16*64*64
  int j = id&63, i=(id>>6)&63, c=id>>12;
  int i0, j0; float fi, fj;
  upfac(i, i0, fi); upfac(j, j0, fj);
  const float* P = pos + (16+c)*1089;
  float v0 = (1.f-fj)*P[i0*33+j0]     + fj*P[i0*33+j0+1];
  float v1 = (1.f-fj)*P[(i0+1)*33+j0] + fj*P[(i0+1)*33+j0+1];
  veH[id] = (1.f-fi)*v0 + fi*v1;
}

// ---------------- fused: upsample sim 33->64 (2D), softmax, sv & sve -> so ----------------
__global__ __launch_bounds__(64) void k_attn(const float* __restrict__ ss, const float* __restrict__ vb,
                                             const float* __restrict__ veH, float* __restrict__ so){
  int bg = blockIdx.x; int b = bg>>3; int g = bg&7;
  __shared__ float S[1089];     // simsum tile 33x33
  __shared__ float lv[1024];    // vb tile [16 c][64 j]
  __shared__ float pm[64*65];   // softmax rows, padded stride 65
  int tid = threadIdx.x;
  for (int e=tid;e<1089;e+=64) S[e] = ss[bg*1089 + e];
  for (int e=tid;e<1024;e+=64) lv[e] = vb[bg*1024 + e];
  __syncthreads();
  int i = tid;
  int i0; float fi; upfac(i, i0, fi);
  const float* R0 = S + i0*33;
  const float* R1 = S + (i0+1)*33;
  float mx = -1e30f;
  for (int j=0;j<64;++j){
    int j0; float fj; upfac(j, j0, fj);
    float v0 = (1.f-fj)*R0[j0] + fj*R0[j0+1];
    float v1 = (1.f-fj)*R1[j0] + fj*R1[j0+1];
    float su = (1.f-fi)*v0 + fi*v1;
    pm[i*65+j] = su;
    mx = fmaxf(mx, su);
  }
  float s = 0.f;
  for (int j=0;j<64;++j){ float e = expf(pm[i*65+j]-mx); pm[i*65+j]=e; s+=e; }
  float inv = 1.f/s;
  float* ob = so + b*16384 + g*2048;   // channel 2*(g*16+c) lives at offset (g*16+c)*128
  for (int c=0;c<16;++c){
    float a=0.f;
    const float* vr = lv + c*64;
    #pragma unroll 8
    for (int j=0;j<64;++j) a += pm[i*65+j]*vr[j];
    ob[c*128 + i] = a*inv;             // sv -> even channel
  }
  for (int c=0;c<16;++c){
    const float* er = veH + (c*64 + i)*64;
    float a=0.f;
    #pragma unroll 8
    for (int j=0;j<64;++j) a += pm[i*65+j]*er[j];
    ob[c*128 + 64 + i] = a*inv;        // sve -> odd channel
  }
}

// ---------------- BN(so) + pair-sum + transpose -> o in (N,C,H,W) ----------------
__global__ void k_o(const float* __restrict__ so, const float2* __restrict__ st, float* __restrict__ o){
  int id = blockIdx.x*256 + threadIdx.x;  // ((n*128+oc)*64+h)*64+w
  int w = id&63, h=(id>>6)&63, oc=(id>>12)&127, n=id>>19;
  int b = n*64 + w;
  float2 s0 = st[2*oc], s1 = st[2*oc+1];
  float v0 = so[b*16384 + (2*oc)*64 + h];
  float v1 = so[b*16384 + (2*oc+1)*64 + h];
  o[id] = v0*s0.x + s0.y + v1*s1.x + s1.y;
}

// ---------------- spatial block: shifted-channel construction ----------------
__device__ __forceinline__ float xo_val(const float* __restrict__ o, int n, int c, int h, int w){
  if (c >= 40) return o[((n*128 + c)*64 + h)*64 + w];
  int grp = c / 10;
  int cc = c - grp*10;
  int base = (n*128 + cc)*64;
  if (grp==0) return (w>=2) ? o[(base + h)*64 + (w-2)] : 0.f;      // r
  if (grp==1) return (w<62) ? o[(base + h)*64 + (w+2)] : 0.f;      // l
  if (grp==2) return (h>=2) ? o[(base + (h-2))*64 + w] : 0.f;      // d
  return (h<62) ? o[(base + (h+2))*64 + w] : 0.f;                  // u
}

__global__ __launch_bounds__(256) void k_instats(const float* __restrict__ o, const float* __restrict__ g,
                                                 const float* __restrict__ bta, float2* __restrict__ st){
  int nb = blockIdx.x; int n = nb>>7, c = nb&127;
  int t = threadIdx.x;
  float s=0.f,s2=0.f;
  for (int e=t;e<4096;e+=256){
    int h=e>>6, w=e&63;
    float v = xo_val(o,n,c,h,w);
    s+=v; s2+=v*v;
  }
  __shared__ float rs[256], rq[256];
  rs[t]=s; rq[t]=s2; __syncthreads();
  for (int oo=128;oo>0;oo>>=1){ if(t<oo){ rs[t]+=rs[t+oo]; rq[t]+=rq[t+oo]; } __syncthreads(); }
  if (t==0){
    float m = rs[0]*(1.0f/4096.0f);
    float var = rq[0]*(1.0f/4096.0f) - m*m;
    float sc = g[c]/sqrtf(var + EPSV);
    st[nb] = make_float2(sc, bta[c] - m*sc);
  }
}

__global__ void k_xn(const float* __restrict__ o, const float2* __restrict__ st, float* __restrict__ xn){
  int id = blockIdx.x*256+threadIdx.x;
  int w=id&63,h=(id>>6)&63,c=(id>>12)&127,n=id>>19;
  float2 sb = st[n*128+c];
  xn[id] = xo_val(o,n,c,h,w)*sb.x + sb.y;
}

// ---------------- MLP layer 1: h1 = gelu(W1 (512x128) @ xn), per n ----------------
__global__ __launch_bounds__(256) void k_mlp1(const float* __restrict__ xn, const float* __restrict__ w1,
                                              float* __restrict__ h1){
  int hw0 = blockIdx.x*64, ct = blockIdx.y, n = blockIdx.z;
  int tid = threadIdx.x, hwl = tid&63, cw = tid>>6;
  __shared__ float lx[1024];   // [16 k][64 hw]
  __shared__ float lw[2048];   // [16 k][128 c_out]
  float acc[32];
  #pragma unroll
  for (int i=0;i<32;++i) acc[i]=0.f;
  for (int c0=0;c0<128;c0+=16){
    __syncthreads();
    for (int e=tid;e<1024;e+=256){ int kk=e>>6, hh=e&63; lx[e] = xn[(n*128 + c0+kk)*4096 + hw0+hh]; }
    for (int e=tid;e<2048;e+=256){ int kk=e>>7, ccx=e&127; lw[kk*128+ccx] = w1[(ct*128+ccx)*128 + c0+kk]; }
    __syncthreads();
    for (int kk=0;kk<16;++kk){
      float xv = lx[kk*64 + hwl];
      const float* wr = &lw[kk*128 + cw*32];
      #pragma unroll
      for (int i=0;i<32;++i) acc[i] += wr[i]*xv;
    }
  }
  #pragma unroll
  for (int i=0;i<32;++i){
    int o = ct*128 + cw*32 + i;
    float v = acc[i];
    v = 0.5f*v*(1.0f + erff(v*0.70710678118654752440f));  // exact gelu
    h1[(n*512 + o)*4096 + hw0 + hwl] = v;
  }
}

// ---------------- MLP layer 2 + residual (o lives in d_out) ----------------
__global__ __launch_bounds__(256) void k_mlp2(const float* __restrict__ h1, const float* __restrict__ w2,
                                              float* __restrict__ out){
  int hw0 = blockIdx.x*64, n = blockIdx.y;
  int tid=threadIdx.x, hwl=tid&63, cw=tid>>6;
  __shared__ float lh[1024];   // [16 k][64 hw]
  __shared__ float lw[2048];   // [16 k][128 c_out]
  float acc[32];
  #pragma unroll
  for (int i=0;i<32;++i) acc[i]=0.f;
  for (int k0=0;k0<512;k0+=16){
    __syncthreads();
    for (int e=tid;e<1024;e+=256){ int kk=e>>6,hh=e&63; lh[e]=h1[(n*512 + k0+kk)*4096 + hw0+hh]; }
    for (int e=tid;e<2048;e+=256){ int kk=e>>7, ccx=e&127; lw[kk*128+ccx] = w2[ccx*512 + k0+kk]; }
    __syncthreads();
    for (int kk=0;kk<16;++kk){
      float hv = lh[kk*64+hwl];
      const float* wr = &lw[kk*128 + cw*32];
      #pragma unroll
      for (int i=0;i<32;++i) acc[i] += wr[i]*hv;
    }
  }
  #pragma unroll
  for (int i=0;i<32;++i){
    int c = cw*32+i;
    int idx = (n*128+c)*4096 + hw0+hwl;
    out[idx] = acc[i] + out[idx];    // residual: same-thread read-then-write
  }
}

extern "C" void kernel_launch(void* const* d_in, const int* in_sizes, int n_in,
                              void* d_out, int out_size, void* d_ws, size_t ws_size,
                              hipStream_t stream) {
  (void)in_sizes; (void)n_in; (void)out_size; (void)ws_size;
  const float* x       = (const float*)d_in[0];
  const float* qkvw    = (const float*)d_in[1];
  const float* bng     = (const float*)d_in[2];
  const float* bnb     = (const float*)d_in[3];
  const float* baserel = (const float*)d_in[4];
  const float* simg    = (const float*)d_in[5];
  const float* simb    = (const float*)d_in[6];
  const float* outg    = (const float*)d_in[7];
  const float* outb    = (const float*)d_in[8];
  const float* ing     = (const float*)d_in[9];
  const float* inb     = (const float*)d_in[10];
  const float* w1      = (const float*)d_in[11];
  const float* w2      = (const float*)d_in[12];

  float* ws = (float*)d_ws;
  float*  W127  = ws + F_W127;
  float*  W64   = ws + F_W64;
  float2* qkvst = (float2*)(ws + F_QKVST);
  float2* simst = (float2*)(ws + F_SIMST);
  float2* sost  = (float2*)(ws + F_SOST);
  float2* inst  = (float2*)(ws + F_INST);
  float*  postmp= ws + F_POSTMP;
  float*  pos   = ws + F_POS;
  float*  qkv   = ws + F_QKV;
  float*  qkvr  = ws + F_QKVR;
  float*  sim   = ws + F_SIM;
  float*  ssum  = ws + F_SIMSUM;
  float*  vb    = ws + F_VB;
  float*  veH   = ws + F_VEH;
  float*  so    = ws + F_SO;     // aliases qkv (dead)
  float*  xn    = ws + F_XN;     // aliases sim (dead)
  float*  h1    = ws + F_H1;     // aliases sim tail + simsum + vb (dead)
  float*  out   = (float*)d_out;

  k_tables  <<<dim3(1),        dim3(128), 0, stream>>>(W127, W64);
  k_qkv     <<<dim3(512,4),    dim3(256), 0, stream>>>(x, qkvw, qkv);
  k_bnstats <<<dim3(256),      dim3(256), 0, stream>>>(qkv, bng, bnb, qkvst);
  k_qkvr    <<<dim3(16896),    dim3(256), 0, stream>>>(qkv, W64, qkvst, qkvr);
  k_pos1    <<<dim3(524),      dim3(256), 0, stream>>>(baserel, W127, postmp);
  k_pos2    <<<dim3(137),      dim3(256), 0, stream>>>(postmp, W127, pos);
  k_sim     <<<dim3(512,8),    dim3(256), 0, stream>>>(qkvr, pos, sim);
  k_simstats<<<dim3(192),      dim3(256), 0, stream>>>(sim, simg, simb, simst);
  k_simsum  <<<dim3(17424),    dim3(256), 0, stream>>>(sim, simst, ssum);
  k_vb      <<<dim3(16384),    dim3(256), 0, stream>>>(qkvr, vb);
  k_veH     <<<dim3(256),      dim3(256), 0, stream>>>(pos, veH);
  k_attn    <<<dim3(4096),     dim3(64),  0, stream>>>(ssum, vb, veH, so);
  k_bnstats <<<dim3(256),      dim3(256), 0, stream>>>(so, outg, outb, sost);
  k_o       <<<dim3(16384),    dim3(256), 0, stream>>>(so, sost, out);
  k_instats <<<dim3(1024),     dim3(256), 0, stream>>>(out, ing, inb, inst);
  k_xn      <<<dim3(16384),    dim3(256), 0, stream>>>(out, inst, xn);
  k_mlp1    <<<dim3(64,4,8),   dim3(256), 0, stream>>>(xn, w1, h1);
  k_mlp2    <<<dim3(64,8),     dim3(256), 0, stream>>>(h1, w2, out);
}

// Round 3
// 1067.766 us; speedup vs baseline: 1.0520x; 1.0520x over previous
//
#include <hip/hip_runtime.h>
#include <math.h>

// Problem constants: N=8, C=128, H=64, W=64, B=N*W=512, ADJ=33, G=8, GP=16
constexpr float EPSV = 1e-5f;

// ---------------- workspace layout (offsets in floats) ----------------
constexpr size_t F_W127  = 0;                      // 33*127 = 4191 (padded 4224)
constexpr size_t F_W64   = F_W127 + 4224;          // 33*64 = 2112
constexpr size_t F_QKVST = F_W64  + 2112;          // float2[256] -> 512 floats
constexpr size_t F_SIMST = F_QKVST+ 512;           // float2[192] -> 384
constexpr size_t F_SOST  = F_SIMST+ 384;           // float2[256] -> 512
constexpr size_t F_INST  = F_SOST + 512;           // float2[1024]-> 2048
constexpr size_t F_POSTMP= F_INST + 2048;          // 32*33*127 = 134112
constexpr size_t F_POS   = F_POSTMP + 134112;      // 32*33*33 = 34848
constexpr size_t F_QKV   = F_POS  + 34848;         // 512*256*64 = 8388608 (alias: SO)
constexpr size_t F_QKVR  = F_QKV  + 8388608;       // 512*256*33 = 4325376
constexpr size_t F_SIM   = F_QKVR + 4325376;       // 512*24*1089 = 13381632 (alias: XN, H1)
constexpr size_t F_SIMSUM= F_SIM  + 13381632;      // 512*8*1089 = 4460544
constexpr size_t F_VB    = F_SIMSUM + 4460544;     // 512*8*16*64 = 4194304 (16B-aligned base)
constexpr size_t F_VEH   = F_VB   + 4194304;       // 16*64*64 = 65536 (16B-aligned base)
constexpr size_t F_SO    = F_QKV;                  // qkv dead after k_qkvr
constexpr size_t F_XN    = F_SIM;                  // sim dead after k_simsum
constexpr size_t F_H1    = F_SIM + 4194304;        // 16777216 floats; spans dead sim/simsum/vb

// ---------------- resize weight tables (jax.image.resize, antialias=True) ----------------
__global__ void k_tables(float* __restrict__ W127, float* __restrict__ W64){
  int i = threadIdx.x;
  if (i < 33){
    const float inv = 127.0f/33.0f;          // kernel_scale for downsample (antialias)
    float x = ((float)i + 0.5f)*inv - 0.5f;  // half-pixel sample position
    float s = 0.f;
    for (int j=0;j<127;++j){ float w = 1.0f - fabsf((float)j - x)/inv; w = fmaxf(w,0.f); W127[i*127+j]=w; s+=w; }
    float r = 1.0f/s;
    for (int j=0;j<127;++j) W127[i*127+j] *= r;
  } else if (i < 66){
    int ii = i-33;
    const float inv = 64.0f/33.0f;
    float x = ((float)ii + 0.5f)*inv - 0.5f;
    float s=0.f;
    for (int j=0;j<64;++j){ float w = 1.0f - fabsf((float)j - x)/inv; w=fmaxf(w,0.f); W64[ii*64+j]=w; s+=w; }
    float r=1.0f/s;
    for (int j=0;j<64;++j) W64[ii*64+j]*=r;
  }
}

// up-sample 33->64: clamp + 2-tap lerp (matches jax normalized edge weights)
__device__ __forceinline__ void upfac(int o, int& j0, float& f){
  float x = ((float)o + 0.5f)*0.515625f - 0.5f;   // 33/64 = 0.515625 exact
  x = fminf(fmaxf(x, 0.f), 32.f);
  int j = (int)x; j = j < 31 ? j : 31;
  j0 = j; f = x - (float)j;
}

// ---------------- QKV projection: qkv[b,o,l] = sum_c w[o,c]*x[n,c,l,w], b=n*64+w ----------------
__global__ __launch_bounds__(256) void k_qkv(const float* __restrict__ x, const float* __restrict__ qkv_w,
                                             float* __restrict__ qkv){
  int b = blockIdx.x, o0 = blockIdx.y*64;
  int n = b>>6, w = b&63;
  __shared__ float lx[8192];   // x slice [128 c][64 l]
  __shared__ float lw[4096];   // w chunk transposed [64 c][64 o]
  int tid = threadIdx.x;
  for (int e=tid;e<8192;e+=256){ int c=e>>6, l=e&63; lx[e] = x[((n*128+c)*64+l)*64 + w]; }
  int l = tid&63, ow = tid>>6;
  float acc[16];
  #pragma unroll
  for (int i=0;i<16;++i) acc[i]=0.f;
  for (int half=0;half<2;++half){
    int c0 = half*64;
    __syncthreads();
    for (int e=tid;e<4096;e+=256){ int cc=e>>6, ol=e&63; lw[e] = qkv_w[(o0+ol)*128 + c0+cc]; }
    __syncthreads();
    for (int cc=0;cc<64;++cc){
      float xv = lx[(c0+cc)*64 + l];
      const float* wr = &lw[cc*64 + ow*16];
      #pragma unroll
      for (int i=0;i<16;++i) acc[i] += wr[i]*xv;
    }
  }
  #pragma unroll
  for (int i=0;i<16;++i) qkv[b*16384 + (o0 + ow*16 + i)*64 + l] = acc[i];
}

// ---------------- BN stats over [512][256][64], per channel (used for qkv and so) ----------------
__global__ __launch_bounds__(256) void k_bnstats(const float* __restrict__ src, const float* __restrict__ g,
                                                 const float* __restrict__ bta, float2* __restrict__ st){
  int ch = blockIdx.x, t = threadIdx.x;
  float s=0.f, s2=0.f;
  for (int e=t; e<512*64; e+=256){
    int r=e>>6, l=e&63;
    float v = src[(r*256+ch)*64 + l];
    s+=v; s2+=v*v;
  }
  __shared__ float rs[256], rq[256];
  rs[t]=s; rq[t]=s2; __syncthreads();
  for (int o=128;o>0;o>>=1){ if(t<o){ rs[t]+=rs[t+o]; rq[t]+=rq[t+o]; } __syncthreads(); }
  if (t==0){
    float m = rs[0]*(1.0f/32768.0f);
    float var = rq[0]*(1.0f/32768.0f) - m*m;
    float sc = g[ch]/sqrtf(var + EPSV);
    st[ch] = make_float2(sc, bta[ch] - m*sc);
  }
}

// ---------------- qkv: BN fold + resize 64->33 along l ----------------
__global__ void k_qkvr(const float* __restrict__ qkv, const float* __restrict__ W64,
                       const float2* __restrict__ st, float* __restrict__ qkvr){
  int id = blockIdx.x*256 + threadIdx.x;       // 512*256*33
  int b = id / 8448; int r = id - b*8448; int ch = r / 33; int i = r - ch*33;
  const float* row = qkv + (b*256 + ch)*64;
  const float* wr = W64 + i*64;
  float a=0.f;
  #pragma unroll 16
  for (int t=0;t<64;++t) a += wr[t]*row[t];
  float2 sb = st[ch];
  qkvr[id] = a*sb.x + sb.y;
}

// ---------------- pos = resize(base_relative, (32,33,33)) separable ----------------
__global__ void k_pos1(const float* __restrict__ base, const float* __restrict__ W127, float* __restrict__ tmp){
  int id = blockIdx.x*256 + threadIdx.x;
  if (id >= 32*33*127) return;
  int c = id / 4191; int r = id - c*4191; int i = r / 127; int xx = r - i*127;
  const float* wr = W127 + i*127;
  const float* bc = base + c*16129 + xx;
  float a=0.f;
  for (int y=0;y<127;++y) a += wr[y]*bc[y*127];
  tmp[id] = a;
}
__global__ void k_pos2(const float* __restrict__ tmp, const float* __restrict__ W127, float* __restrict__ pos){
  int id = blockIdx.x*256 + threadIdx.x;
  if (id >= 32*33*33) return;
  int c = id / 1089; int r = id - c*1089; int i = r / 33; int j = r - i*33;
  const float* wr = W127 + j*127;
  const float* tc = tmp + c*4191 + i*127;
  float a=0.f;
  for (int xx=0;xx<127;++xx) a += wr[xx]*tc[xx];
  pos[id] = a;
}

// ---------------- sim = concat([qk, qr, kr]) for each (b,g) ----------------
__global__ __launch_bounds__(256) void k_sim(const float* __restrict__ qkvr, const float* __restrict__ pos,
                                             float* __restrict__ sim){
  int b = blockIdx.x, g = blockIdx.y;
  __shared__ float lqa[264], lka[264];  // [8 c][33 i]
  int tid = threadIdx.x;
  for (int e=tid;e<528;e+=256){
    int half = (e < 264) ? 0 : 1;
    int e2 = e - half*264;
    int c = e2/33, i = e2 - c*33;
    float v = qkvr[(b*256 + g*32 + half*8 + c)*33 + i];
    if (half==0) lqa[e2]=v; else lka[e2]=v;
  }
  __syncthreads();
  for (int p=tid;p<1089;p+=256){
    int i = p/33, j = p - i*33;
    float qk=0.f, qr=0.f, kr=0.f;
    #pragma unroll
    for (int c=0;c<8;++c){
      float qa_ = lqa[c*33+i];
      float ka_ = lka[c*33+j];
      qk += qa_*ka_;
      qr += qa_*pos[c*1089 + i*33 + j];          // q_e = pos[0:8]
      kr += ka_*pos[(8+c)*1089 + j*33 + i];      // k_e = pos[8:16], transposed use
    }
    sim[(b*24 + g)*1089 + p] = qk;
    sim[(b*24 + 8 + g)*1089 + p] = qr;
    sim[(b*24 + 16 + g)*1089 + p] = kr;
  }
}

// ---------------- per-(n, ch24) stats over (W, i, j) ----------------
__global__ __launch_bounds__(256) void k_simstats(const float* __restrict__ sim, const float* __restrict__ g,
                                                  const float* __restrict__ bta, float2* __restrict__ st){
  int nb = blockIdx.x; int n = nb/24, ch = nb - n*24;
  int t = threadIdx.x;
  float s=0.f, s2=0.f;
  for (int e=t; e<64*1089; e+=256){
    int w = e/1089, p = e - w*1089;
    float v = sim[((n*64+w)*24 + ch)*1089 + p];
    s+=v; s2+=v*v;
  }
  __shared__ float rs[256], rq[256];
  rs[t]=s; rq[t]=s2; __syncthreads();
  for (int o=128;o>0;o>>=1){ if(t<o){ rs[t]+=rs[t+o]; rq[t]+=rq[t+o]; } __syncthreads(); }
  if (t==0){
    float m = rs[0]*(1.0f/69696.0f);
    float var = rq[0]*(1.0f/69696.0f) - m*m;
    float sc = g[ch]/sqrtf(var + EPSV);
    st[nb] = make_float2(sc, bta[ch] - m*sc);
  }
}

// ---------------- normalize + sum over the 3 groups ----------------
__global__ void k_simsum(const float* __restrict__ sim, const float2* __restrict__ st, float* __restrict__ ss){
  int id = blockIdx.x*256 + threadIdx.x;      // 512*8*1089
  int b = id / 8712; int r = id - b*8712; int g = r / 1089; int p = r - g*1089;
  int n = b>>6;
  float a = 0.f;
  #pragma unroll
  for (int t3=0;t3<3;++t3){
    float2 sb = st[n*24 + t3*8 + g];
    a += sim[(b*24 + t3*8 + g)*1089 + p]*sb.x + sb.y;
  }
  ss[id] = a;
}

// ---------------- vb: resize va (33) back to 64 along last dim ----------------
__global__ void k_vb(const float* __restrict__ qkvr, float* __restrict__ vb){
  int id = blockIdx.x*256 + threadIdx.x;      // (b*8+g)*16+c)*64 + j
  int j = id & 63; int r = id >> 6;
  int b = r >> 7; int rem = r & 127; int g = rem >> 4; int c = rem & 15;
  const float* row = qkvr + (b*256 + g*32 + 16 + c)*33;
  int j0; float f; upfac(j, j0, f);
  vb[id] = (1.f-f)*row[j0] + f*row[j0+1];
}

// ---------------- v_eH: resize v_e (16,33,33) -> (16,64,64) ----------------
__global__ void k_veH(const float* __restrict__ pos, float* __restrict__ veH){
  int id = blockIdx.x*256 + threadIdx.x;  // 16*64*64
  int j = id&63, i=(id>>6)&63, c=id>>12;
  int i0, j0; float fi, fj;
  upfac(i, i0, fi); upfac(j, j0, fj);
  const float* P = pos + (16+c)*1089;
  float v0 = (1.f-fj)*P[i0*33+j0]     + fj*P[i0*33+j0+1];
  float v1 = (1.f-fj)*P[(i0+1)*33+j0] + fj*P[(i0+1)*33+j0+1];
  veH[id] = (1.f-fi)*v0 + fi*v1;
}

// ---------------- fused: upsample sim 33->64 (2D), softmax, sv & sve -> so ----------------
// 4 waves/block; each wave independently handles one (b,g). Softmax probabilities in
// registers (p[64]). vb tile held in a NATIVELY-TYPED float4 LDS array (alignment
// guaranteed by type -- no reinterpret casts on LDS). veH read as float4 from the
// 16B-aligned buffer base. LDS/block = 33.9KB -> 4 blocks = 16 waves/CU.
__global__ __launch_bounds__(256) void k_attn(const float* __restrict__ ss, const float* __restrict__ vb,
                                              const float* __restrict__ veH, float* __restrict__ so){
  int wv = threadIdx.x >> 6;
  int i  = threadIdx.x & 63;
  int bg = blockIdx.x*4 + wv;
  int b = bg>>3, g = bg&7;
  __shared__ float  S[4][1092];   // 33x33 simsum tile per wave
  __shared__ float4 V[4][256];    // [16 c][16 q4] vb tile per wave, natively float4
  float* Sw = S[wv];
  const float4* vb4 = (const float4*)(vb + (size_t)bg*1024);   // bg*4096B from 16B-aligned base
  for (int e=i;e<1089;e+=64) Sw[e] = ss[(size_t)bg*1089 + e];
  for (int e=i;e<256;e+=64)  V[wv][e] = vb4[e];
  __syncthreads();

  // phase A: bilinear upsample row i (33->64 both dims) + softmax, in registers
  int i0; float fi; upfac(i, i0, fi);
  const float* R0 = Sw + i0*33;
  const float* R1 = R0 + 33;
  float p[64];
  float mx = -1e30f;
  #pragma unroll
  for (int j=0;j<64;++j){
    int j0; float fj; upfac(j, j0, fj);       // j constant after unroll
    float v0 = (1.f-fj)*R0[j0] + fj*R0[j0+1];
    float v1 = (1.f-fj)*R1[j0] + fj*R1[j0+1];
    float su = (1.f-fi)*v0 + fi*v1;
    p[j] = su;
    mx = fmaxf(mx, su);
  }
  float s = 0.f;
  #pragma unroll
  for (int j=0;j<64;++j){ float e = expf(p[j]-mx); p[j]=e; s+=e; }
  float inv = 1.f/s;

  // phase B: sv (LDS float4 broadcast) and sve (global float4, L2-hit)
  float* ob = so + (size_t)b*16384 + g*2048;   // channel 2*(g*16+c) at offset (g*16+c)*128
  const float4* lv4 = &V[wv][0];
  for (int c=0;c<16;++c){
    float a=0.f;
    #pragma unroll
    for (int q=0;q<16;++q){
      float4 v4 = lv4[c*16+q];
      a += p[4*q]*v4.x + p[4*q+1]*v4.y + p[4*q+2]*v4.z + p[4*q+3]*v4.w;
    }
    ob[c*128 + i] = a*inv;             // sv -> even channel
  }
  const float4* veH4 = (const float4*)veH;     // buffer base is 16B-aligned
  for (int c=0;c<16;++c){
    float a=0.f;
    #pragma unroll
    for (int q=0;q<16;++q){
      float4 v4 = veH4[(c*64 + i)*16 + q];
      a += p[4*q]*v4.x + p[4*q+1]*v4.y + p[4*q+2]*v4.z + p[4*q+3]*v4.w;
    }
    ob[c*128 + 64 + i] = a*inv;        // sve -> odd channel
  }
}

// ---------------- BN(so) + pair-sum + transpose -> o in (N,C,H,W) ----------------
__global__ void k_o(const float* __restrict__ so, const float2* __restrict__ st, float* __restrict__ o){
  int id = blockIdx.x*256 + threadIdx.x;  // ((n*128+oc)*64+h)*64+w
  int w = id&63, h=(id>>6)&63, oc=(id>>12)&127, n=id>>19;
  int b = n*64 + w;
  float2 s0 = st[2*oc], s1 = st[2*oc+1];
  float v0 = so[b*16384 + (2*oc)*64 + h];
  float v1 = so[b*16384 + (2*oc+1)*64 + h];
  o[id] = v0*s0.x + s0.y + v1*s1.x + s1.y;
}

// ---------------- spatial block: shifted-channel construction ----------------
__device__ __forceinline__ float xo_val(const float* __restrict__ o, int n, int c, int h, int w){
  if (c >= 40) return o[((n*128 + c)*64 + h)*64 + w];
  int grp = c / 10;
  int cc = c - grp*10;
  int base = (n*128 + cc)*64;
  if (grp==0) return (w>=2) ? o[(base + h)*64 + (w-2)] : 0.f;      // r
  if (grp==1) return (w<62) ? o[(base + h)*64 + (w+2)] : 0.f;      // l
  if (grp==2) return (h>=2) ? o[(base + (h-2))*64 + w] : 0.f;      // d
  return (h<62) ? o[(base + (h+2))*64 + w] : 0.f;                  // u
}

__global__ __launch_bounds__(256) void k_instats(const float* __restrict__ o, const float* __restrict__ g,
                                                 const float* __restrict__ bta, float2* __restrict__ st){
  int nb = blockIdx.x; int n = nb>>7, c = nb&127;
  int t = threadIdx.x;
  float s=0.f,s2=0.f;
  for (int e=t;e<4096;e+=256){
    int h=e>>6, w=e&63;
    float v = xo_val(o,n,c,h,w);
    s+=v; s2+=v*v;
  }
  __shared__ float rs[256], rq[256];
  rs[t]=s; rq[t]=s2; __syncthreads();
  for (int oo=128;oo>0;oo>>=1){ if(t<oo){ rs[t]+=rs[t+oo]; rq[t]+=rq[t+oo]; } __syncthreads(); }
  if (t==0){
    float m = rs[0]*(1.0f/4096.0f);
    float var = rq[0]*(1.0f/4096.0f) - m*m;
    float sc = g[c]/sqrtf(var + EPSV);
    st[nb] = make_float2(sc, bta[c] - m*sc);
  }
}

__global__ void k_xn(const float* __restrict__ o, const float2* __restrict__ st, float* __restrict__ xn){
  int id = blockIdx.x*256+threadIdx.x;
  int w=id&63,h=(id>>6)&63,c=(id>>12)&127,n=id>>19;
  float2 sb = st[n*128+c];
  xn[id] = xo_val(o,n,c,h,w)*sb.x + sb.y;
}

// ---------------- MLP layer 1: h1 = gelu(W1 (512x128) @ xn), per n ----------------
__global__ __launch_bounds__(256) void k_mlp1(const float* __restrict__ xn, const float* __restrict__ w1,
                                              float* __restrict__ h1){
  int hw0 = blockIdx.x*64, ct = blockIdx.y, n = blockIdx.z;
  int tid = threadIdx.x, hwl = tid&63, cw = tid>>6;
  __shared__ float lx[1024];   // [16 k][64 hw]
  __shared__ float lw[2048];   // [16 k][128 c_out]
  float acc[32];
  #pragma unroll
  for (int i=0;i<32;++i) acc[i]=0.f;
  for (int c0=0;c0<128;c0+=16){
    __syncthreads();
    for (int e=tid;e<1024;e+=256){ int kk=e>>6, hh=e&63; lx[e] = xn[(n*128 + c0+kk)*4096 + hw0+hh]; }
    for (int e=tid;e<2048;e+=256){ int kk=e>>7, ccx=e&127; lw[kk*128+ccx] = w1[(ct*128+ccx)*128 + c0+kk]; }
    __syncthreads();
    for (int kk=0;kk<16;++kk){
      float xv = lx[kk*64 + hwl];
      const float* wr = &lw[kk*128 + cw*32];
      #pragma unroll
      for (int i=0;i<32;++i) acc[i] += wr[i]*xv;
    }
  }
  #pragma unroll
  for (int i=0;i<32;++i){
    int o = ct*128 + cw*32 + i;
    float v = acc[i];
    v = 0.5f*v*(1.0f + erff(v*0.70710678118654752440f));  // exact gelu
    h1[(n*512 + o)*4096 + hw0 + hwl] = v;
  }
}

// ---------------- MLP layer 2 + residual (o lives in d_out) ----------------
__global__ __launch_bounds__(256) void k_mlp2(const float* __restrict__ h1, const float* __restrict__ w2,
                                              float* __restrict__ out){
  int hw0 = blockIdx.x*64, n = blockIdx.y;
  int tid=threadIdx.x, hwl=tid&63, cw=tid>>6;
  __shared__ float lh[1024];   // [16 k][64 hw]
  __shared__ float lw[2048];   // [16 k][128 c_out]
  float acc[32];
  #pragma unroll
  for (int i=0;i<32;++i) acc[i]=0.f;
  for (int k0=0;k0<512;k0+=16){
    __syncthreads();
    for (int e=tid;e<1024;e+=256){ int kk=e>>6,hh=e&63; lh[e]=h1[(n*512 + k0+kk)*4096 + hw0+hh]; }
    for (int e=tid;e<2048;e+=256){ int kk=e>>7, ccx=e&127; lw[kk*128+ccx] = w2[ccx*512 + k0+kk]; }
    __syncthreads();
    for (int kk=0;kk<16;++kk){
      float hv = lh[kk*64+hwl];
      const float* wr = &lw[kk*128 + cw*32];
      #pragma unroll
      for (int i=0;i<32;++i) acc[i] += wr[i]*hv;
    }
  }
  #pragma unroll
  for (int i=0;i<32;++i){
    int c = cw*32+i;
    int idx = (n*128+c)*4096 + hw0+hwl;
    out[idx] = acc[i] + out[idx];    // residual: same-thread read-then-write
  }
}

extern "C" void kernel_launch(void* const* d_in, const int* in_sizes, int n_in,
                              void* d_out, int out_size, void* d_ws, size_t ws_size,
                              hipStream_t stream) {
  (void)in_sizes; (void)n_in; (void)out_size; (void)ws_size;
  const float* x       = (const float*)d_in[0];
  const float* qkvw    = (const float*)d_in[1];
  const float* bng     = (const float*)d_in[2];
  const float* bnb     = (const float*)d_in[3];
  const float* baserel = (const float*)d_in[4];
  const float* simg    = (const float*)d_in[5];
  const float* simb    = (const float*)d_in[6];
  const float* outg    = (const float*)d_in[7];
  const float* outb    = (const float*)d_in[8];
  const float* ing     = (const float*)d_in[9];
  const float* inb     = (const float*)d_in[10];
  const float* w1      = (const float*)d_in[11];
  const float* w2      = (const float*)d_in[12];

  float* ws = (float*)d_ws;
  float*  W127  = ws + F_W127;
  float*  W64   = ws + F_W64;
  float2* qkvst = (float2*)(ws + F_QKVST);
  float2* simst = (float2*)(ws + F_SIMST);
  float2* sost  = (float2*)(ws + F_SOST);
  float2* inst  = (float2*)(ws + F_INST);
  float*  postmp= ws + F_POSTMP;
  float*  pos   = ws + F_POS;
  float*  qkv   = ws + F_QKV;
  float*  qkvr  = ws + F_QKVR;
  float*  sim   = ws + F_SIM;
  float*  ssum  = ws + F_SIMSUM;
  float*  vb    = ws + F_VB;
  float*  veH   = ws + F_VEH;
  float*  so    = ws + F_SO;     // aliases qkv (dead)
  float*  xn    = ws + F_XN;     // aliases sim (dead)
  float*  h1    = ws + F_H1;     // aliases sim tail + simsum + vb (dead)
  float*  out   = (float*)d_out;

  k_tables  <<<dim3(1),        dim3(128), 0, stream>>>(W127, W64);
  k_qkv     <<<dim3(512,4),    dim3(256), 0, stream>>>(x, qkvw, qkv);
  k_bnstats <<<dim3(256),      dim3(256), 0, stream>>>(qkv, bng, bnb, qkvst);
  k_qkvr    <<<dim3(16896),    dim3(256), 0, stream>>>(qkv, W64, qkvst, qkvr);
  k_pos1    <<<dim3(524),      dim3(256), 0, stream>>>(baserel, W127, postmp);
  k_pos2    <<<dim3(137),      dim3(256), 0, stream>>>(postmp, W127, pos);
  k_sim     <<<dim3(512,8),    dim3(256), 0, stream>>>(qkvr, pos, sim);
  k_simstats<<<dim3(192),      dim3(256), 0, stream>>>(sim, simg, simb, simst);
  k_simsum  <<<dim3(17424),    dim3(256), 0, stream>>>(sim, simst, ssum);
  k_vb      <<<dim3(16384),    dim3(256), 0, stream>>>(qkvr, vb);
  k_veH     <<<dim3(256),      dim3(256), 0, stream>>>(pos, veH);
  k_attn    <<<dim3(1024),     dim3(256), 0, stream>>>(ssum, vb, veH, so);
  k_bnstats <<<dim3(256),      dim3(256), 0, stream>>>(so, outg, outb, sost);
  k_o       <<<dim3(16384),    dim3(256), 0, stream>>>(so, sost, out);
  k_instats <<<dim3(1024),     dim3(256), 0, stream>>>(out, ing, inb, inst);
  k_xn      <<<dim3(16384),    dim3(256), 0, stream>>>(out, inst, xn);
  k_mlp1    <<<dim3(64,4,8),   dim3(256), 0, stream>>>(xn, w1, h1);
  k_mlp2    <<<dim3(64,8),     dim3(256), 0, stream>>>(h1, w2, out);
}

// Round 4
// 842.083 us; speedup vs baseline: 1.3339x; 1.2680x over previous
//
#include <hip/hip_runtime.h>
#include <math.h>

// Problem constants: N=8, C=128, H=64, W=64, B=N*W=512, ADJ=33, G=8, GP=16
constexpr float EPSV = 1e-5f;

// ---------------- workspace layout (offsets in floats) ----------------
constexpr size_t F_W127  = 0;                      // 33*127 = 4191 (padded 4224)
constexpr size_t F_W64   = F_W127 + 4224;          // 33*64 = 2112
constexpr size_t F_QKVST = F_W64  + 2112;          // float2[256] -> 512 floats
constexpr size_t F_SIMST = F_QKVST+ 512;           // float2[192] -> 384
constexpr size_t F_SOST  = F_SIMST+ 384;           // float2[256] -> 512
constexpr size_t F_INST  = F_SOST + 512;           // float2[1024]-> 2048
constexpr size_t F_POSTMP= F_INST + 2048;          // 32*33*127 = 134112 (alias: w1T+w2T after pos2)
constexpr size_t F_POS   = F_POSTMP + 134112;      // 32*33*33 = 34848 (alias: wT before pos2)
constexpr size_t F_QKV   = F_POS  + 34848;         // 512*256*64 = 8388608 (alias: SO)
constexpr size_t F_QKVR  = F_QKV  + 8388608;       // 512*256*33 = 4325376
constexpr size_t F_SIM   = F_QKVR + 4325376;       // 512*24*1089 = 13381632 (alias: XP early, XN/H1 late)
constexpr size_t F_SIMSUM= F_SIM  + 13381632;      // 512*8*1089 = 4460544
constexpr size_t F_VB    = F_SIMSUM + 4460544;     // 512*8*16*64 = 4194304 (16B-aligned base)
constexpr size_t F_VEH   = F_VB   + 4194304;       // 16*64*64 = 65536 (16B-aligned base)
constexpr size_t F_SO    = F_QKV;                  // qkv dead after k_qkvr
constexpr size_t F_XP    = F_SIM;                  // xp (512*128*64=4194304) dead before k_sim
constexpr size_t F_XN    = F_SIM;                  // sim dead after k_simsum
constexpr size_t F_H1    = F_SIM + 4194304;        // 16777216 floats; spans dead sim/simsum/vb
constexpr size_t F_WT    = F_POS;                  // qkv_w^T (32768) dead before k_pos2
constexpr size_t F_W1T   = F_POSTMP;               // 65536, written after pos2 (postmp dead)
constexpr size_t F_W2T   = F_POSTMP + 65536;       // 65536 (65536*2=131072 <= 134112)

__device__ __forceinline__ void fma4(float4& a, const float4& h, float s){
  a.x += h.x*s; a.y += h.y*s; a.z += h.z*s; a.w += h.w*s;
}

// ---------------- resize weight tables (jax.image.resize, antialias=True) ----------------
__global__ void k_tables(float* __restrict__ W127, float* __restrict__ W64){
  int i = threadIdx.x;
  if (i < 33){
    const float inv = 127.0f/33.0f;          // kernel_scale for downsample (antialias)
    float x = ((float)i + 0.5f)*inv - 0.5f;  // half-pixel sample position
    float s = 0.f;
    for (int j=0;j<127;++j){ float w = 1.0f - fabsf((float)j - x)/inv; w = fmaxf(w,0.f); W127[i*127+j]=w; s+=w; }
    float r = 1.0f/s;
    for (int j=0;j<127;++j) W127[i*127+j] *= r;
  } else if (i < 66){
    int ii = i-33;
    const float inv = 64.0f/33.0f;
    float x = ((float)ii + 0.5f)*inv - 0.5f;
    float s=0.f;
    for (int j=0;j<64;++j){ float w = 1.0f - fabsf((float)j - x)/inv; w=fmaxf(w,0.f); W64[ii*64+j]=w; s+=w; }
    float r=1.0f/s;
    for (int j=0;j<64;++j) W64[ii*64+j]*=r;
  }
}

// up-sample 33->64: clamp + 2-tap lerp (matches jax normalized edge weights)
__device__ __forceinline__ void upfac(int o, int& j0, float& f){
  float x = ((float)o + 0.5f)*0.515625f - 0.5f;   // 33/64 = 0.515625 exact
  x = fminf(fmaxf(x, 0.f), 32.f);
  int j = (int)x; j = j < 31 ? j : 31;
  j0 = j; f = x - (float)j;
}

// ---------------- generic 32x32-tiled transpose: dst[c*R+r] = src[r*C+c] ----------------
__global__ __launch_bounds__(256) void k_tr(const float* __restrict__ src, float* __restrict__ dst,
                                            int R, int C){
  __shared__ float T[32][33];
  int r0 = blockIdx.x*32, c0 = blockIdx.y*32;
  int tx = threadIdx.x&31, ty = threadIdx.x>>5;  // 32 x 8
  #pragma unroll
  for (int q=0;q<4;++q){ int r = ty + q*8; T[r][tx] = src[(r0+r)*C + c0+tx]; }
  __syncthreads();
  #pragma unroll
  for (int q=0;q<4;++q){ int c = ty + q*8; dst[(c0+c)*R + r0+tx] = T[tx][c]; }
}

// ---------------- x (N,C,H,W) -> xp (N*W, C, H): per-(n,c) 64x64 transpose ----------------
__global__ __launch_bounds__(256) void k_xt(const float* __restrict__ x, float* __restrict__ xp){
  __shared__ float T[64][65];
  int n = blockIdx.x>>7, c = blockIdx.x&127;
  const float* src = x + ((size_t)(n*128 + c))*4096;
  int tid = threadIdx.x;
  for (int e=tid;e<4096;e+=256){ int h=e>>6, w=e&63; T[h][w] = src[e]; }  // lanes along w: coalesced
  __syncthreads();
  for (int e=tid;e<4096;e+=256){
    int w=e>>6, h=e&63;                       // lanes along h: coalesced writes
    xp[((size_t)((n*64+w)*128 + c))*64 + h] = T[h][w];
  }
}

// ---------------- QKV projection GEMM: qkv[b,o,l] = sum_c wT[c,o]*xp[b,c,l] ----------------
// per-thread 4o x 4l register tile, float4 LDS reads (2 ds_read_b128 per 16 FMA)
__global__ __launch_bounds__(256) void k_qkv(const float* __restrict__ xp, const float* __restrict__ wT,
                                             float* __restrict__ qkv){
  int b = blockIdx.x, o0 = blockIdx.y*64;
  int tid = threadIdx.x;
  int lt = tid&15, ot = tid>>4;
  __shared__ float4 LX[32][16];   // [kk][l/4]
  __shared__ float4 LW[32][16];   // [kk][o/4]
  const float4* xp4 = (const float4*)xp;
  const float4* wT4 = (const float4*)wT;
  float4 acc[4];
  #pragma unroll
  for (int j=0;j<4;++j) acc[j] = make_float4(0.f,0.f,0.f,0.f);
  for (int c0=0;c0<128;c0+=32){
    __syncthreads();
    #pragma unroll
    for (int p=0;p<2;++p){
      int e = tid + p*256; int kk=e>>4, q=e&15;
      LX[kk][q] = xp4[(size_t)b*2048 + (c0+kk)*16 + q];
      LW[kk][q] = wT4[(c0+kk)*64 + (o0>>2) + q];
    }
    __syncthreads();
    #pragma unroll
    for (int kk=0;kk<32;++kk){
      float4 x4 = LX[kk][lt];
      float4 w4 = LW[kk][ot];
      fma4(acc[0], x4, w4.x); fma4(acc[1], x4, w4.y);
      fma4(acc[2], x4, w4.z); fma4(acc[3], x4, w4.w);
    }
  }
  float4* qkv4 = (float4*)qkv;
  #pragma unroll
  for (int j=0;j<4;++j)
    qkv4[((size_t)b*16384 + (o0 + ot*4 + j)*64)/4 + lt] = acc[j];
}

// ---------------- BN stats over [512][256][64], per channel (used for qkv and so) ----------------
__global__ __launch_bounds__(256) void k_bnstats(const float* __restrict__ src, const float* __restrict__ g,
                                                 const float* __restrict__ bta, float2* __restrict__ st){
  int ch = blockIdx.x, t = threadIdx.x;
  float s=0.f, s2=0.f;
  for (int e=t; e<512*64; e+=256){
    int r=e>>6, l=e&63;
    float v = src[(r*256+ch)*64 + l];
    s+=v; s2+=v*v;
  }
  __shared__ float rs[256], rq[256];
  rs[t]=s; rq[t]=s2; __syncthreads();
  for (int o=128;o>0;o>>=1){ if(t<o){ rs[t]+=rs[t+o]; rq[t]+=rq[t+o]; } __syncthreads(); }
  if (t==0){
    float m = rs[0]*(1.0f/32768.0f);
    float var = rq[0]*(1.0f/32768.0f) - m*m;
    float sc = g[ch]/sqrtf(var + EPSV);
    st[ch] = make_float2(sc, bta[ch] - m*sc);
  }
}

// ---------------- qkv: BN fold + resize 64->33 along l ----------------
__global__ void k_qkvr(const float* __restrict__ qkv, const float* __restrict__ W64,
                       const float2* __restrict__ st, float* __restrict__ qkvr){
  int id = blockIdx.x*256 + threadIdx.x;       // 512*256*33
  int b = id / 8448; int r = id - b*8448; int ch = r / 33; int i = r - ch*33;
  const float* row = qkv + (b*256 + ch)*64;
  const float* wr = W64 + i*64;
  float a=0.f;
  #pragma unroll 16
  for (int t=0;t<64;++t) a += wr[t]*row[t];
  float2 sb = st[ch];
  qkvr[id] = a*sb.x + sb.y;
}

// ---------------- pos = resize(base_relative, (32,33,33)) separable ----------------
__global__ void k_pos1(const float* __restrict__ base, const float* __restrict__ W127, float* __restrict__ tmp){
  int id = blockIdx.x*256 + threadIdx.x;
  if (id >= 32*33*127) return;
  int c = id / 4191; int r = id - c*4191; int i = r / 127; int xx = r - i*127;
  const float* wr = W127 + i*127;
  const float* bc = base + c*16129 + xx;
  float a=0.f;
  for (int y=0;y<127;++y) a += wr[y]*bc[y*127];
  tmp[id] = a;
}
__global__ void k_pos2(const float* __restrict__ tmp, const float* __restrict__ W127, float* __restrict__ pos){
  int id = blockIdx.x*256 + threadIdx.x;
  if (id >= 32*33*33) return;
  int c = id / 1089; int r = id - c*1089; int i = r / 33; int j = r - i*33;
  const float* wr = W127 + j*127;
  const float* tc = tmp + c*4191 + i*127;
  float a=0.f;
  for (int xx=0;xx<127;++xx) a += wr[xx]*tc[xx];
  pos[id] = a;
}

// ---------------- sim = concat([qk, qr, kr]) for each (b,g) ----------------
__global__ __launch_bounds__(256) void k_sim(const float* __restrict__ qkvr, const float* __restrict__ pos,
                                             float* __restrict__ sim){
  int b = blockIdx.x, g = blockIdx.y;
  __shared__ float lqa[264], lka[264];  // [8 c][33 i]
  int tid = threadIdx.x;
  for (int e=tid;e<528;e+=256){
    int half = (e < 264) ? 0 : 1;
    int e2 = e - half*264;
    int c = e2/33, i = e2 - c*33;
    float v = qkvr[(b*256 + g*32 + half*8 + c)*33 + i];
    if (half==0) lqa[e2]=v; else lka[e2]=v;
  }
  __syncthreads();
  for (int p=tid;p<1089;p+=256){
    int i = p/33, j = p - i*33;
    float qk=0.f, qr=0.f, kr=0.f;
    #pragma unroll
    for (int c=0;c<8;++c){
      float qa_ = lqa[c*33+i];
      float ka_ = lka[c*33+j];
      qk += qa_*ka_;
      qr += qa_*pos[c*1089 + i*33 + j];          // q_e = pos[0:8]
      kr += ka_*pos[(8+c)*1089 + j*33 + i];      // k_e = pos[8:16], transposed use
    }
    sim[(b*24 + g)*1089 + p] = qk;
    sim[(b*24 + 8 + g)*1089 + p] = qr;
    sim[(b*24 + 16 + g)*1089 + p] = kr;
  }
}

// ---------------- per-(n, ch24) stats over (W, i, j) ----------------
__global__ __launch_bounds__(256) void k_simstats(const float* __restrict__ sim, const float* __restrict__ g,
                                                  const float* __restrict__ bta, float2* __restrict__ st){
  int nb = blockIdx.x; int n = nb/24, ch = nb - n*24;
  int t = threadIdx.x;
  float s=0.f, s2=0.f;
  for (int e=t; e<64*1089; e+=256){
    int w = e/1089, p = e - w*1089;
    float v = sim[((n*64+w)*24 + ch)*1089 + p];
    s+=v; s2+=v*v;
  }
  __shared__ float rs[256], rq[256];
  rs[t]=s; rq[t]=s2; __syncthreads();
  for (int o=128;o>0;o>>=1){ if(t<o){ rs[t]+=rs[t+o]; rq[t]+=rq[t+o]; } __syncthreads(); }
  if (t==0){
    float m = rs[0]*(1.0f/69696.0f);
    float var = rq[0]*(1.0f/69696.0f) - m*m;
    float sc = g[ch]/sqrtf(var + EPSV);
    st[nb] = make_float2(sc, bta[ch] - m*sc);
  }
}

// ---------------- normalize + sum over the 3 groups ----------------
__global__ void k_simsum(const float* __restrict__ sim, const float2* __restrict__ st, float* __restrict__ ss){
  int id = blockIdx.x*256 + threadIdx.x;      // 512*8*1089
  int b = id / 8712; int r = id - b*8712; int g = r / 1089; int p = r - g*1089;
  int n = b>>6;
  float a = 0.f;
  #pragma unroll
  for (int t3=0;t3<3;++t3){
    float2 sb = st[n*24 + t3*8 + g];
    a += sim[(b*24 + t3*8 + g)*1089 + p]*sb.x + sb.y;
  }
  ss[id] = a;
}

// ---------------- vb: resize va (33) back to 64 along last dim ----------------
__global__ void k_vb(const float* __restrict__ qkvr, float* __restrict__ vb){
  int id = blockIdx.x*256 + threadIdx.x;      // (b*8+g)*16+c)*64 + j
  int j = id & 63; int r = id >> 6;
  int b = r >> 7; int rem = r & 127; int g = rem >> 4; int c = rem & 15;
  const float* row = qkvr + (b*256 + g*32 + 16 + c)*33;
  int j0; float f; upfac(j, j0, f);
  vb[id] = (1.f-f)*row[j0] + f*row[j0+1];
}

// ---------------- v_eH: resize v_e (16,33,33) -> (16,64,64) ----------------
__global__ void k_veH(const float* __restrict__ pos, float* __restrict__ veH){
  int id = blockIdx.x*256 + threadIdx.x;  // 16*64*64
  int j = id&63, i=(id>>6)&63, c=id>>12;
  int i0, j0; float fi, fj;
  upfac(i, i0, fi); upfac(j, j0, fj);
  const float* P = pos + (16+c)*1089;
  float v0 = (1.f-fj)*P[i0*33+j0]     + fj*P[i0*33+j0+1];
  float v1 = (1.f-fj)*P[(i0+1)*33+j0] + fj*P[(i0+1)*33+j0+1];
  veH[id] = (1.f-fi)*v0 + fi*v1;
}

// ---------------- fused: upsample sim 33->64 (2D), softmax, sv & sve -> so ----------------
__global__ __launch_bounds__(256) void k_attn(const float* __restrict__ ss, const float* __restrict__ vb,
                                              const float* __restrict__ veH, float* __restrict__ so){
  int wv = threadIdx.x >> 6;
  int i  = threadIdx.x & 63;
  int bg = blockIdx.x*4 + wv;
  int b = bg>>3, g = bg&7;
  __shared__ float  S[4][1092];   // 33x33 simsum tile per wave
  __shared__ float4 V[4][256];    // [16 c][16 q4] vb tile per wave, natively float4
  float* Sw = S[wv];
  const float4* vb4 = (const float4*)(vb + (size_t)bg*1024);   // bg*4096B from 16B-aligned base
  for (int e=i;e<1089;e+=64) Sw[e] = ss[(size_t)bg*1089 + e];
  for (int e=i;e<256;e+=64)  V[wv][e] = vb4[e];
  __syncthreads();

  // phase A: bilinear upsample row i (33->64 both dims) + softmax, in registers
  int i0; float fi; upfac(i, i0, fi);
  const float* R0 = Sw + i0*33;
  const float* R1 = R0 + 33;
  float p[64];
  float mx = -1e30f;
  #pragma unroll
  for (int j=0;j<64;++j){
    int j0; float fj; upfac(j, j0, fj);       // j constant after unroll
    float v0 = (1.f-fj)*R0[j0] + fj*R0[j0+1];
    float v1 = (1.f-fj)*R1[j0] + fj*R1[j0+1];
    float su = (1.f-fi)*v0 + fi*v1;
    p[j] = su;
    mx = fmaxf(mx, su);
  }
  float s = 0.f;
  #pragma unroll
  for (int j=0;j<64;++j){ float e = expf(p[j]-mx); p[j]=e; s+=e; }
  float inv = 1.f/s;

  // phase B: sv (LDS float4 broadcast) and sve (global float4, L2-hit)
  float* ob = so + (size_t)b*16384 + g*2048;   // channel 2*(g*16+c) at offset (g*16+c)*128
  const float4* lv4 = &V[wv][0];
  for (int c=0;c<16;++c){
    float a=0.f;
    #pragma unroll
    for (int q=0;q<16;++q){
      float4 v4 = lv4[c*16+q];
      a += p[4*q]*v4.x + p[4*q+1]*v4.y + p[4*q+2]*v4.z + p[4*q+3]*v4.w;
    }
    ob[c*128 + i] = a*inv;             // sv -> even channel
  }
  const float4* veH4 = (const float4*)veH;     // buffer base is 16B-aligned
  for (int c=0;c<16;++c){
    float a=0.f;
    #pragma unroll
    for (int q=0;q<16;++q){
      float4 v4 = veH4[(c*64 + i)*16 + q];
      a += p[4*q]*v4.x + p[4*q+1]*v4.y + p[4*q+2]*v4.z + p[4*q+3]*v4.w;
    }
    ob[c*128 + 64 + i] = a*inv;        // sve -> odd channel
  }
}

// ---------------- BN(so) + pair-sum + transpose -> o in (N,C,H,W) ----------------
__global__ void k_o(const float* __restrict__ so, const float2* __restrict__ st, float* __restrict__ o){
  int id = blockIdx.x*256 + threadIdx.x;  // ((n*128+oc)*64+h)*64+w
  int w = id&63, h=(id>>6)&63, oc=(id>>12)&127, n=id>>19;
  int b = n*64 + w;
  float2 s0 = st[2*oc], s1 = st[2*oc+1];
  float v0 = so[b*16384 + (2*oc)*64 + h];
  float v1 = so[b*16384 + (2*oc+1)*64 + h];
  o[id] = v0*s0.x + s0.y + v1*s1.x + s1.y;
}

// ---------------- spatial block: shifted-channel construction ----------------
__device__ __forceinline__ float xo_val(const float* __restrict__ o, int n, int c, int h, int w){
  if (c >= 40) return o[((n*128 + c)*64 + h)*64 + w];
  int grp = c / 10;
  int cc = c - grp*10;
  int base = (n*128 + cc)*64;
  if (grp==0) return (w>=2) ? o[(base + h)*64 + (w-2)] : 0.f;      // r
  if (grp==1) return (w<62) ? o[(base + h)*64 + (w+2)] : 0.f;      // l
  if (grp==2) return (h>=2) ? o[(base + (h-2))*64 + w] : 0.f;      // d
  return (h<62) ? o[(base + (h+2))*64 + w] : 0.f;                  // u
}

__global__ __launch_bounds__(256) void k_instats(const float* __restrict__ o, const float* __restrict__ g,
                                                 const float* __restrict__ bta, float2* __restrict__ st){
  int nb = blockIdx.x; int n = nb>>7, c = nb&127;
  int t = threadIdx.x;
  float s=0.f,s2=0.f;
  for (int e=t;e<4096;e+=256){
    int h=e>>6, w=e&63;
    float v = xo_val(o,n,c,h,w);
    s+=v; s2+=v*v;
  }
  __shared__ float rs[256], rq[256];
  rs[t]=s; rq[t]=s2; __syncthreads();
  for (int oo=128;oo>0;oo>>=1){ if(t<oo){ rs[t]+=rs[t+oo]; rq[t]+=rq[t+oo]; } __syncthreads(); }
  if (t==0){
    float m = rs[0]*(1.0f/4096.0f);
    float var = rq[0]*(1.0f/4096.0f) - m*m;
    float sc = g[c]/sqrtf(var + EPSV);
    st[nb] = make_float2(sc, bta[c] - m*sc);
  }
}

__global__ void k_xn(const float* __restrict__ o, const float2* __restrict__ st, float* __restrict__ xn){
  int id = blockIdx.x*256+threadIdx.x;
  int w=id&63,h=(id>>6)&63,c=(id>>12)&127,n=id>>19;
  float2 sb = st[n*128+c];
  xn[id] = xo_val(o,n,c,h,w)*sb.x + sb.y;
}

// ---------------- MLP layer 1: h1 = gelu(w1T^T @ xn), 32hw x 128cout tile ----------------
__global__ __launch_bounds__(256) void k_mlp1(const float* __restrict__ xn, const float* __restrict__ w1T,
                                              float* __restrict__ h1){
  int hw0 = blockIdx.x*32, co0 = blockIdx.y*128, n = blockIdx.z;
  int tid = threadIdx.x;
  int hwt = tid&7, cot = tid>>3;
  __shared__ float4 LH[32][8];    // [kk][hw/4]
  __shared__ float4 LW[32][32];   // [kk][cout/4]
  const float4* xn4  = (const float4*)xn;
  const float4* w1T4 = (const float4*)w1T;
  float4 acc[4];
  #pragma unroll
  for (int j=0;j<4;++j) acc[j] = make_float4(0.f,0.f,0.f,0.f);
  for (int c0=0;c0<128;c0+=32){
    __syncthreads();
    { int kk=tid>>3, q=tid&7;
      LH[kk][q] = xn4[((size_t)(n*128 + c0+kk)*4096 + hw0)/4 + q]; }
    #pragma unroll
    for (int p=0;p<4;++p){
      int e = tid + p*256; int kk=e>>5, q=e&31;
      LW[kk][q] = w1T4[((size_t)(c0+kk)*512 + co0)/4 + q];
    }
    __syncthreads();
    #pragma unroll
    for (int kk=0;kk<32;++kk){
      float4 h = LH[kk][hwt];
      float4 w = LW[kk][cot];
      fma4(acc[0], h, w.x); fma4(acc[1], h, w.y);
      fma4(acc[2], h, w.z); fma4(acc[3], h, w.w);
    }
  }
  float4* h14 = (float4*)h1;
  #pragma unroll
  for (int j=0;j<4;++j){
    int cout = co0 + cot*4 + j;
    float4 v = acc[j];
    v.x = 0.5f*v.x*(1.0f + erff(v.x*0.70710678f));
    v.y = 0.5f*v.y*(1.0f + erff(v.y*0.70710678f));
    v.z = 0.5f*v.z*(1.0f + erff(v.z*0.70710678f));
    v.w = 0.5f*v.w*(1.0f + erff(v.w*0.70710678f));
    h14[((size_t)(n*512 + cout)*4096 + hw0)/4 + hwt] = v;
  }
}

// ---------------- MLP layer 2 + residual: 32hw x 128cout tile, K=512 ----------------
__global__ __launch_bounds__(256) void k_mlp2(const float* __restrict__ h1, const float* __restrict__ w2T,
                                              float* __restrict__ out){
  int hw0 = blockIdx.x*32, n = blockIdx.z;
  int tid = threadIdx.x;
  int hwt = tid&7, cot = tid>>3;
  __shared__ float4 LH[32][8];    // [kk][hw/4]
  __shared__ float4 LW[32][32];   // [kk][cout/4]
  const float4* h14  = (const float4*)h1;
  const float4* w2T4 = (const float4*)w2T;
  float4 acc[4];
  #pragma unroll
  for (int j=0;j<4;++j) acc[j] = make_float4(0.f,0.f,0.f,0.f);
  for (int k0=0;k0<512;k0+=32){
    __syncthreads();
    { int kk=tid>>3, q=tid&7;
      LH[kk][q] = h14[((size_t)(n*512 + k0+kk)*4096 + hw0)/4 + q]; }
    #pragma unroll
    for (int p=0;p<4;++p){
      int e = tid + p*256; int kk=e>>5, q=e&31;
      LW[kk][q] = w2T4[((size_t)(k0+kk)*128)/4 + q];
    }
    __syncthreads();
    #pragma unroll
    for (int kk=0;kk<32;++kk){
      float4 h = LH[kk][hwt];
      float4 w = LW[kk][cot];
      fma4(acc[0], h, w.x); fma4(acc[1], h, w.y);
      fma4(acc[2], h, w.z); fma4(acc[3], h, w.w);
    }
  }
  float4* out4 = (float4*)out;
  #pragma unroll
  for (int j=0;j<4;++j){
    int c = cot*4 + j;
    size_t idx = ((size_t)(n*128 + c)*4096 + hw0)/4 + hwt;
    float4 prev = out4[idx];
    prev.x += acc[j].x; prev.y += acc[j].y; prev.z += acc[j].z; prev.w += acc[j].w;
    out4[idx] = prev;    // residual: same-thread read-then-write
  }
}

extern "C" void kernel_launch(void* const* d_in, const int* in_sizes, int n_in,
                              void* d_out, int out_size, void* d_ws, size_t ws_size,
                              hipStream_t stream) {
  (void)in_sizes; (void)n_in; (void)out_size; (void)ws_size;
  const float* x       = (const float*)d_in[0];
  const float* qkvw    = (const float*)d_in[1];
  const float* bng     = (const float*)d_in[2];
  const float* bnb     = (const float*)d_in[3];
  const float* baserel = (const float*)d_in[4];
  const float* simg    = (const float*)d_in[5];
  const float* simb    = (const float*)d_in[6];
  const float* outg    = (const float*)d_in[7];
  const float* outb    = (const float*)d_in[8];
  const float* ing     = (const float*)d_in[9];
  const float* inb     = (const float*)d_in[10];
  const float* w1      = (const float*)d_in[11];
  const float* w2      = (const float*)d_in[12];

  float* ws = (float*)d_ws;
  float*  W127  = ws + F_W127;
  float*  W64   = ws + F_W64;
  float2* qkvst = (float2*)(ws + F_QKVST);
  float2* simst = (float2*)(ws + F_SIMST);
  float2* sost  = (float2*)(ws + F_SOST);
  float2* inst  = (float2*)(ws + F_INST);
  float*  postmp= ws + F_POSTMP;
  float*  pos   = ws + F_POS;
  float*  qkv   = ws + F_QKV;
  float*  qkvr  = ws + F_QKVR;
  float*  sim   = ws + F_SIM;
  float*  ssum  = ws + F_SIMSUM;
  float*  vb    = ws + F_VB;
  float*  veH   = ws + F_VEH;
  float*  so    = ws + F_SO;     // aliases qkv (dead)
  float*  xp    = ws + F_XP;     // aliases sim (dead until k_sim)
  float*  xn    = ws + F_XN;     // aliases sim (dead)
  float*  h1    = ws + F_H1;     // aliases sim tail + simsum + vb (dead)
  float*  wT    = ws + F_WT;     // aliases pos (dead until k_pos2)
  float*  w1T   = ws + F_W1T;    // aliases postmp (dead after k_pos2)
  float*  w2T   = ws + F_W2T;
  float*  out   = (float*)d_out;

  k_tables  <<<dim3(1),        dim3(128), 0, stream>>>(W127, W64);
  k_tr      <<<dim3(8,4),      dim3(256), 0, stream>>>(qkvw, wT, 256, 128);  // wT[c][o]
  k_xt      <<<dim3(1024),     dim3(256), 0, stream>>>(x, xp);
  k_qkv     <<<dim3(512,4),    dim3(256), 0, stream>>>(xp, wT, qkv);
  k_bnstats <<<dim3(256),      dim3(256), 0, stream>>>(qkv, bng, bnb, qkvst);
  k_qkvr    <<<dim3(16896),    dim3(256), 0, stream>>>(qkv, W64, qkvst, qkvr);
  k_pos1    <<<dim3(524),      dim3(256), 0, stream>>>(baserel, W127, postmp);
  k_pos2    <<<dim3(137),      dim3(256), 0, stream>>>(postmp, W127, pos);
  k_tr      <<<dim3(16,4),     dim3(256), 0, stream>>>(w1, w1T, 512, 128);   // w1T[c][o512]
  k_tr      <<<dim3(4,16),     dim3(256), 0, stream>>>(w2, w2T, 128, 512);   // w2T[k][c128]
  k_sim     <<<dim3(512,8),    dim3(256), 0, stream>>>(qkvr, pos, sim);
  k_simstats<<<dim3(192),      dim3(256), 0, stream>>>(sim, simg, simb, simst);
  k_simsum  <<<dim3(17424),    dim3(256), 0, stream>>>(sim, simst, ssum);
  k_vb      <<<dim3(16384),    dim3(256), 0, stream>>>(qkvr, vb);
  k_veH     <<<dim3(256),      dim3(256), 0, stream>>>(pos, veH);
  k_attn    <<<dim3(1024),     dim3(256), 0, stream>>>(ssum, vb, veH, so);
  k_bnstats <<<dim3(256),      dim3(256), 0, stream>>>(so, outg, outb, sost);
  k_o       <<<dim3(16384),    dim3(256), 0, stream>>>(so, sost, out);
  k_instats <<<dim3(1024),     dim3(256), 0, stream>>>(out, ing, inb, inst);
  k_xn      <<<dim3(16384),    dim3(256), 0, stream>>>(out, inst, xn);
  k_mlp1    <<<dim3(128,4,8),  dim3(256), 0, stream>>>(xn, w1T, h1);
  k_mlp2    <<<dim3(128,1,8),  dim3(256), 0, stream>>>(h1, w2T, out);
}

// Round 5
// 769.454 us; speedup vs baseline: 1.4598x; 1.0944x over previous
//
#include <hip/hip_runtime.h>
#include <math.h>

// Problem constants: N=8, C=128, H=64, W=64, B=N*W=512, ADJ=33, G=8, GP=16
constexpr float EPSV = 1e-5f;

// ---------------- workspace layout (offsets in floats) ----------------
constexpr size_t F_W127  = 0;                      // 33*127 = 4191 (padded 4224)
constexpr size_t F_W64   = F_W127 + 4224;          // 33*64 = 2112
constexpr size_t F_QKVST = F_W64  + 2112;          // float2[256] -> 512 floats
constexpr size_t F_SIMST = F_QKVST+ 512;           // float2[192] -> 384
constexpr size_t F_SOST  = F_SIMST+ 384;           // float2[256] -> 512
constexpr size_t F_INST  = F_SOST + 512;           // float2[1024]-> 2048
constexpr size_t F_POSTMP= F_INST + 2048;          // 32*33*127 = 134112 (alias: w1T+w2T after pos2)
constexpr size_t F_POS   = F_POSTMP + 134112;      // 32*33*33 = 34848 (alias: wT before pos2)
constexpr size_t F_QKV   = F_POS  + 34848;         // qkvT [512][64][256] = 8388608 (alias: SO)
constexpr size_t F_QKVR  = F_QKV  + 8388608;       // qkvrT [512][33][256] = 4325376
constexpr size_t F_SIM   = F_QKVR + 4325376;       // 512*24*1089 = 13381632 (alias: XP early, BNP, XN/H1 late)
constexpr size_t F_SIMSUM= F_SIM  + 13381632;      // 512*8*1089 = 4460544
constexpr size_t F_VB    = F_SIMSUM + 4460544;     // 512*8*16*64 = 4194304 (16B-aligned base)
constexpr size_t F_VEH   = F_VB   + 4194304;       // 16*64*64 = 65536 (16B-aligned base)
constexpr size_t F_SO    = F_QKV;                  // qkvT dead after k_qkvr
constexpr size_t F_XP    = F_SIM;                  // xp (4194304) dead after k_qkv
constexpr size_t F_BNP   = F_SIM;                  // bn partials (32*256 float2 = 16384 f), after xp dead
constexpr size_t F_XN    = F_SIM;                  // sim dead after k_simsum
constexpr size_t F_H1    = F_SIM + 4194304;        // 16777216 floats; spans dead sim/simsum/vb
constexpr size_t F_WT    = F_POS;                  // qkv_w^T (32768) dead before k_pos2
constexpr size_t F_W1T   = F_POSTMP;               // 65536, written after pos2 (postmp dead)
constexpr size_t F_W2T   = F_POSTMP + 65536;       // 65536 (131072 <= 134112)

__device__ __forceinline__ void fma4(float4& a, const float4& h, float s){
  a.x += h.x*s; a.y += h.y*s; a.z += h.z*s; a.w += h.w*s;
}

// ---------------- resize weight tables (jax.image.resize, antialias=True) ----------------
__global__ void k_tables(float* __restrict__ W127, float* __restrict__ W64){
  int i = threadIdx.x;
  if (i < 33){
    const float inv = 127.0f/33.0f;          // kernel_scale for downsample (antialias)
    float x = ((float)i + 0.5f)*inv - 0.5f;  // half-pixel sample position
    float s = 0.f;
    for (int j=0;j<127;++j){ float w = 1.0f - fabsf((float)j - x)/inv; w = fmaxf(w,0.f); W127[i*127+j]=w; s+=w; }
    float r = 1.0f/s;
    for (int j=0;j<127;++j) W127[i*127+j] *= r;
  } else if (i < 66){
    int ii = i-33;
    const float inv = 64.0f/33.0f;
    float x = ((float)ii + 0.5f)*inv - 0.5f;
    float s=0.f;
    for (int j=0;j<64;++j){ float w = 1.0f - fabsf((float)j - x)/inv; w=fmaxf(w,0.f); W64[ii*64+j]=w; s+=w; }
    float r=1.0f/s;
    for (int j=0;j<64;++j) W64[ii*64+j]*=r;
  }
}

// up-sample 33->64: clamp + 2-tap lerp (matches jax normalized edge weights)
__device__ __forceinline__ void upfac(int o, int& j0, float& f){
  float x = ((float)o + 0.5f)*0.515625f - 0.5f;   // 33/64 = 0.515625 exact
  x = fminf(fmaxf(x, 0.f), 32.f);
  int j = (int)x; j = j < 31 ? j : 31;
  j0 = j; f = x - (float)j;
}

// ---------------- generic 32x32-tiled transpose: dst[c*R+r] = src[r*C+c] ----------------
__global__ __launch_bounds__(256) void k_tr(const float* __restrict__ src, float* __restrict__ dst,
                                            int R, int C){
  __shared__ float T[32][33];
  int r0 = blockIdx.x*32, c0 = blockIdx.y*32;
  int tx = threadIdx.x&31, ty = threadIdx.x>>5;  // 32 x 8
  #pragma unroll
  for (int q=0;q<4;++q){ int r = ty + q*8; T[r][tx] = src[(r0+r)*C + c0+tx]; }
  __syncthreads();
  #pragma unroll
  for (int q=0;q<4;++q){ int c = ty + q*8; dst[(c0+c)*R + r0+tx] = T[tx][c]; }
}

// ---------------- x (N,C,H,W) -> xp (N*W, C, H): per-(n,c) 64x64 transpose ----------------
__global__ __launch_bounds__(256) void k_xt(const float* __restrict__ x, float* __restrict__ xp){
  __shared__ float T[64][65];
  int n = blockIdx.x>>7, c = blockIdx.x&127;
  const float* src = x + ((size_t)(n*128 + c))*4096;
  int tid = threadIdx.x;
  for (int e=tid;e<4096;e+=256){ int h=e>>6, w=e&63; T[h][w] = src[e]; }  // lanes along w: coalesced
  __syncthreads();
  for (int e=tid;e<4096;e+=256){
    int w=e>>6, h=e&63;                       // lanes along h: coalesced writes
    xp[((size_t)((n*64+w)*128 + c))*64 + h] = T[h][w];
  }
}

// ---------------- QKV projection GEMM -> TRANSPOSED out: qkvT[b][l][o] ----------------
// per-thread 4l x 4o tile (float4 across o so stores are o-contiguous/coalesced)
__global__ __launch_bounds__(256) void k_qkv(const float* __restrict__ xp, const float* __restrict__ wT,
                                             float* __restrict__ qkvT){
  int b = blockIdx.x, o0 = blockIdx.y*64;
  int tid = threadIdx.x;
  int ot = tid&15, lt = tid>>4;
  __shared__ float4 LX[32][16];   // [kk][l/4]
  __shared__ float4 LW[32][16];   // [kk][o/4]
  const float4* xp4 = (const float4*)xp;
  const float4* wT4 = (const float4*)wT;
  float4 acc[4];                  // acc[j] = l=lt*4+j, float4 across o
  #pragma unroll
  for (int j=0;j<4;++j) acc[j] = make_float4(0.f,0.f,0.f,0.f);
  for (int c0=0;c0<128;c0+=32){
    __syncthreads();
    #pragma unroll
    for (int p=0;p<2;++p){
      int e = tid + p*256; int kk=e>>4, q=e&15;
      LX[kk][q] = xp4[(size_t)b*2048 + (c0+kk)*16 + q];
      LW[kk][q] = wT4[(c0+kk)*64 + (o0>>2) + q];
    }
    __syncthreads();
    #pragma unroll
    for (int kk=0;kk<32;++kk){
      float4 x4 = LX[kk][lt];
      float4 w4 = LW[kk][ot];
      fma4(acc[0], w4, x4.x); fma4(acc[1], w4, x4.y);
      fma4(acc[2], w4, x4.z); fma4(acc[3], w4, x4.w);
    }
  }
  float4* qkvT4 = (float4*)qkvT;
  #pragma unroll
  for (int j=0;j<4;++j)
    qkvT4[((size_t)b*16384 + (lt*4+j)*256 + o0 + ot*4)>>2] = acc[j];
}

// ---------------- BN partial sums over rows of qkvT [32768 rows][256 ch] ----------------
__global__ __launch_bounds__(256) void k_bnsum(const float* __restrict__ qkvT, float2* __restrict__ part){
  int chG = blockIdx.x, rowG = blockIdx.y;
  int cl = threadIdx.x&63;
  int ch = chG*64 + cl;
  int rs = threadIdx.x>>6;  // 0..3
  float s=0.f, s2=0.f;
  for (int r = rowG*1024 + rs; r < rowG*1024 + 1024; r += 4){
    float v = qkvT[(size_t)r*256 + ch]; s+=v; s2+=v*v;
  }
  __shared__ float S1[4][64], S2[4][64];
  S1[rs][cl]=s; S2[rs][cl]=s2; __syncthreads();
  if (rs==0){
    s  = S1[0][cl]+S1[1][cl]+S1[2][cl]+S1[3][cl];
    s2 = S2[0][cl]+S2[1][cl]+S2[2][cl]+S2[3][cl];
    part[rowG*256 + ch] = make_float2(s, s2);
  }
}
__global__ void k_stats2(const float2* __restrict__ part, const float* __restrict__ g,
                         const float* __restrict__ bta, float2* __restrict__ st){
  int ch = threadIdx.x;  // 256
  float s=0.f, s2=0.f;
  for (int r=0;r<32;++r){ float2 p = part[r*256 + ch]; s+=p.x; s2+=p.y; }
  float m = s*(1.0f/32768.0f);
  float var = s2*(1.0f/32768.0f) - m*m;
  float sc = g[ch]/sqrtf(var + EPSV);
  st[ch] = make_float2(sc, bta[ch] - m*sc);
}

// ---------------- qkvr: BN fold + resize 64->33, qkvT[b][t][ch] -> qkvrT[b][i][ch] ----------------
// thread = one ch; 64 coalesced loads into regs; weights are wave-uniform float4 loads.
__global__ __launch_bounds__(256) void k_qkvr(const float* __restrict__ qkvT, const float* __restrict__ W64,
                                              const float2* __restrict__ st, float* __restrict__ qkvrT){
  int b = blockIdx.x, ch = threadIdx.x;
  const float* base = qkvT + (size_t)b*16384 + ch;
  float xr[64];
  #pragma unroll
  for (int t=0;t<64;++t) xr[t] = base[t*256];
  float2 sb = st[ch];
  float* ob = qkvrT + (size_t)b*8448 + ch;
  for (int i=0;i<33;++i){
    const float4* wr = (const float4*)(W64 + i*64);   // wave-uniform
    float a = 0.f;
    #pragma unroll
    for (int q=0;q<16;++q){
      float4 w4 = wr[q];
      a += w4.x*xr[4*q] + w4.y*xr[4*q+1] + w4.z*xr[4*q+2] + w4.w*xr[4*q+3];
    }
    ob[i*256] = a*sb.x + sb.y;
  }
}

// ---------------- pos = resize(base_relative, (32,33,33)) separable ----------------
__global__ void k_pos1(const float* __restrict__ base, const float* __restrict__ W127, float* __restrict__ tmp){
  int id = blockIdx.x*256 + threadIdx.x;
  if (id >= 32*33*127) return;
  int c = id / 4191; int r = id - c*4191; int i = r / 127; int xx = r - i*127;
  const float* wr = W127 + i*127;
  const float* bc = base + c*16129 + xx;
  float a=0.f;
  for (int y=0;y<127;++y) a += wr[y]*bc[y*127];
  tmp[id] = a;
}
__global__ void k_pos2(const float* __restrict__ tmp, const float* __restrict__ W127, float* __restrict__ pos){
  int id = blockIdx.x*256 + threadIdx.x;
  if (id >= 32*33*33) return;
  int c = id / 1089; int r = id - c*1089; int i = r / 33; int j = r - i*33;
  const float* wr = W127 + j*127;
  const float* tc = tmp + c*4191 + i*127;
  float a=0.f;
  for (int xx=0;xx<127;++xx) a += wr[xx]*tc[xx];
  pos[id] = a;
}

// ---------------- sim = concat([qk, qr, kr]) for each (b,g) ----------------
__global__ __launch_bounds__(256) void k_sim(const float* __restrict__ qkvrT, const float* __restrict__ pos,
                                             float* __restrict__ sim){
  int b = blockIdx.x, g = blockIdx.y;
  __shared__ float lqa[264], lka[264];  // [8 c][33 i]
  int tid = threadIdx.x;
  for (int e=tid;e<528;e+=256){
    int half = (e < 264) ? 0 : 1;
    int e2 = e - half*264;
    int c = e2/33, i = e2 - c*33;
    float v = qkvrT[(size_t)b*8448 + i*256 + (g*32 + half*8 + c)];
    if (half==0) lqa[e2]=v; else lka[e2]=v;
  }
  __syncthreads();
  for (int p=tid;p<1089;p+=256){
    int i = p/33, j = p - i*33;
    float qk=0.f, qr=0.f, kr=0.f;
    #pragma unroll
    for (int c=0;c<8;++c){
      float qa_ = lqa[c*33+i];
      float ka_ = lka[c*33+j];
      qk += qa_*ka_;
      qr += qa_*pos[c*1089 + i*33 + j];          // q_e = pos[0:8]
      kr += ka_*pos[(8+c)*1089 + j*33 + i];      // k_e = pos[8:16], transposed use
    }
    sim[(b*24 + g)*1089 + p] = qk;
    sim[(b*24 + 8 + g)*1089 + p] = qr;
    sim[(b*24 + 16 + g)*1089 + p] = kr;
  }
}

// ---------------- per-(n, ch24) stats over (W, i, j) ----------------
__global__ __launch_bounds__(256) void k_simstats(const float* __restrict__ sim, const float* __restrict__ g,
                                                  const float* __restrict__ bta, float2* __restrict__ st){
  int nb = blockIdx.x; int n = nb/24, ch = nb - n*24;
  int t = threadIdx.x;
  float s=0.f, s2=0.f;
  for (int e=t; e<64*1089; e+=256){
    int w = e/1089, p = e - w*1089;
    float v = sim[((n*64+w)*24 + ch)*1089 + p];
    s+=v; s2+=v*v;
  }
  __shared__ float rs[256], rq[256];
  rs[t]=s; rq[t]=s2; __syncthreads();
  for (int o=128;o>0;o>>=1){ if(t<o){ rs[t]+=rs[t+o]; rq[t]+=rq[t+o]; } __syncthreads(); }
  if (t==0){
    float m = rs[0]*(1.0f/69696.0f);
    float var = rq[0]*(1.0f/69696.0f) - m*m;
    float sc = g[ch]/sqrtf(var + EPSV);
    st[nb] = make_float2(sc, bta[ch] - m*sc);
  }
}

// ---------------- normalize + sum over the 3 groups ----------------
__global__ void k_simsum(const float* __restrict__ sim, const float2* __restrict__ st, float* __restrict__ ss){
  int id = blockIdx.x*256 + threadIdx.x;      // 512*8*1089
  int b = id / 8712; int r = id - b*8712; int g = r / 1089; int p = r - g*1089;
  int n = b>>6;
  float a = 0.f;
  #pragma unroll
  for (int t3=0;t3<3;++t3){
    float2 sb = st[n*24 + t3*8 + g];
    a += sim[(b*24 + t3*8 + g)*1089 + p]*sb.x + sb.y;
  }
  ss[id] = a;
}

// ---------------- vb: resize va (33) back to 64 along last dim ----------------
__global__ void k_vb(const float* __restrict__ qkvrT, float* __restrict__ vb){
  int id = blockIdx.x*256 + threadIdx.x;      // (b*8+g)*16+c)*64 + j
  int j = id & 63; int r = id >> 6;
  int b = r >> 7; int rem = r & 127; int g = rem >> 4; int c = rem & 15;
  const float* base = qkvrT + (size_t)b*8448 + (g*32 + 16 + c);
  int j0; float f; upfac(j, j0, f);
  vb[id] = (1.f-f)*base[j0*256] + f*base[(j0+1)*256];
}

// ---------------- v_eH: resize v_e (16,33,33) -> (16,64,64) ----------------
__global__ void k_veH(const float* __restrict__ pos, float* __restrict__ veH){
  int id = blockIdx.x*256 + threadIdx.x;  // 16*64*64
  int j = id&63, i=(id>>6)&63, c=id>>12;
  int i0, j0; float fi, fj;
  upfac(i, i0, fi); upfac(j, j0, fj);
  const float* P = pos + (16+c)*1089;
  float v0 = (1.f-fj)*P[i0*33+j0]     + fj*P[i0*33+j0+1];
  float v1 = (1.f-fj)*P[(i0+1)*33+j0] + fj*P[(i0+1)*33+j0+1];
  veH[id] = (1.f-fi)*v0 + fi*v1;
}

// ---------------- fused: upsample sim 33->64 (2D), softmax, sv & sve -> so ----------------
__global__ __launch_bounds__(256) void k_attn(const float* __restrict__ ss, const float* __restrict__ vb,
                                              const float* __restrict__ veH, float* __restrict__ so){
  int wv = threadIdx.x >> 6;
  int i  = threadIdx.x & 63;
  int bg = blockIdx.x*4 + wv;
  int b = bg>>3, g = bg&7;
  __shared__ float  S[4][1092];   // 33x33 simsum tile per wave
  __shared__ float4 V[4][256];    // [16 c][16 q4] vb tile per wave, natively float4
  float* Sw = S[wv];
  const float4* vb4 = (const float4*)(vb + (size_t)bg*1024);   // bg*4096B from 16B-aligned base
  for (int e=i;e<1089;e+=64) Sw[e] = ss[(size_t)bg*1089 + e];
  for (int e=i;e<256;e+=64)  V[wv][e] = vb4[e];
  __syncthreads();

  // phase A: bilinear upsample row i (33->64 both dims) + softmax, in registers
  int i0; float fi; upfac(i, i0, fi);
  const float* R0 = Sw + i0*33;
  const float* R1 = R0 + 33;
  float p[64];
  float mx = -1e30f;
  #pragma unroll
  for (int j=0;j<64;++j){
    int j0; float fj; upfac(j, j0, fj);       // j constant after unroll
    float v0 = (1.f-fj)*R0[j0] + fj*R0[j0+1];
    float v1 = (1.f-fj)*R1[j0] + fj*R1[j0+1];
    float su = (1.f-fi)*v0 + fi*v1;
    p[j] = su;
    mx = fmaxf(mx, su);
  }
  float s = 0.f;
  #pragma unroll
  for (int j=0;j<64;++j){ float e = expf(p[j]-mx); p[j]=e; s+=e; }
  float inv = 1.f/s;

  // phase B: sv (LDS float4 broadcast) and sve (global float4, L2-hit)
  float* ob = so + (size_t)b*16384 + g*2048;   // channel 2*(g*16+c) at offset (g*16+c)*128
  const float4* lv4 = &V[wv][0];
  for (int c=0;c<16;++c){
    float a=0.f;
    #pragma unroll
    for (int q=0;q<16;++q){
      float4 v4 = lv4[c*16+q];
      a += p[4*q]*v4.x + p[4*q+1]*v4.y + p[4*q+2]*v4.z + p[4*q+3]*v4.w;
    }
    ob[c*128 + i] = a*inv;             // sv -> even channel
  }
  const float4* veH4 = (const float4*)veH;     // buffer base is 16B-aligned
  for (int c=0;c<16;++c){
    float a=0.f;
    #pragma unroll
    for (int q=0;q<16;++q){
      float4 v4 = veH4[(c*64 + i)*16 + q];
      a += p[4*q]*v4.x + p[4*q+1]*v4.y + p[4*q+2]*v4.z + p[4*q+3]*v4.w;
    }
    ob[c*128 + 64 + i] = a*inv;        // sve -> odd channel
  }
}

// ---------------- BN(so) + pair-sum + transpose -> o in (N,C,H,W) ----------------
__global__ void k_o(const float* __restrict__ so, const float2* __restrict__ st, float* __restrict__ o){
  int id = blockIdx.x*256 + threadIdx.x;  // ((n*128+oc)*64+h)*64+w
  int w = id&63, h=(id>>6)&63, oc=(id>>12)&127, n=id>>19;
  int b = n*64 + w;
  float2 s0 = st[2*oc], s1 = st[2*oc+1];
  float v0 = so[b*16384 + (2*oc)*64 + h];
  float v1 = so[b*16384 + (2*oc+1)*64 + h];
  o[id] = v0*s0.x + s0.y + v1*s1.x + s1.y;
}

// ---------------- BN stats over [512][256][64] rows (so layout) ----------------
__global__ __launch_bounds__(256) void k_bnstats(const float* __restrict__ src, const float* __restrict__ g,
                                                 const float* __restrict__ bta, float2* __restrict__ st){
  int ch = blockIdx.x, t = threadIdx.x;
  float s=0.f, s2=0.f;
  for (int e=t; e<512*64; e+=256){
    int r=e>>6, l=e&63;
    float v = src[(r*256+ch)*64 + l];
    s+=v; s2+=v*v;
  }
  __shared__ float rs[256], rq[256];
  rs[t]=s; rq[t]=s2; __syncthreads();
  for (int o=128;o>0;o>>=1){ if(t<o){ rs[t]+=rs[t+o]; rq[t]+=rq[t+o]; } __syncthreads(); }
  if (t==0){
    float m = rs[0]*(1.0f/32768.0f);
    float var = rq[0]*(1.0f/32768.0f) - m*m;
    float sc = g[ch]/sqrtf(var + EPSV);
    st[ch] = make_float2(sc, bta[ch] - m*sc);
  }
}

// ---------------- spatial block: shifted-channel construction ----------------
__device__ __forceinline__ float xo_val(const float* __restrict__ o, int n, int c, int h, int w){
  if (c >= 40) return o[((n*128 + c)*64 + h)*64 + w];
  int grp = c / 10;
  int cc = c - grp*10;
  int base = (n*128 + cc)*64;
  if (grp==0) return (w>=2) ? o[(base + h)*64 + (w-2)] : 0.f;      // r
  if (grp==1) return (w<62) ? o[(base + h)*64 + (w+2)] : 0.f;      // l
  if (grp==2) return (h>=2) ? o[(base + (h-2))*64 + w] : 0.f;      // d
  return (h<62) ? o[(base + (h+2))*64 + w] : 0.f;                  // u
}

__global__ __launch_bounds__(256) void k_instats(const float* __restrict__ o, const float* __restrict__ g,
                                                 const float* __restrict__ bta, float2* __restrict__ st){
  int nb = blockIdx.x; int n = nb>>7, c = nb&127;
  int t = threadIdx.x;
  float s=0.f,s2=0.f;
  for (int e=t;e<4096;e+=256){
    int h=e>>6, w=e&63;
    float v = xo_val(o,n,c,h,w);
    s+=v; s2+=v*v;
  }
  __shared__ float rs[256], rq[256];
  rs[t]=s; rq[t]=s2; __syncthreads();
  for (int oo=128;oo>0;oo>>=1){ if(t<oo){ rs[t]+=rs[t+oo]; rq[t]+=rq[t+oo]; } __syncthreads(); }
  if (t==0){
    float m = rs[0]*(1.0f/4096.0f);
    float var = rq[0]*(1.0f/4096.0f) - m*m;
    float sc = g[c]/sqrtf(var + EPSV);
    st[nb] = make_float2(sc, bta[c] - m*sc);
  }
}

__global__ void k_xn(const float* __restrict__ o, const float2* __restrict__ st, float* __restrict__ xn){
  int id = blockIdx.x*256+threadIdx.x;
  int w=id&63,h=(id>>6)&63,c=(id>>12)&127,n=id>>19;
  float2 sb = st[n*128+c];
  xn[id] = xo_val(o,n,c,h,w)*sb.x + sb.y;
}

// ---------------- MLP layer 1: h1 = gelu(w1T^T @ xn), 32hw x 128cout tile ----------------
__global__ __launch_bounds__(256) void k_mlp1(const float* __restrict__ xn, const float* __restrict__ w1T,
                                              float* __restrict__ h1){
  int hw0 = blockIdx.x*32, co0 = blockIdx.y*128, n = blockIdx.z;
  int tid = threadIdx.x;
  int hwt = tid&7, cot = tid>>3;
  __shared__ float4 LH[32][8];    // [kk][hw/4]
  __shared__ float4 LW[32][32];   // [kk][cout/4]
  const float4* xn4  = (const float4*)xn;
  const float4* w1T4 = (const float4*)w1T;
  float4 acc[4];
  #pragma unroll
  for (int j=0;j<4;++j) acc[j] = make_float4(0.f,0.f,0.f,0.f);
  for (int c0=0;c0<128;c0+=32){
    __syncthreads();
    { int kk=tid>>3, q=tid&7;
      LH[kk][q] = xn4[((size_t)(n*128 + c0+kk)*4096 + hw0)/4 + q]; }
    #pragma unroll
    for (int p=0;p<4;++p){
      int e = tid + p*256; int kk=e>>5, q=e&31;
      LW[kk][q] = w1T4[((size_t)(c0+kk)*512 + co0)/4 + q];
    }
    __syncthreads();
    #pragma unroll
    for (int kk=0;kk<32;++kk){
      float4 h = LH[kk][hwt];
      float4 w = LW[kk][cot];
      fma4(acc[0], h, w.x); fma4(acc[1], h, w.y);
      fma4(acc[2], h, w.z); fma4(acc[3], h, w.w);
    }
  }
  float4* h14 = (float4*)h1;
  #pragma unroll
  for (int j=0;j<4;++j){
    int cout = co0 + cot*4 + j;
    float4 v = acc[j];
    v.x = 0.5f*v.x*(1.0f + erff(v.x*0.70710678f));
    v.y = 0.5f*v.y*(1.0f + erff(v.y*0.70710678f));
    v.z = 0.5f*v.z*(1.0f + erff(v.z*0.70710678f));
    v.w = 0.5f*v.w*(1.0f + erff(v.w*0.70710678f));
    h14[((size_t)(n*512 + cout)*4096 + hw0)/4 + hwt] = v;
  }
}

// ---------------- MLP layer 2 + residual: 32hw x 128cout tile, K=512 ----------------
__global__ __launch_bounds__(256) void k_mlp2(const float* __restrict__ h1, const float* __restrict__ w2T,
                                              float* __restrict__ out){
  int hw0 = blockIdx.x*32, n = blockIdx.z;
  int tid = threadIdx.x;
  int hwt = tid&7, cot = tid>>3;
  __shared__ float4 LH[32][8];    // [kk][hw/4]
  __shared__ float4 LW[32][32];   // [kk][cout/4]
  const float4* h14  = (const float4*)h1;
  const float4* w2T4 = (const float4*)w2T;
  float4 acc[4];
  #pragma unroll
  for (int j=0;j<4;++j) acc[j] = make_float4(0.f,0.f,0.f,0.f);
  for (int k0=0;k0<512;k0+=32){
    __syncthreads();
    { int kk=tid>>3, q=tid&7;
      LH[kk][q] = h14[((size_t)(n*512 + k0+kk)*4096 + hw0)/4 + q]; }
    #pragma unroll
    for (int p=0;p<4;++p){
      int e = tid + p*256; int kk=e>>5, q=e&31;
      LW[kk][q] = w2T4[((size_t)(k0+kk)*128)/4 + q];
    }
    __syncthreads();
    #pragma unroll
    for (int kk=0;kk<32;++kk){
      float4 h = LH[kk][hwt];
      float4 w = LW[kk][cot];
      fma4(acc[0], h, w.x); fma4(acc[1], h, w.y);
      fma4(acc[2], h, w.z); fma4(acc[3], h, w.w);
    }
  }
  float4* out4 = (float4*)out;
  #pragma unroll
  for (int j=0;j<4;++j){
    int c = cot*4 + j;
    size_t idx = ((size_t)(n*128 + c)*4096 + hw0)/4 + hwt;
    float4 prev = out4[idx];
    prev.x += acc[j].x; prev.y += acc[j].y; prev.z += acc[j].z; prev.w += acc[j].w;
    out4[idx] = prev;    // residual: same-thread read-then-write
  }
}

extern "C" void kernel_launch(void* const* d_in, const int* in_sizes, int n_in,
                              void* d_out, int out_size, void* d_ws, size_t ws_size,
                              hipStream_t stream) {
  (void)in_sizes; (void)n_in; (void)out_size; (void)ws_size;
  const float* x       = (const float*)d_in[0];
  const float* qkvw    = (const float*)d_in[1];
  const float* bng     = (const float*)d_in[2];
  const float* bnb     = (const float*)d_in[3];
  const float* baserel = (const float*)d_in[4];
  const float* simg    = (const float*)d_in[5];
  const float* simb    = (const float*)d_in[6];
  const float* outg    = (const float*)d_in[7];
  const float* outb    = (const float*)d_in[8];
  const float* ing     = (const float*)d_in[9];
  const float* inb     = (const float*)d_in[10];
  const float* w1      = (const float*)d_in[11];
  const float* w2      = (const float*)d_in[12];

  float* ws = (float*)d_ws;
  float*  W127  = ws + F_W127;
  float*  W64   = ws + F_W64;
  float2* qkvst = (float2*)(ws + F_QKVST);
  float2* simst = (float2*)(ws + F_SIMST);
  float2* sost  = (float2*)(ws + F_SOST);
  float2* inst  = (float2*)(ws + F_INST);
  float*  postmp= ws + F_POSTMP;
  float*  pos   = ws + F_POS;
  float*  qkvT  = ws + F_QKV;
  float*  qkvrT = ws + F_QKVR;
  float*  sim   = ws + F_SIM;
  float*  ssum  = ws + F_SIMSUM;
  float*  vb    = ws + F_VB;
  float*  veH   = ws + F_VEH;
  float*  so    = ws + F_SO;     // aliases qkvT (dead)
  float*  xp    = ws + F_XP;     // aliases sim (dead until k_sim)
  float2* bnp   = (float2*)(ws + F_BNP);  // aliases xp (dead after k_qkv)
  float*  xn    = ws + F_XN;     // aliases sim (dead)
  float*  h1    = ws + F_H1;     // aliases sim tail + simsum + vb (dead)
  float*  wT    = ws + F_WT;     // aliases pos (dead until k_pos2)
  float*  w1T   = ws + F_W1T;    // aliases postmp (dead after k_pos2)
  float*  w2T   = ws + F_W2T;
  float*  out   = (float*)d_out;

  k_tables  <<<dim3(1),        dim3(128), 0, stream>>>(W127, W64);
  k_tr      <<<dim3(8,4),      dim3(256), 0, stream>>>(qkvw, wT, 256, 128);  // wT[c][o]
  k_xt      <<<dim3(1024),     dim3(256), 0, stream>>>(x, xp);
  k_qkv     <<<dim3(512,4),    dim3(256), 0, stream>>>(xp, wT, qkvT);
  k_bnsum   <<<dim3(4,32),     dim3(256), 0, stream>>>(qkvT, bnp);
  k_stats2  <<<dim3(1),        dim3(256), 0, stream>>>(bnp, bng, bnb, qkvst);
  k_qkvr    <<<dim3(512),      dim3(256), 0, stream>>>(qkvT, W64, qkvst, qkvrT);
  k_pos1    <<<dim3(524),      dim3(256), 0, stream>>>(baserel, W127, postmp);
  k_pos2    <<<dim3(137),      dim3(256), 0, stream>>>(postmp, W127, pos);
  k_tr      <<<dim3(16,4),     dim3(256), 0, stream>>>(w1, w1T, 512, 128);   // w1T[c][o512]
  k_tr      <<<dim3(4,16),     dim3(256), 0, stream>>>(w2, w2T, 128, 512);   // w2T[k][c128]
  k_sim     <<<dim3(512,8),    dim3(256), 0, stream>>>(qkvrT, pos, sim);
  k_simstats<<<dim3(192),      dim3(256), 0, stream>>>(sim, simg, simb, simst);
  k_simsum  <<<dim3(17424),    dim3(256), 0, stream>>>(sim, simst, ssum);
  k_vb      <<<dim3(16384),    dim3(256), 0, stream>>>(qkvrT, vb);
  k_veH     <<<dim3(256),      dim3(256), 0, stream>>>(pos, veH);
  k_attn    <<<dim3(1024),     dim3(256), 0, stream>>>(ssum, vb, veH, so);
  k_bnstats <<<dim3(256),      dim3(256), 0, stream>>>(so, outg, outb, sost);
  k_o       <<<dim3(16384),    dim3(256), 0, stream>>>(so, sost, out);
  k_instats <<<dim3(1024),     dim3(256), 0, stream>>>(out, ing, inb, inst);
  k_xn      <<<dim3(16384),    dim3(256), 0, stream>>>(out, inst, xn);
  k_mlp1    <<<dim3(128,4,8),  dim3(256), 0, stream>>>(xn, w1T, h1);
  k_mlp2    <<<dim3(128,1,8),  dim3(256), 0, stream>>>(h1, w2T, out);
}

// Round 6
// 731.812 us; speedup vs baseline: 1.5349x; 1.0514x over previous
//
#include <hip/hip_runtime.h>
#include <math.h>

// Problem constants: N=8, C=128, H=64, W=64, B=N*W=512, ADJ=33, G=8, GP=16
constexpr float EPSV = 1e-5f;

// ---------------- workspace layout (offsets in floats) ----------------
constexpr size_t F_W127  = 0;                      // 33*127 = 4191 (padded 4224)
constexpr size_t F_W64   = F_W127 + 4224;          // 33*64 = 2112
constexpr size_t F_QKVST = F_W64  + 2112;          // float2[256] -> 512 floats
constexpr size_t F_SIMST = F_QKVST+ 512;           // float2[192] -> 384
constexpr size_t F_SOST  = F_SIMST+ 384;           // float2[256] -> 512
constexpr size_t F_INST  = F_SOST + 512;           // float2[1024]-> 2048
constexpr size_t F_POSTMP= F_INST + 2048;          // 32*33*127 = 134112 (alias: w1T+w2T after pos2)
constexpr size_t F_POS   = F_POSTMP + 134112;      // 32*33*33 = 34848 (alias: wT before pos2)
constexpr size_t F_QKV   = F_POS  + 34848;         // qkvT [512][64][256] = 8388608 (alias: SO)
constexpr size_t F_QKVR  = F_QKV  + 8388608;       // qkvrT [512][33][256] = 4325376
constexpr size_t F_SIM   = F_QKVR + 4325376;       // 512*24*1089 = 13381632 (alias: XP early, BNP, XN/H1 late)
constexpr size_t F_SIMSUM= F_SIM  + 13381632;      // 512*8*1089 = 4460544
constexpr size_t F_VB    = F_SIMSUM + 4460544;     // (free - vb eliminated)
constexpr size_t F_VEH   = F_VB   + 4194304;       // VeLT 16*33*64 = 33792
constexpr size_t F_SO    = F_QKV;                  // qkvT dead after k_qkvr
constexpr size_t F_XP    = F_SIM;                  // xp (4194304) dead after k_qkv
constexpr size_t F_BNP   = F_SIM;                  // bn partials (32*256 float2), after xp dead
constexpr size_t F_XN    = F_SIM;                  // sim dead after k_simsum
constexpr size_t F_H1    = F_SIM + 4194304;        // 16777216 floats; spans dead sim/simsum/vb
constexpr size_t F_WT    = F_POS;                  // qkv_w^T (32768) dead before k_pos2
constexpr size_t F_W1T   = F_POSTMP;               // 65536, written after pos2 (postmp dead)
constexpr size_t F_W2T   = F_POSTMP + 65536;       // 65536 (131072 <= 134112)

__device__ __forceinline__ void fma4(float4& a, const float4& h, float s){
  a.x += h.x*s; a.y += h.y*s; a.z += h.z*s; a.w += h.w*s;
}

// ---------------- resize weight tables (jax.image.resize, antialias=True) ----------------
__global__ void k_tables(float* __restrict__ W127, float* __restrict__ W64){
  int i = threadIdx.x;
  if (i < 33){
    const float inv = 127.0f/33.0f;          // kernel_scale for downsample (antialias)
    float x = ((float)i + 0.5f)*inv - 0.5f;  // half-pixel sample position
    float s = 0.f;
    for (int j=0;j<127;++j){ float w = 1.0f - fabsf((float)j - x)/inv; w = fmaxf(w,0.f); W127[i*127+j]=w; s+=w; }
    float r = 1.0f/s;
    for (int j=0;j<127;++j) W127[i*127+j] *= r;
  } else if (i < 66){
    int ii = i-33;
    const float inv = 64.0f/33.0f;
    float x = ((float)ii + 0.5f)*inv - 0.5f;
    float s=0.f;
    for (int j=0;j<64;++j){ float w = 1.0f - fabsf((float)j - x)/inv; w=fmaxf(w,0.f); W64[ii*64+j]=w; s+=w; }
    float r=1.0f/s;
    for (int j=0;j<64;++j) W64[ii*64+j]*=r;
  }
}

// up-sample 33->64: clamp + 2-tap lerp (matches jax normalized edge weights)
__device__ __forceinline__ void upfac(int o, int& j0, float& f){
  float x = ((float)o + 0.5f)*0.515625f - 0.5f;   // 33/64 = 0.515625 exact
  x = fminf(fmaxf(x, 0.f), 32.f);
  int j = (int)x; j = j < 31 ? j : 31;
  j0 = j; f = x - (float)j;
}

// ---------------- generic 32x32-tiled transpose: dst[c*R+r] = src[r*C+c] ----------------
__global__ __launch_bounds__(256) void k_tr(const float* __restrict__ src, float* __restrict__ dst,
                                            int R, int C){
  __shared__ float T[32][33];
  int r0 = blockIdx.x*32, c0 = blockIdx.y*32;
  int tx = threadIdx.x&31, ty = threadIdx.x>>5;  // 32 x 8
  #pragma unroll
  for (int q=0;q<4;++q){ int r = ty + q*8; T[r][tx] = src[(r0+r)*C + c0+tx]; }
  __syncthreads();
  #pragma unroll
  for (int q=0;q<4;++q){ int c = ty + q*8; dst[(c0+c)*R + r0+tx] = T[tx][c]; }
}

// ---------------- x (N,C,H,W) -> xp (N*W, C, H): per-(n,c) 64x64 transpose ----------------
__global__ __launch_bounds__(256) void k_xt(const float* __restrict__ x, float* __restrict__ xp){
  __shared__ float T[64][65];
  int n = blockIdx.x>>7, c = blockIdx.x&127;
  const float* src = x + ((size_t)(n*128 + c))*4096;
  int tid = threadIdx.x;
  for (int e=tid;e<4096;e+=256){ int h=e>>6, w=e&63; T[h][w] = src[e]; }  // lanes along w: coalesced
  __syncthreads();
  for (int e=tid;e<4096;e+=256){
    int w=e>>6, h=e&63;                       // lanes along h: coalesced writes
    xp[((size_t)((n*64+w)*128 + c))*64 + h] = T[h][w];
  }
}

// ---------------- QKV projection GEMM -> TRANSPOSED out: qkvT[b][l][o] ----------------
// per-thread 4l x 4o tile (float4 across o so stores are o-contiguous/coalesced)
__global__ __launch_bounds__(256) void k_qkv(const float* __restrict__ xp, const float* __restrict__ wT,
                                             float* __restrict__ qkvT){
  int b = blockIdx.x, o0 = blockIdx.y*64;
  int tid = threadIdx.x;
  int ot = tid&15, lt = tid>>4;
  __shared__ float4 LX[32][16];   // [kk][l/4]
  __shared__ float4 LW[32][16];   // [kk][o/4]
  const float4* xp4 = (const float4*)xp;
  const float4* wT4 = (const float4*)wT;
  float4 acc[4];                  // acc[j] = l=lt*4+j, float4 across o
  #pragma unroll
  for (int j=0;j<4;++j) acc[j] = make_float4(0.f,0.f,0.f,0.f);
  for (int c0=0;c0<128;c0+=32){
    __syncthreads();
    #pragma unroll
    for (int p=0;p<2;++p){
      int e = tid + p*256; int kk=e>>4, q=e&15;
      LX[kk][q] = xp4[(size_t)b*2048 + (c0+kk)*16 + q];
      LW[kk][q] = wT4[(c0+kk)*64 + (o0>>2) + q];
    }
    __syncthreads();
    #pragma unroll
    for (int kk=0;kk<32;++kk){
      float4 x4 = LX[kk][lt];
      float4 w4 = LW[kk][ot];
      fma4(acc[0], w4, x4.x); fma4(acc[1], w4, x4.y);
      fma4(acc[2], w4, x4.z); fma4(acc[3], w4, x4.w);
    }
  }
  float4* qkvT4 = (float4*)qkvT;
  #pragma unroll
  for (int j=0;j<4;++j)
    qkvT4[((size_t)b*16384 + (lt*4+j)*256 + o0 + ot*4)>>2] = acc[j];
}

// ---------------- BN partial sums over rows of qkvT [32768 rows][256 ch] ----------------
__global__ __launch_bounds__(256) void k_bnsum(const float* __restrict__ qkvT, float2* __restrict__ part){
  int chG = blockIdx.x, rowG = blockIdx.y;
  int cl = threadIdx.x&63;
  int ch = chG*64 + cl;
  int rs = threadIdx.x>>6;  // 0..3
  float s=0.f, s2=0.f;
  for (int r = rowG*1024 + rs; r < rowG*1024 + 1024; r += 4){
    float v = qkvT[(size_t)r*256 + ch]; s+=v; s2+=v*v;
  }
  __shared__ float S1[4][64], S2[4][64];
  S1[rs][cl]=s; S2[rs][cl]=s2; __syncthreads();
  if (rs==0){
    s  = S1[0][cl]+S1[1][cl]+S1[2][cl]+S1[3][cl];
    s2 = S2[0][cl]+S2[1][cl]+S2[2][cl]+S2[3][cl];
    part[rowG*256 + ch] = make_float2(s, s2);
  }
}
__global__ void k_stats2(const float2* __restrict__ part, const float* __restrict__ g,
                         const float* __restrict__ bta, float2* __restrict__ st){
  int ch = threadIdx.x;  // 256
  float s=0.f, s2=0.f;
  for (int r=0;r<32;++r){ float2 p = part[r*256 + ch]; s+=p.x; s2+=p.y; }
  float m = s*(1.0f/32768.0f);
  float var = s2*(1.0f/32768.0f) - m*m;
  float sc = g[ch]/sqrtf(var + EPSV);
  st[ch] = make_float2(sc, bta[ch] - m*sc);
}

// ---------------- qkvr: BN fold + resize 64->33, qkvT[b][t][ch] -> qkvrT[b][i][ch] ----------------
__global__ __launch_bounds__(256) void k_qkvr(const float* __restrict__ qkvT, const float* __restrict__ W64,
                                              const float2* __restrict__ st, float* __restrict__ qkvrT){
  int b = blockIdx.x, ch = threadIdx.x;
  const float* base = qkvT + (size_t)b*16384 + ch;
  float xr[64];
  #pragma unroll
  for (int t=0;t<64;++t) xr[t] = base[t*256];
  float2 sb = st[ch];
  float* ob = qkvrT + (size_t)b*8448 + ch;
  for (int i=0;i<33;++i){
    const float4* wr = (const float4*)(W64 + i*64);   // wave-uniform
    float a = 0.f;
    #pragma unroll
    for (int q=0;q<16;++q){
      float4 w4 = wr[q];
      a += w4.x*xr[4*q] + w4.y*xr[4*q+1] + w4.z*xr[4*q+2] + w4.w*xr[4*q+3];
    }
    ob[i*256] = a*sb.x + sb.y;
  }
}

// ---------------- pos = resize(base_relative, (32,33,33)) separable ----------------
__global__ void k_pos1(const float* __restrict__ base, const float* __restrict__ W127, float* __restrict__ tmp){
  int id = blockIdx.x*256 + threadIdx.x;
  if (id >= 32*33*127) return;
  int c = id / 4191; int r = id - c*4191; int i = r / 127; int xx = r - i*127;
  const float* wr = W127 + i*127;
  const float* bc = base + c*16129 + xx;
  float a=0.f;
  for (int y=0;y<127;++y) a += wr[y]*bc[y*127];
  tmp[id] = a;
}
__global__ void k_pos2(const float* __restrict__ tmp, const float* __restrict__ W127, float* __restrict__ pos){
  int id = blockIdx.x*256 + threadIdx.x;
  if (id >= 32*33*33) return;
  int c = id / 1089; int r = id - c*1089; int i = r / 33; int j = r - i*33;
  const float* wr = W127 + j*127;
  const float* tc = tmp + c*4191 + i*127;
  float a=0.f;
  for (int xx=0;xx<127;++xx) a += wr[xx]*tc[xx];
  pos[id] = a;
}

// ---------------- sim = concat([qk, qr, kr]) for each (b,g) ----------------
__global__ __launch_bounds__(256) void k_sim(const float* __restrict__ qkvrT, const float* __restrict__ pos,
                                             float* __restrict__ sim){
  int b = blockIdx.x, g = blockIdx.y;
  __shared__ float lqa[264], lka[264];  // [8 c][33 i]
  int tid = threadIdx.x;
  for (int e=tid;e<528;e+=256){
    int half = (e < 264) ? 0 : 1;
    int e2 = e - half*264;
    int c = e2/33, i = e2 - c*33;
    float v = qkvrT[(size_t)b*8448 + i*256 + (g*32 + half*8 + c)];
    if (half==0) lqa[e2]=v; else lka[e2]=v;
  }
  __syncthreads();
  for (int p=tid;p<1089;p+=256){
    int i = p/33, j = p - i*33;
    float qk=0.f, qr=0.f, kr=0.f;
    #pragma unroll
    for (int c=0;c<8;++c){
      float qa_ = lqa[c*33+i];
      float ka_ = lka[c*33+j];
      qk += qa_*ka_;
      qr += qa_*pos[c*1089 + i*33 + j];          // q_e = pos[0:8]
      kr += ka_*pos[(8+c)*1089 + j*33 + i];      // k_e = pos[8:16], transposed use
    }
    sim[(b*24 + g)*1089 + p] = qk;
    sim[(b*24 + 8 + g)*1089 + p] = qr;
    sim[(b*24 + 16 + g)*1089 + p] = kr;
  }
}

// ---------------- per-(n, ch24) stats over (W, i, j) ----------------
__global__ __launch_bounds__(256) void k_simstats(const float* __restrict__ sim, const float* __restrict__ g,
                                                  const float* __restrict__ bta, float2* __restrict__ st){
  int nb = blockIdx.x; int n = nb/24, ch = nb - n*24;
  int t = threadIdx.x;
  float s=0.f, s2=0.f;
  for (int e=t; e<64*1089; e+=256){
    int w = e/1089, p = e - w*1089;
    float v = sim[((n*64+w)*24 + ch)*1089 + p];
    s+=v; s2+=v*v;
  }
  __shared__ float rs[256], rq[256];
  rs[t]=s; rq[t]=s2; __syncthreads();
  for (int o=128;o>0;o>>=1){ if(t<o){ rs[t]+=rs[t+o]; rq[t]+=rq[t+o]; } __syncthreads(); }
  if (t==0){
    float m = rs[0]*(1.0f/69696.0f);
    float var = rq[0]*(1.0f/69696.0f) - m*m;
    float sc = g[ch]/sqrtf(var + EPSV);
    st[nb] = make_float2(sc, bta[ch] - m*sc);
  }
}

// ---------------- normalize + sum over the 3 groups ----------------
__global__ void k_simsum(const float* __restrict__ sim, const float2* __restrict__ st, float* __restrict__ ss){
  int id = blockIdx.x*256 + threadIdx.x;      // 512*8*1089
  int b = id / 8712; int r = id - b*8712; int g = r / 1089; int p = r - g*1089;
  int n = b>>6;
  float a = 0.f;
  #pragma unroll
  for (int t3=0;t3<3;++t3){
    float2 sb = st[n*24 + t3*8 + g];
    a += sim[(b*24 + t3*8 + g)*1089 + p]*sb.x + sb.y;
  }
  ss[id] = a;
}

// ---------------- VeLT[c][j33][i] = i-lerped v_e rows (j stays 33-wide) ----------------
__global__ void k_veL(const float* __restrict__ pos, float* __restrict__ VeLT){
  int id = blockIdx.x*256 + threadIdx.x;  // 16*33*64
  if (id >= 33792) return;
  int i = id&63; int r = id>>6; int c = r/33; int j = r - c*33;
  int i0; float fi; upfac(i, i0, fi);
  const float* P = pos + (16+c)*1089;
  VeLT[id] = (1.f-fi)*P[i0*33 + j] + fi*P[(i0+1)*33 + j];
}

// ---------------- fused attention: upsample+softmax folded to Pc[33], sv & sve ----------------
// sv[c][i]  = dot33(Pc[i], va[c])      (va = 33-wide V slice of qkvrT, staged in LDS [j][c])
// sve[c][i] = dot33(Pc[i], VeLT[c][:,i]) (global, i-contiguous -> fully coalesced, L2-resident)
__global__ __launch_bounds__(256) void k_attn(const float* __restrict__ ss, const float* __restrict__ qkvrT,
                                              const float* __restrict__ VeLT, float* __restrict__ so){
  int wv = threadIdx.x >> 6;
  int i  = threadIdx.x & 63;
  int bg = blockIdx.x*4 + wv;
  int b = bg>>3, g = bg&7;
  __shared__ float  S[4][1092];   // 33x33 simsum tile per wave
  __shared__ float4 Va[4][136];   // [j33][c/4] va tile per wave
  float* Sw = S[wv];
  for (int e=i;e<1089;e+=64) Sw[e] = ss[(size_t)bg*1089 + e];
  for (int e=i;e<132;e+=64){
    int j = e>>2, cq = e&3;
    Va[wv][e] = *(const float4*)(qkvrT + (size_t)b*8448 + j*256 + g*32 + 16 + cq*4);
  }
  __syncthreads();

  // phase A: two-pass softmax over the 64-wide upsampled row, folded into Pc[33]
  int i0; float fi; upfac(i, i0, fi);
  const float* R0 = Sw + i0*33;
  const float* R1 = R0 + 33;
  float mx = -1e30f;
  #pragma unroll
  for (int j=0;j<64;++j){
    int j0; float fj; upfac(j, j0, fj);       // constants after unroll
    float v0 = (1.f-fj)*R0[j0] + fj*R0[j0+1];
    float v1 = (1.f-fj)*R1[j0] + fj*R1[j0+1];
    mx = fmaxf(mx, (1.f-fi)*v0 + fi*v1);
  }
  float Pc[33];
  #pragma unroll
  for (int k=0;k<33;++k) Pc[k]=0.f;
  float s = 0.f;
  #pragma unroll
  for (int j=0;j<64;++j){
    int j0; float fj; upfac(j, j0, fj);
    float v0 = (1.f-fj)*R0[j0] + fj*R0[j0+1];
    float v1 = (1.f-fj)*R1[j0] + fj*R1[j0+1];
    float e = expf((1.f-fi)*v0 + fi*v1 - mx);
    s += e;
    Pc[j0]   += e*(1.f-fj);
    Pc[j0+1] += e*fj;
  }
  float inv = 1.f/s;
  #pragma unroll
  for (int k=0;k<33;++k) Pc[k] *= inv;

  // phase B1: sv via LDS float4 broadcasts (4 ds_read_b128 + 16 FMA per j)
  float acc[16];
  #pragma unroll
  for (int c=0;c<16;++c) acc[c]=0.f;
  #pragma unroll
  for (int j=0;j<33;++j){
    float pc = Pc[j];
    float4 a0 = Va[wv][j*4+0], a1 = Va[wv][j*4+1], a2 = Va[wv][j*4+2], a3 = Va[wv][j*4+3];
    acc[0] += pc*a0.x; acc[1] += pc*a0.y; acc[2]  += pc*a0.z; acc[3]  += pc*a0.w;
    acc[4] += pc*a1.x; acc[5] += pc*a1.y; acc[6]  += pc*a1.z; acc[7]  += pc*a1.w;
    acc[8] += pc*a2.x; acc[9] += pc*a2.y; acc[10] += pc*a2.z; acc[11] += pc*a2.w;
    acc[12]+= pc*a3.x; acc[13]+= pc*a3.y; acc[14] += pc*a3.z; acc[15] += pc*a3.w;
  }
  float* ob = so + (size_t)b*16384 + g*2048;   // channel 2*(g*16+c) at offset (g*16+c)*128
  #pragma unroll
  for (int c=0;c<16;++c) ob[c*128 + i] = acc[c];   // sv -> even channel

  // phase B2: sve via coalesced global loads of VeLT (L2-resident, lane-contiguous)
  #pragma unroll
  for (int c=0;c<16;++c) acc[c]=0.f;
  #pragma unroll
  for (int j=0;j<33;++j){
    float pc = Pc[j];
    const float* vr = VeLT + j*64 + i;
    #pragma unroll
    for (int c=0;c<16;++c) acc[c] += pc * vr[c*2112];
  }
  #pragma unroll
  for (int c=0;c<16;++c) ob[c*128 + 64 + i] = acc[c];  // sve -> odd channel
}

// ---------------- BN(so) + pair-sum + transpose -> o in (N,C,H,W) ----------------
__global__ void k_o(const float* __restrict__ so, const float2* __restrict__ st, float* __restrict__ o){
  int id = blockIdx.x*256 + threadIdx.x;  // ((n*128+oc)*64+h)*64+w
  int w = id&63, h=(id>>6)&63, oc=(id>>12)&127, n=id>>19;
  int b = n*64 + w;
  float2 s0 = st[2*oc], s1 = st[2*oc+1];
  float v0 = so[b*16384 + (2*oc)*64 + h];
  float v1 = so[b*16384 + (2*oc+1)*64 + h];
  o[id] = v0*s0.x + s0.y + v1*s1.x + s1.y;
}

// ---------------- BN stats over [512][256][64] rows (so layout) ----------------
__global__ __launch_bounds__(256) void k_bnstats(const float* __restrict__ src, const float* __restrict__ g,
                                                 const float* __restrict__ bta, float2* __restrict__ st){
  int ch = blockIdx.x, t = threadIdx.x;
  float s=0.f, s2=0.f;
  for (int e=t; e<512*64; e+=256){
    int r=e>>6, l=e&63;
    float v = src[(r*256+ch)*64 + l];
    s+=v; s2+=v*v;
  }
  __shared__ float rs[256], rq[256];
  rs[t]=s; rq[t]=s2; __syncthreads();
  for (int o=128;o>0;o>>=1){ if(t<o){ rs[t]+=rs[t+o]; rq[t]+=rq[t+o]; } __syncthreads(); }
  if (t==0){
    float m = rs[0]*(1.0f/32768.0f);
    float var = rq[0]*(1.0f/32768.0f) - m*m;
    float sc = g[ch]/sqrtf(var + EPSV);
    st[ch] = make_float2(sc, bta[ch] - m*sc);
  }
}

// ---------------- spatial block: shifted-channel construction ----------------
__device__ __forceinline__ float xo_val(const float* __restrict__ o, int n, int c, int h, int w){
  if (c >= 40) return o[((n*128 + c)*64 + h)*64 + w];
  int grp = c / 10;
  int cc = c - grp*10;
  int base = (n*128 + cc)*64;
  if (grp==0) return (w>=2) ? o[(base + h)*64 + (w-2)] : 0.f;      // r
  if (grp==1) return (w<62) ? o[(base + h)*64 + (w+2)] : 0.f;      // l
  if (grp==2) return (h>=2) ? o[(base + (h-2))*64 + w] : 0.f;      // d
  return (h<62) ? o[(base + (h+2))*64 + w] : 0.f;                  // u
}

__global__ __launch_bounds__(256) void k_instats(const float* __restrict__ o, const float* __restrict__ g,
                                                 const float* __restrict__ bta, float2* __restrict__ st){
  int nb = blockIdx.x; int n = nb>>7, c = nb&127;
  int t = threadIdx.x;
  float s=0.f,s2=0.f;
  for (int e=t;e<4096;e+=256){
    int h=e>>6, w=e&63;
    float v = xo_val(o,n,c,h,w);
    s+=v; s2+=v*v;
  }
  __shared__ float rs[256], rq[256];
  rs[t]=s; rq[t]=s2; __syncthreads();
  for (int oo=128;oo>0;oo>>=1){ if(t<oo){ rs[t]+=rs[t+oo]; rq[t]+=rq[t+oo]; } __syncthreads(); }
  if (t==0){
    float m = rs[0]*(1.0f/4096.0f);
    float var = rq[0]*(1.0f/4096.0f) - m*m;
    float sc = g[c]/sqrtf(var + EPSV);
    st[nb] = make_float2(sc, bta[c] - m*sc);
  }
}

__global__ void k_xn(const float* __restrict__ o, const float2* __restrict__ st, float* __restrict__ xn){
  int id = blockIdx.x*256+threadIdx.x;
  int w=id&63,h=(id>>6)&63,c=(id>>12)&127,n=id>>19;
  float2 sb = st[n*128+c];
  xn[id] = xo_val(o,n,c,h,w)*sb.x + sb.y;
}

// ---------------- MLP layer 1: h1 = gelu(w1T^T @ xn), 32hw x 128cout tile ----------------
__global__ __launch_bounds__(256) void k_mlp1(const float* __restrict__ xn, const float* __restrict__ w1T,
                                              float* __restrict__ h1){
  int hw0 = blockIdx.x*32, co0 = blockIdx.y*128, n = blockIdx.z;
  int tid = threadIdx.x;
  int hwt = tid&7, cot = tid>>3;
  __shared__ float4 LH[32][8];    // [kk][hw/4]
  __shared__ float4 LW[32][32];   // [kk][cout/4]
  const float4* xn4  = (const float4*)xn;
  const float4* w1T4 = (const float4*)w1T;
  float4 acc[4];
  #pragma unroll
  for (int j=0;j<4;++j) acc[j] = make_float4(0.f,0.f,0.f,0.f);
  for (int c0=0;c0<128;c0+=32){
    __syncthreads();
    { int kk=tid>>3, q=tid&7;
      LH[kk][q] = xn4[((size_t)(n*128 + c0+kk)*4096 + hw0)/4 + q]; }
    #pragma unroll
    for (int p=0;p<4;++p){
      int e = tid + p*256; int kk=e>>5, q=e&31;
      LW[kk][q] = w1T4[((size_t)(c0+kk)*512 + co0)/4 + q];
    }
    __syncthreads();
    #pragma unroll
    for (int kk=0;kk<32;++kk){
      float4 h = LH[kk][hwt];
      float4 w = LW[kk][cot];
      fma4(acc[0], h, w.x); fma4(acc[1], h, w.y);
      fma4(acc[2], h, w.z); fma4(acc[3], h, w.w);
    }
  }
  float4* h14 = (float4*)h1;
  #pragma unroll
  for (int j=0;j<4;++j){
    int cout = co0 + cot*4 + j;
    float4 v = acc[j];
    v.x = 0.5f*v.x*(1.0f + erff(v.x*0.70710678f));
    v.y = 0.5f*v.y*(1.0f + erff(v.y*0.70710678f));
    v.z = 0.5f*v.z*(1.0f + erff(v.z*0.70710678f));
    v.w = 0.5f*v.w*(1.0f + erff(v.w*0.70710678f));
    h14[((size_t)(n*512 + cout)*4096 + hw0)/4 + hwt] = v;
  }
}

// ---------------- MLP layer 2 + residual: 32hw x 128cout tile, K=512 ----------------
__global__ __launch_bounds__(256) void k_mlp2(const float* __restrict__ h1, const float* __restrict__ w2T,
                                              float* __restrict__ out){
  int hw0 = blockIdx.x*32, n = blockIdx.z;
  int tid = threadIdx.x;
  int hwt = tid&7, cot = tid>>3;
  __shared__ float4 LH[32][8];    // [kk][hw/4]
  __shared__ float4 LW[32][32];   // [kk][cout/4]
  const float4* h14  = (const float4*)h1;
  const float4* w2T4 = (const float4*)w2T;
  float4 acc[4];
  #pragma unroll
  for (int j=0;j<4;++j) acc[j] = make_float4(0.f,0.f,0.f,0.f);
  for (int k0=0;k0<512;k0+=32){
    __syncthreads();
    { int kk=tid>>3, q=tid&7;
      LH[kk][q] = h14[((size_t)(n*512 + k0+kk)*4096 + hw0)/4 + q]; }
    #pragma unroll
    for (int p=0;p<4;++p){
      int e = tid + p*256; int kk=e>>5, q=e&31;
      LW[kk][q] = w2T4[((size_t)(k0+kk)*128)/4 + q];
    }
    __syncthreads();
    #pragma unroll
    for (int kk=0;kk<32;++kk){
      float4 h = LH[kk][hwt];
      float4 w = LW[kk][cot];
      fma4(acc[0], h, w.x); fma4(acc[1], h, w.y);
      fma4(acc[2], h, w.z); fma4(acc[3], h, w.w);
    }
  }
  float4* out4 = (float4*)out;
  #pragma unroll
  for (int j=0;j<4;++j){
    int c = cot*4 + j;
    size_t idx = ((size_t)(n*128 + c)*4096 + hw0)/4 + hwt;
    float4 prev = out4[idx];
    prev.x += acc[j].x; prev.y += acc[j].y; prev.z += acc[j].z; prev.w += acc[j].w;
    out4[idx] = prev;    // residual: same-thread read-then-write
  }
}

extern "C" void kernel_launch(void* const* d_in, const int* in_sizes, int n_in,
                              void* d_out, int out_size, void* d_ws, size_t ws_size,
                              hipStream_t stream) {
  (void)in_sizes; (void)n_in; (void)out_size; (void)ws_size;
  const float* x       = (const float*)d_in[0];
  const float* qkvw    = (const float*)d_in[1];
  const float* bng     = (const float*)d_in[2];
  const float* bnb     = (const float*)d_in[3];
  const float* baserel = (const float*)d_in[4];
  const float* simg    = (const float*)d_in[5];
  const float* simb    = (const float*)d_in[6];
  const float* outg    = (const float*)d_in[7];
  const float* outb    = (const float*)d_in[8];
  const float* ing     = (const float*)d_in[9];
  const float* inb     = (const float*)d_in[10];
  const float* w1      = (const float*)d_in[11];
  const float* w2      = (const float*)d_in[12];

  float* ws = (float*)d_ws;
  float*  W127  = ws + F_W127;
  float*  W64   = ws + F_W64;
  float2* qkvst = (float2*)(ws + F_QKVST);
  float2* simst = (float2*)(ws + F_SIMST);
  float2* sost  = (float2*)(ws + F_SOST);
  float2* inst  = (float2*)(ws + F_INST);
  float*  postmp= ws + F_POSTMP;
  float*  pos   = ws + F_POS;
  float*  qkvT  = ws + F_QKV;
  float*  qkvrT = ws + F_QKVR;
  float*  sim   = ws + F_SIM;
  float*  ssum  = ws + F_SIMSUM;
  float*  veLT  = ws + F_VEH;
  float*  so    = ws + F_SO;     // aliases qkvT (dead)
  float*  xp    = ws + F_XP;     // aliases sim (dead until k_sim)
  float2* bnp   = (float2*)(ws + F_BNP);  // aliases xp (dead after k_qkv)
  float*  xn    = ws + F_XN;     // aliases sim (dead)
  float*  h1    = ws + F_H1;     // aliases sim tail + simsum + vb (dead)
  float*  wT    = ws + F_WT;     // aliases pos (dead until k_pos2)
  float*  w1T   = ws + F_W1T;    // aliases postmp (dead after k_pos2)
  float*  w2T   = ws + F_W2T;
  float*  out   = (float*)d_out;

  k_tables  <<<dim3(1),        dim3(128), 0, stream>>>(W127, W64);
  k_tr      <<<dim3(8,4),      dim3(256), 0, stream>>>(qkvw, wT, 256, 128);  // wT[c][o]
  k_xt      <<<dim3(1024),     dim3(256), 0, stream>>>(x, xp);
  k_qkv     <<<dim3(512,4),    dim3(256), 0, stream>>>(xp, wT, qkvT);
  k_bnsum   <<<dim3(4,32),     dim3(256), 0, stream>>>(qkvT, bnp);
  k_stats2  <<<dim3(1),        dim3(256), 0, stream>>>(bnp, bng, bnb, qkvst);
  k_qkvr    <<<dim3(512),      dim3(256), 0, stream>>>(qkvT, W64, qkvst, qkvrT);
  k_pos1    <<<dim3(524),      dim3(256), 0, stream>>>(baserel, W127, postmp);
  k_pos2    <<<dim3(137),      dim3(256), 0, stream>>>(postmp, W127, pos);
  k_tr      <<<dim3(16,4),     dim3(256), 0, stream>>>(w1, w1T, 512, 128);   // w1T[c][o512]
  k_tr      <<<dim3(4,16),     dim3(256), 0, stream>>>(w2, w2T, 128, 512);   // w2T[k][c128]
  k_sim     <<<dim3(512,8),    dim3(256), 0, stream>>>(qkvrT, pos, sim);
  k_simstats<<<dim3(192),      dim3(256), 0, stream>>>(sim, simg, simb, simst);
  k_simsum  <<<dim3(17424),    dim3(256), 0, stream>>>(sim, simst, ssum);
  k_veL     <<<dim3(132),      dim3(256), 0, stream>>>(pos, veLT);
  k_attn    <<<dim3(1024),     dim3(256), 0, stream>>>(ssum, qkvrT, veLT, so);
  k_bnstats <<<dim3(256),      dim3(256), 0, stream>>>(so, outg, outb, sost);
  k_o       <<<dim3(16384),    dim3(256), 0, stream>>>(so, sost, out);
  k_instats <<<dim3(1024),     dim3(256), 0, stream>>>(out, ing, inb, inst);
  k_xn      <<<dim3(16384),    dim3(256), 0, stream>>>(out, inst, xn);
  k_mlp1    <<<dim3(128,4,8),  dim3(256), 0, stream>>>(xn, w1T, h1);
  k_mlp2    <<<dim3(128,1,8),  dim3(256), 0, stream>>>(h1, w2T, out);
}

// Round 7
// 679.764 us; speedup vs baseline: 1.6524x; 1.0766x over previous
//
#include <hip/hip_runtime.h>
#include <math.h>

// Problem constants: N=8, C=128, H=64, W=64, B=N*W=512, ADJ=33, G=8, GP=16
constexpr float EPSV = 1e-5f;

// ---------------- workspace layout (offsets in floats) ----------------
constexpr size_t F_W127  = 0;                      // 33*127 = 4191 (padded 4224)
constexpr size_t F_W64   = F_W127 + 4224;          // 33*64 = 2112
constexpr size_t F_QKVST = F_W64  + 2112;          // float2[256] -> 512 floats
constexpr size_t F_SIMST = F_QKVST+ 512;           // float2[192] -> 384
constexpr size_t F_SOST  = F_SIMST+ 384;           // float2[256] -> 512
constexpr size_t F_INST  = F_SOST + 512;           // float2[1024]-> 2048
constexpr size_t F_POSTMP= F_INST + 2048;          // 32*33*127 = 134112 (alias: w1T+w2T after pos2)
constexpr size_t F_POS   = F_POSTMP + 134112;      // 32*33*33 = 34848 (alias: wT before pos2)
constexpr size_t F_QKV   = F_POS  + 34848;         // qkvT [512][64][256] = 8388608 (alias: SO)
constexpr size_t F_QKVR  = F_QKV  + 8388608;       // qkvrT [512][33][256] = 4325376
constexpr size_t F_SIM   = F_QKVR + 4325376;       // 512*24*1089 = 13381632 (alias: XP early, BNP, XN/H1 late)
constexpr size_t F_SIMSUM= F_SIM  + 13381632;      // 512*8*1089 = 4460544
constexpr size_t F_VB    = F_SIMSUM + 4460544;     // (free)
constexpr size_t F_VEH   = F_VB   + 4194304;       // VeLT 16*33*64 = 33792
constexpr size_t F_SO    = F_QKV;                  // qkvT dead after k_qkvr
constexpr size_t F_XP    = F_SIM;                  // xp (4194304) dead after k_qkv
constexpr size_t F_BNP   = F_SIM;                  // bn partials (32*256 float2), after xp dead
constexpr size_t F_XN    = F_SIM;                  // sim dead after k_simsum
constexpr size_t F_H1    = F_SIM + 4194304;        // 16777216 floats; spans dead sim/simsum/vb
constexpr size_t F_WT    = F_POS;                  // qkv_w^T (32768) dead before k_pos2
constexpr size_t F_W1T   = F_POSTMP;               // 65536, written after pos2 (postmp dead)
constexpr size_t F_W2T   = F_POSTMP + 65536;       // 65536 (131072 <= 134112)

__device__ __forceinline__ void fma4(float4& a, const float4& h, float s){
  a.x += h.x*s; a.y += h.y*s; a.z += h.z*s; a.w += h.w*s;
}

// ---- compile-time 33->64 upsample tables (frontend constants: SROA/branch-fold safe) ----
struct UpT { int j0[64]; float fj[64]; };
constexpr UpT mkUp(){
  UpT t{};
  for (int o=0;o<64;++o){
    float x = ((float)o + 0.5f)*0.515625f - 0.5f;   // 33/64 exact
    if (x < 0.f) x = 0.f;
    if (x > 32.f) x = 32.f;
    int j = (int)x; if (j > 31) j = 31;
    t.j0[o] = j; t.fj[o] = x - (float)j;
  }
  return t;
}
constexpr UpT UT = mkUp();

// runtime variant (used by small prep kernels)
__device__ __forceinline__ void upfac(int o, int& j0, float& f){
  float x = ((float)o + 0.5f)*0.515625f - 0.5f;
  x = fminf(fmaxf(x, 0.f), 32.f);
  int j = (int)x; j = j < 31 ? j : 31;
  j0 = j; f = x - (float)j;
}

// ---------------- resize weight tables (jax.image.resize, antialias=True) ----------------
__global__ void k_tables(float* __restrict__ W127, float* __restrict__ W64){
  int i = threadIdx.x;
  if (i < 33){
    const float inv = 127.0f/33.0f;          // kernel_scale for downsample (antialias)
    float x = ((float)i + 0.5f)*inv - 0.5f;  // half-pixel sample position
    float s = 0.f;
    for (int j=0;j<127;++j){ float w = 1.0f - fabsf((float)j - x)/inv; w = fmaxf(w,0.f); W127[i*127+j]=w; s+=w; }
    float r = 1.0f/s;
    for (int j=0;j<127;++j) W127[i*127+j] *= r;
  } else if (i < 66){
    int ii = i-33;
    const float inv = 64.0f/33.0f;
    float x = ((float)ii + 0.5f)*inv - 0.5f;
    float s=0.f;
    for (int j=0;j<64;++j){ float w = 1.0f - fabsf((float)j - x)/inv; w=fmaxf(w,0.f); W64[ii*64+j]=w; s+=w; }
    float r=1.0f/s;
    for (int j=0;j<64;++j) W64[ii*64+j]*=r;
  }
}

// ---------------- generic 32x32-tiled transpose: dst[c*R+r] = src[r*C+c] ----------------
__global__ __launch_bounds__(256) void k_tr(const float* __restrict__ src, float* __restrict__ dst,
                                            int R, int C){
  __shared__ float T[32][33];
  int r0 = blockIdx.x*32, c0 = blockIdx.y*32;
  int tx = threadIdx.x&31, ty = threadIdx.x>>5;  // 32 x 8
  #pragma unroll
  for (int q=0;q<4;++q){ int r = ty + q*8; T[r][tx] = src[(r0+r)*C + c0+tx]; }
  __syncthreads();
  #pragma unroll
  for (int q=0;q<4;++q){ int c = ty + q*8; dst[(c0+c)*R + r0+tx] = T[tx][c]; }
}

// ---------------- x (N,C,H,W) -> xp (N*W, C, H): per-(n,c) 64x64 transpose ----------------
__global__ __launch_bounds__(256) void k_xt(const float* __restrict__ x, float* __restrict__ xp){
  __shared__ float T[64][65];
  int n = blockIdx.x>>7, c = blockIdx.x&127;
  const float* src = x + ((size_t)(n*128 + c))*4096;
  int tid = threadIdx.x;
  for (int e=tid;e<4096;e+=256){ int h=e>>6, w=e&63; T[h][w] = src[e]; }  // lanes along w: coalesced
  __syncthreads();
  for (int e=tid;e<4096;e+=256){
    int w=e>>6, h=e&63;                       // lanes along h: coalesced writes
    xp[((size_t)((n*64+w)*128 + c))*64 + h] = T[h][w];
  }
}

// ---------------- QKV projection GEMM -> TRANSPOSED out: qkvT[b][l][o] ----------------
__global__ __launch_bounds__(256) void k_qkv(const float* __restrict__ xp, const float* __restrict__ wT,
                                             float* __restrict__ qkvT){
  int b = blockIdx.x, o0 = blockIdx.y*64;
  int tid = threadIdx.x;
  int ot = tid&15, lt = tid>>4;
  __shared__ float4 LX[32][16];   // [kk][l/4]
  __shared__ float4 LW[32][16];   // [kk][o/4]
  const float4* xp4 = (const float4*)xp;
  const float4* wT4 = (const float4*)wT;
  float4 acc[4];                  // acc[j] = l=lt*4+j, float4 across o
  #pragma unroll
  for (int j=0;j<4;++j) acc[j] = make_float4(0.f,0.f,0.f,0.f);
  for (int c0=0;c0<128;c0+=32){
    __syncthreads();
    #pragma unroll
    for (int p=0;p<2;++p){
      int e = tid + p*256; int kk=e>>4, q=e&15;
      LX[kk][q] = xp4[(size_t)b*2048 + (c0+kk)*16 + q];
      LW[kk][q] = wT4[(c0+kk)*64 + (o0>>2) + q];
    }
    __syncthreads();
    #pragma unroll
    for (int kk=0;kk<32;++kk){
      float4 x4 = LX[kk][lt];
      float4 w4 = LW[kk][ot];
      fma4(acc[0], w4, x4.x); fma4(acc[1], w4, x4.y);
      fma4(acc[2], w4, x4.z); fma4(acc[3], w4, x4.w);
    }
  }
  float4* qkvT4 = (float4*)qkvT;
  #pragma unroll
  for (int j=0;j<4;++j)
    qkvT4[((size_t)b*16384 + (lt*4+j)*256 + o0 + ot*4)>>2] = acc[j];
}

// ---------------- BN partial sums over rows of qkvT [32768 rows][256 ch] ----------------
__global__ __launch_bounds__(256) void k_bnsum(const float* __restrict__ qkvT, float2* __restrict__ part){
  int chG = blockIdx.x, rowG = blockIdx.y;
  int cl = threadIdx.x&63;
  int ch = chG*64 + cl;
  int rs = threadIdx.x>>6;  // 0..3
  float s=0.f, s2=0.f;
  for (int r = rowG*1024 + rs; r < rowG*1024 + 1024; r += 4){
    float v = qkvT[(size_t)r*256 + ch]; s+=v; s2+=v*v;
  }
  __shared__ float S1[4][64], S2[4][64];
  S1[rs][cl]=s; S2[rs][cl]=s2; __syncthreads();
  if (rs==0){
    s  = S1[0][cl]+S1[1][cl]+S1[2][cl]+S1[3][cl];
    s2 = S2[0][cl]+S2[1][cl]+S2[2][cl]+S2[3][cl];
    part[rowG*256 + ch] = make_float2(s, s2);
  }
}
__global__ void k_stats2(const float2* __restrict__ part, const float* __restrict__ g,
                         const float* __restrict__ bta, float2* __restrict__ st){
  int ch = threadIdx.x;  // 256
  float s=0.f, s2=0.f;
  for (int r=0;r<32;++r){ float2 p = part[r*256 + ch]; s+=p.x; s2+=p.y; }
  float m = s*(1.0f/32768.0f);
  float var = s2*(1.0f/32768.0f) - m*m;
  float sc = g[ch]/sqrtf(var + EPSV);
  st[ch] = make_float2(sc, bta[ch] - m*sc);
}

// ---------------- qkvr: BN fold + resize 64->33, qkvT[b][t][ch] -> qkvrT[b][i][ch] ----------------
__global__ __launch_bounds__(256) void k_qkvr(const float* __restrict__ qkvT, const float* __restrict__ W64,
                                              const float2* __restrict__ st, float* __restrict__ qkvrT){
  int b = blockIdx.x, ch = threadIdx.x;
  const float* base = qkvT + (size_t)b*16384 + ch;
  float xr[64];
  #pragma unroll
  for (int t=0;t<64;++t) xr[t] = base[t*256];
  float2 sb = st[ch];
  float* ob = qkvrT + (size_t)b*8448 + ch;
  for (int i=0;i<33;++i){
    const float4* wr = (const float4*)(W64 + i*64);   // wave-uniform
    float a = 0.f;
    #pragma unroll
    for (int q=0;q<16;++q){
      float4 w4 = wr[q];
      a += w4.x*xr[4*q] + w4.y*xr[4*q+1] + w4.z*xr[4*q+2] + w4.w*xr[4*q+3];
    }
    ob[i*256] = a*sb.x + sb.y;
  }
}

// ---------------- pos = resize(base_relative, (32,33,33)) separable ----------------
__global__ void k_pos1(const float* __restrict__ base, const float* __restrict__ W127, float* __restrict__ tmp){
  int id = blockIdx.x*256 + threadIdx.x;
  if (id >= 32*33*127) return;
  int c = id / 4191; int r = id - c*4191; int i = r / 127; int xx = r - i*127;
  const float* wr = W127 + i*127;
  const float* bc = base + c*16129 + xx;
  float a=0.f;
  for (int y=0;y<127;++y) a += wr[y]*bc[y*127];
  tmp[id] = a;
}
__global__ void k_pos2(const float* __restrict__ tmp, const float* __restrict__ W127, float* __restrict__ pos){
  int id = blockIdx.x*256 + threadIdx.x;
  if (id >= 32*33*33) return;
  int c = id / 1089; int r = id - c*1089; int i = r / 33; int j = r - i*33;
  const float* wr = W127 + j*127;
  const float* tc = tmp + c*4191 + i*127;
  float a=0.f;
  for (int xx=0;xx<127;++xx) a += wr[xx]*tc[xx];
  pos[id] = a;
}

// ---------------- sim = concat([qk, qr, kr]) for each (b,g) ----------------
__global__ __launch_bounds__(256) void k_sim(const float* __restrict__ qkvrT, const float* __restrict__ pos,
                                             float* __restrict__ sim){
  int b = blockIdx.x, g = blockIdx.y;
  __shared__ float lqa[264], lka[264];  // [8 c][33 i]
  int tid = threadIdx.x;
  for (int e=tid;e<528;e+=256){
    int half = (e < 264) ? 0 : 1;
    int e2 = e - half*264;
    int c = e2/33, i = e2 - c*33;
    float v = qkvrT[(size_t)b*8448 + i*256 + (g*32 + half*8 + c)];
    if (half==0) lqa[e2]=v; else lka[e2]=v;
  }
  __syncthreads();
  for (int p=tid;p<1089;p+=256){
    int i = p/33, j = p - i*33;
    float qk=0.f, qr=0.f, kr=0.f;
    #pragma unroll
    for (int c=0;c<8;++c){
      float qa_ = lqa[c*33+i];
      float ka_ = lka[c*33+j];
      qk += qa_*ka_;
      qr += qa_*pos[c*1089 + i*33 + j];          // q_e = pos[0:8]
      kr += ka_*pos[(8+c)*1089 + j*33 + i];      // k_e = pos[8:16], transposed use
    }
    sim[(b*24 + g)*1089 + p] = qk;
    sim[(b*24 + 8 + g)*1089 + p] = qr;
    sim[(b*24 + 16 + g)*1089 + p] = kr;
  }
}

// ---------------- per-(n, ch24) stats over (W, i, j) ----------------
__global__ __launch_bounds__(256) void k_simstats(const float* __restrict__ sim, const float* __restrict__ g,
                                                  const float* __restrict__ bta, float2* __restrict__ st){
  int nb = blockIdx.x; int n = nb/24, ch = nb - n*24;
  int t = threadIdx.x;
  float s=0.f, s2=0.f;
  for (int e=t; e<64*1089; e+=256){
    int w = e/1089, p = e - w*1089;
    float v = sim[((n*64+w)*24 + ch)*1089 + p];
    s+=v; s2+=v*v;
  }
  __shared__ float rs[256], rq[256];
  rs[t]=s; rq[t]=s2; __syncthreads();
  for (int o=128;o>0;o>>=1){ if(t<o){ rs[t]+=rs[t+o]; rq[t]+=rq[t+o]; } __syncthreads(); }
  if (t==0){
    float m = rs[0]*(1.0f/69696.0f);
    float var = rq[0]*(1.0f/69696.0f) - m*m;
    float sc = g[ch]/sqrtf(var + EPSV);
    st[nb] = make_float2(sc, bta[ch] - m*sc);
  }
}

// ---------------- normalize + sum over the 3 groups ----------------
__global__ void k_simsum(const float* __restrict__ sim, const float2* __restrict__ st, float* __restrict__ ss){
  int id = blockIdx.x*256 + threadIdx.x;      // 512*8*1089
  int b = id / 8712; int r = id - b*8712; int g = r / 1089; int p = r - g*1089;
  int n = b>>6;
  float a = 0.f;
  #pragma unroll
  for (int t3=0;t3<3;++t3){
    float2 sb = st[n*24 + t3*8 + g];
    a += sim[(b*24 + t3*8 + g)*1089 + p]*sb.x + sb.y;
  }
  ss[id] = a;
}

// ---------------- VeLT[c][j33][i] = i-lerped v_e rows (j stays 33-wide) ----------------
__global__ void k_veL(const float* __restrict__ pos, float* __restrict__ VeLT){
  int id = blockIdx.x*256 + threadIdx.x;  // 16*33*64
  if (id >= 33792) return;
  int i = id&63; int r = id>>6; int c = r/33; int j = r - c*33;
  int i0; float fi; upfac(i, i0, fi);
  const float* P = pos + (16+c)*1089;
  VeLT[id] = (1.f-fi)*P[i0*33 + j] + fi*P[(i0+1)*33 + j];
}

// ---------------- fused attention: single-pass softmax, fold consumed on the fly ----------------
// For output row i: e[j]=exp(upsampled sim), s=sum. For k=0..32 the folded weight
// qk = sum_{j: j0=k} e_j(1-fj) + sum_{j: j0=k-1} e_j fj is computed as scalar SSA
// (constexpr tables -> constant branches) and immediately consumed:
//   sv[c]  += qk * Va[k][c]        (LDS b128 broadcast)
//   sve[c] += qk * VeLT[c][k][i]   (coalesced 256B global, L2-resident)
// No local array has a non-literal index -> nothing can demote to scratch.
__global__ __launch_bounds__(256) void k_attn(const float* __restrict__ ss, const float* __restrict__ qkvrT,
                                              const float* __restrict__ VeLT, float* __restrict__ so){
  int wv = threadIdx.x >> 6;
  int i  = threadIdx.x & 63;
  int bg = blockIdx.x*4 + wv;
  int b = bg>>3, g = bg&7;
  __shared__ float  S[4][1092];   // 33x33 simsum tile per wave
  __shared__ float4 Va[4][136];   // [j33][c/4] va tile per wave
  float* Sw = S[wv];
  for (int e=i;e<1089;e+=64) Sw[e] = ss[(size_t)bg*1089 + e];
  for (int e=i;e<132;e+=64){
    int j = e>>2, cq = e&3;
    Va[wv][e] = *(const float4*)(qkvrT + (size_t)b*8448 + j*256 + g*32 + 16 + cq*4);
  }
  __syncthreads();

  // phase A: single-pass exp of the bilinear-upsampled row (no max subtraction:
  // sim is BN-normalized, |su| <~ 10, exp safe in fp32)
  int i0; float fi; upfac(i, i0, fi);
  const float* R0 = Sw + i0*33;
  const float* R1 = R0 + 33;
  float p[64];
  float s = 0.f;
  #pragma unroll
  for (int j=0;j<64;++j){
    float fj = UT.fj[j]; int j0 = UT.j0[j];     // literal constants after unroll
    float v0 = (1.f-fj)*R0[j0] + fj*R0[j0+1];
    float v1 = (1.f-fj)*R1[j0] + fj*R1[j0+1];
    float e = expf((1.f-fi)*v0 + fi*v1);
    p[j] = e; s += e;
  }
  float inv = 1.f/s;

  // phase B: fold + both contractions in one k-sweep
  float av[16], ae[16];
  #pragma unroll
  for (int c=0;c<16;++c){ av[c]=0.f; ae[c]=0.f; }
  #pragma unroll
  for (int k=0;k<33;++k){
    float qk = 0.f;
    #pragma unroll
    for (int j=0;j<64;++j){
      if (UT.j0[k==0?63:j] == -1) {}            // (no-op; keeps structure simple)
      if (UT.j0[j] == k)        qk += p[j]*(1.f-UT.fj[j]);
      else if (UT.j0[j] == k-1) qk += p[j]*UT.fj[j];
    }
    float4 a0 = Va[wv][k*4+0], a1 = Va[wv][k*4+1], a2 = Va[wv][k*4+2], a3 = Va[wv][k*4+3];
    av[0] += qk*a0.x; av[1] += qk*a0.y; av[2]  += qk*a0.z; av[3]  += qk*a0.w;
    av[4] += qk*a1.x; av[5] += qk*a1.y; av[6]  += qk*a1.z; av[7]  += qk*a1.w;
    av[8] += qk*a2.x; av[9] += qk*a2.y; av[10] += qk*a2.z; av[11] += qk*a2.w;
    av[12]+= qk*a3.x; av[13]+= qk*a3.y; av[14] += qk*a3.z; av[15] += qk*a3.w;
    const float* vr = VeLT + k*64 + i;
    #pragma unroll
    for (int c=0;c<16;++c) ae[c] += qk * vr[c*2112];
  }
  float* ob = so + (size_t)b*16384 + g*2048;   // channel 2*(g*16+c) at offset (g*16+c)*128
  #pragma unroll
  for (int c=0;c<16;++c) ob[c*128 + i]      = av[c]*inv;   // sv  -> even channel
  #pragma unroll
  for (int c=0;c<16;++c) ob[c*128 + 64 + i] = ae[c]*inv;   // sve -> odd channel
}

// ---------------- BN(so) + pair-sum + transpose -> o in (N,C,H,W) ----------------
__global__ void k_o(const float* __restrict__ so, const float2* __restrict__ st, float* __restrict__ o){
  int id = blockIdx.x*256 + threadIdx.x;  // ((n*128+oc)*64+h)*64+w
  int w = id&63, h=(id>>6)&63, oc=(id>>12)&127, n=id>>19;
  int b = n*64 + w;
  float2 s0 = st[2*oc], s1 = st[2*oc+1];
  float v0 = so[b*16384 + (2*oc)*64 + h];
  float v1 = so[b*16384 + (2*oc+1)*64 + h];
  o[id] = v0*s0.x + s0.y + v1*s1.x + s1.y;
}

// ---------------- BN stats over [512][256][64] rows (so layout) ----------------
__global__ __launch_bounds__(256) void k_bnstats(const float* __restrict__ src, const float* __restrict__ g,
                                                 const float* __restrict__ bta, float2* __restrict__ st){
  int ch = blockIdx.x, t = threadIdx.x;
  float s=0.f, s2=0.f;
  for (int e=t; e<512*64; e+=256){
    int r=e>>6, l=e&63;
    float v = src[(r*256+ch)*64 + l];
    s+=v; s2+=v*v;
  }
  __shared__ float rs[256], rq[256];
  rs[t]=s; rq[t]=s2; __syncthreads();
  for (int o=128;o>0;o>>=1){ if(t<o){ rs[t]+=rs[t+o]; rq[t]+=rq[t+o]; } __syncthreads(); }
  if (t==0){
    float m = rs[0]*(1.0f/32768.0f);
    float var = rq[0]*(1.0f/32768.0f) - m*m;
    float sc = g[ch]/sqrtf(var + EPSV);
    st[ch] = make_float2(sc, bta[ch] - m*sc);
  }
}

// ---------------- spatial block: shifted-channel construction ----------------
__device__ __forceinline__ float xo_val(const float* __restrict__ o, int n, int c, int h, int w){
  if (c >= 40) return o[((n*128 + c)*64 + h)*64 + w];
  int grp = c / 10;
  int cc = c - grp*10;
  int base = (n*128 + cc)*64;
  if (grp==0) return (w>=2) ? o[(base + h)*64 + (w-2)] : 0.f;      // r
  if (grp==1) return (w<62) ? o[(base + h)*64 + (w+2)] : 0.f;      // l
  if (grp==2) return (h>=2) ? o[(base + (h-2))*64 + w] : 0.f;      // d
  return (h<62) ? o[(base + (h+2))*64 + w] : 0.f;                  // u
}

__global__ __launch_bounds__(256) void k_instats(const float* __restrict__ o, const float* __restrict__ g,
                                                 const float* __restrict__ bta, float2* __restrict__ st){
  int nb = blockIdx.x; int n = nb>>7, c = nb&127;
  int t = threadIdx.x;
  float s=0.f,s2=0.f;
  for (int e=t;e<4096;e+=256){
    int h=e>>6, w=e&63;
    float v = xo_val(o,n,c,h,w);
    s+=v; s2+=v*v;
  }
  __shared__ float rs[256], rq[256];
  rs[t]=s; rq[t]=s2; __syncthreads();
  for (int oo=128;oo>0;oo>>=1){ if(t<oo){ rs[t]+=rs[t+oo]; rq[t]+=rq[t+oo]; } __syncthreads(); }
  if (t==0){
    float m = rs[0]*(1.0f/4096.0f);
    float var = rq[0]*(1.0f/4096.0f) - m*m;
    float sc = g[c]/sqrtf(var + EPSV);
    st[nb] = make_float2(sc, bta[c] - m*sc);
  }
}

__global__ void k_xn(const float* __restrict__ o, const float2* __restrict__ st, float* __restrict__ xn){
  int id = blockIdx.x*256+threadIdx.x;
  int w=id&63,h=(id>>6)&63,c=(id>>12)&127,n=id>>19;
  float2 sb = st[n*128+c];
  xn[id] = xo_val(o,n,c,h,w)*sb.x + sb.y;
}

// ---------------- MLP layer 1: h1 = gelu(w1T^T @ xn), 32hw x 128cout tile ----------------
__global__ __launch_bounds__(256) void k_mlp1(const float* __restrict__ xn, const float* __restrict__ w1T,
                                              float* __restrict__ h1){
  int hw0 = blockIdx.x*32, co0 = blockIdx.y*128, n = blockIdx.z;
  int tid = threadIdx.x;
  int hwt = tid&7, cot = tid>>3;
  __shared__ float4 LH[32][8];    // [kk][hw/4]
  __shared__ float4 LW[32][32];   // [kk][cout/4]
  const float4* xn4  = (const float4*)xn;
  const float4* w1T4 = (const float4*)w1T;
  float4 acc[4];
  #pragma unroll
  for (int j=0;j<4;++j) acc[j] = make_float4(0.f,0.f,0.f,0.f);
  for (int c0=0;c0<128;c0+=32){
    __syncthreads();
    { int kk=tid>>3, q=tid&7;
      LH[kk][q] = xn4[((size_t)(n*128 + c0+kk)*4096 + hw0)/4 + q]; }
    #pragma unroll
    for (int p=0;p<4;++p){
      int e = tid + p*256; int kk=e>>5, q=e&31;
      LW[kk][q] = w1T4[((size_t)(c0+kk)*512 + co0)/4 + q];
    }
    __syncthreads();
    #pragma unroll
    for (int kk=0;kk<32;++kk){
      float4 h = LH[kk][hwt];
      float4 w = LW[kk][cot];
      fma4(acc[0], h, w.x); fma4(acc[1], h, w.y);
      fma4(acc[2], h, w.z); fma4(acc[3], h, w.w);
    }
  }
  float4* h14 = (float4*)h1;
  #pragma unroll
  for (int j=0;j<4;++j){
    int cout = co0 + cot*4 + j;
    float4 v = acc[j];
    v.x = 0.5f*v.x*(1.0f + erff(v.x*0.70710678f));
    v.y = 0.5f*v.y*(1.0f + erff(v.y*0.70710678f));
    v.z = 0.5f*v.z*(1.0f + erff(v.z*0.70710678f));
    v.w = 0.5f*v.w*(1.0f + erff(v.w*0.70710678f));
    h14[((size_t)(n*512 + cout)*4096 + hw0)/4 + hwt] = v;
  }
}

// ---------------- MLP layer 2 + residual: 32hw x 128cout tile, K=512 ----------------
__global__ __launch_bounds__(256) void k_mlp2(const float* __restrict__ h1, const float* __restrict__ w2T,
                                              float* __restrict__ out){
  int hw0 = blockIdx.x*32, n = blockIdx.z;
  int tid = threadIdx.x;
  int hwt = tid&7, cot = tid>>3;
  __shared__ float4 LH[32][8];    // [kk][hw/4]
  __shared__ float4 LW[32][32];   // [kk][cout/4]
  const float4* h14  = (const float4*)h1;
  const float4* w2T4 = (const float4*)w2T;
  float4 acc[4];
  #pragma unroll
  for (int j=0;j<4;++j) acc[j] = make_float4(0.f,0.f,0.f,0.f);
  for (int k0=0;k0<512;k0+=32){
    __syncthreads();
    { int kk=tid>>3, q=tid&7;
      LH[kk][q] = h14[((size_t)(n*512 + k0+kk)*4096 + hw0)/4 + q]; }
    #pragma unroll
    for (int p=0;p<4;++p){
      int e = tid + p*256; int kk=e>>5, q=e&31;
      LW[kk][q] = w2T4[((size_t)(k0+kk)*128)/4 + q];
    }
    __syncthreads();
    #pragma unroll
    for (int kk=0;kk<32;++kk){
      float4 h = LH[kk][hwt];
      float4 w = LW[kk][cot];
      fma4(acc[0], h, w.x); fma4(acc[1], h, w.y);
      fma4(acc[2], h, w.z); fma4(acc[3], h, w.w);
    }
  }
  float4* out4 = (float4*)out;
  #pragma unroll
  for (int j=0;j<4;++j){
    int c = cot*4 + j;
    size_t idx = ((size_t)(n*128 + c)*4096 + hw0)/4 + hwt;
    float4 prev = out4[idx];
    prev.x += acc[j].x; prev.y += acc[j].y; prev.z += acc[j].z; prev.w += acc[j].w;
    out4[idx] = prev;    // residual: same-thread read-then-write
  }
}

extern "C" void kernel_launch(void* const* d_in, const int* in_sizes, int n_in,
                              void* d_out, int out_size, void* d_ws, size_t ws_size,
                              hipStream_t stream) {
  (void)in_sizes; (void)n_in; (void)out_size; (void)ws_size;
  const float* x       = (const float*)d_in[0];
  const float* qkvw    = (const float*)d_in[1];
  const float* bng     = (const float*)d_in[2];
  const float* bnb     = (const float*)d_in[3];
  const float* baserel = (const float*)d_in[4];
  const float* simg    = (const float*)d_in[5];
  const float* simb    = (const float*)d_in[6];
  const float* outg    = (const float*)d_in[7];
  const float* outb    = (const float*)d_in[8];
  const float* ing     = (const float*)d_in[9];
  const float* inb     = (const float*)d_in[10];
  const float* w1      = (const float*)d_in[11];
  const float* w2      = (const float*)d_in[12];

  float* ws = (float*)d_ws;
  float*  W127  = ws + F_W127;
  float*  W64   = ws + F_W64;
  float2* qkvst = (float2*)(ws + F_QKVST);
  float2* simst = (float2*)(ws + F_SIMST);
  float2* sost  = (float2*)(ws + F_SOST);
  float2* inst  = (float2*)(ws + F_INST);
  float*  postmp= ws + F_POSTMP;
  float*  pos   = ws + F_POS;
  float*  qkvT  = ws + F_QKV;
  float*  qkvrT = ws + F_QKVR;
  float*  sim   = ws + F_SIM;
  float*  ssum  = ws + F_SIMSUM;
  float*  veLT  = ws + F_VEH;
  float*  so    = ws + F_SO;     // aliases qkvT (dead)
  float*  xp    = ws + F_XP;     // aliases sim (dead until k_sim)
  float2* bnp   = (float2*)(ws + F_BNP);  // aliases xp (dead after k_qkv)
  float*  xn    = ws + F_XN;     // aliases sim (dead)
  float*  h1    = ws + F_H1;     // aliases sim tail + simsum + vb (dead)
  float*  wT    = ws + F_WT;     // aliases pos (dead until k_pos2)
  float*  w1T   = ws + F_W1T;    // aliases postmp (dead after k_pos2)
  float*  w2T   = ws + F_W2T;
  float*  out   = (float*)d_out;

  k_tables  <<<dim3(1),        dim3(128), 0, stream>>>(W127, W64);
  k_tr      <<<dim3(8,4),      dim3(256), 0, stream>>>(qkvw, wT, 256, 128);  // wT[c][o]
  k_xt      <<<dim3(1024),     dim3(256), 0, stream>>>(x, xp);
  k_qkv     <<<dim3(512,4),    dim3(256), 0, stream>>>(xp, wT, qkvT);
  k_bnsum   <<<dim3(4,32),     dim3(256), 0, stream>>>(qkvT, bnp);
  k_stats2  <<<dim3(1),        dim3(256), 0, stream>>>(bnp, bng, bnb, qkvst);
  k_qkvr    <<<dim3(512),      dim3(256), 0, stream>>>(qkvT, W64, qkvst, qkvrT);
  k_pos1    <<<dim3(524),      dim3(256), 0, stream>>>(baserel, W127, postmp);
  k_pos2    <<<dim3(137),      dim3(256), 0, stream>>>(postmp, W127, pos);
  k_tr      <<<dim3(16,4),     dim3(256), 0, stream>>>(w1, w1T, 512, 128);   // w1T[c][o512]
  k_tr      <<<dim3(4,16),     dim3(256), 0, stream>>>(w2, w2T, 128, 512);   // w2T[k][c128]
  k_sim     <<<dim3(512,8),    dim3(256), 0, stream>>>(qkvrT, pos, sim);
  k_simstats<<<dim3(192),      dim3(256), 0, stream>>>(sim, simg, simb, simst);
  k_simsum  <<<dim3(17424),    dim3(256), 0, stream>>>(sim, simst, ssum);
  k_veL     <<<dim3(132),      dim3(256), 0, stream>>>(pos, veLT);
  k_attn    <<<dim3(1024),     dim3(256), 0, stream>>>(ssum, qkvrT, veLT, so);
  k_bnstats <<<dim3(256),      dim3(256), 0, stream>>>(so, outg, outb, sost);
  k_o       <<<dim3(16384),    dim3(256), 0, stream>>>(so, sost, out);
  k_instats <<<dim3(1024),     dim3(256), 0, stream>>>(out, ing, inb, inst);
  k_xn      <<<dim3(16384),    dim3(256), 0, stream>>>(out, inst, xn);
  k_mlp1    <<<dim3(128,4,8),  dim3(256), 0, stream>>>(xn, w1T, h1);
  k_mlp2    <<<dim3(128,1,8),  dim3(256), 0, stream>>>(h1, w2T, out);
}

// Round 8
// 607.646 us; speedup vs baseline: 1.8485x; 1.1187x over previous
//
#include <hip/hip_runtime.h>
#include <math.h>

// Problem constants: N=8, C=128, H=64, W=64, B=N*W=512, ADJ=33, G=8, GP=16
constexpr float EPSV = 1e-5f;

// ---------------- workspace layout (offsets in floats) ----------------
constexpr size_t F_W127  = 0;                      // 33*127 = 4191 (padded 4224)
constexpr size_t F_W64   = F_W127 + 4224;          // 33*64 = 2112
constexpr size_t F_QKVST = F_W64  + 2112;          // float2[256] -> 512 floats
constexpr size_t F_SIMST = F_QKVST+ 512;           // float2[192] -> 384
constexpr size_t F_SOST  = F_SIMST+ 384;           // float2[256] -> 512
constexpr size_t F_INST  = F_SOST + 512;           // float2[1024]-> 2048
constexpr size_t F_POSTMP= F_INST + 2048;          // 32*33*127 = 134112 (alias: w1T+w2T after pos2)
constexpr size_t F_POS   = F_POSTMP + 134112;      // 32*33*33 = 34848 (alias: wT before pos2)
constexpr size_t F_QKV   = F_POS  + 34848;         // qkvT [512][64][256] = 8388608 (alias: SO)
constexpr size_t F_QKVR  = F_QKV  + 8388608;       // qkvrT [512][33][256] = 4325376
constexpr size_t F_SIM   = F_QKVR + 4325376;       // 512*24*1089 = 13381632 (alias: XP early, BNP, XN/H1 late)
constexpr size_t F_PART6 = F_SIM  + 13381632;      // 4096*6 = 24576 (was ssum region)
constexpr size_t F_VEH   = F_PART6 + 4460544;      // VeLT 16*33*64 = 33792
constexpr size_t F_SO    = F_QKV;                  // qkvT dead after k_qkvr
constexpr size_t F_XP    = F_SIM;                  // xp (4194304) dead after k_qkv
constexpr size_t F_BNP   = F_SIM;                  // bn partials (32*256 float2), after xp dead
constexpr size_t F_XN    = F_SIM;                  // sim dead after k_attn
constexpr size_t F_H1    = F_SIM + 4194304;        // 16777216 floats; spans dead sim tail/part6
constexpr size_t F_WT    = F_POS;                  // qkv_w^T (32768) dead before k_pos2
constexpr size_t F_W1T   = F_POSTMP;               // 65536, written after pos2 (postmp dead)
constexpr size_t F_W2T   = F_POSTMP + 65536;       // 65536 (131072 <= 134112)

__device__ __forceinline__ void fma4(float4& a, const float4& h, float s){
  a.x += h.x*s; a.y += h.y*s; a.z += h.z*s; a.w += h.w*s;
}

// ---- compile-time 33->64 upsample tables (frontend constants: SROA/branch-fold safe) ----
struct UpT { int j0[64]; float fj[64]; };
constexpr UpT mkUp(){
  UpT t{};
  for (int o=0;o<64;++o){
    float x = ((float)o + 0.5f)*0.515625f - 0.5f;   // 33/64 exact
    if (x < 0.f) x = 0.f;
    if (x > 32.f) x = 32.f;
    int j = (int)x; if (j > 31) j = 31;
    t.j0[o] = j; t.fj[o] = x - (float)j;
  }
  return t;
}
constexpr UpT UT = mkUp();

// runtime variant (used by small prep kernels)
__device__ __forceinline__ void upfac(int o, int& j0, float& f){
  float x = ((float)o + 0.5f)*0.515625f - 0.5f;
  x = fminf(fmaxf(x, 0.f), 32.f);
  int j = (int)x; j = j < 31 ? j : 31;
  j0 = j; f = x - (float)j;
}

// ---------------- resize weight tables (jax.image.resize, antialias=True) ----------------
__global__ void k_tables(float* __restrict__ W127, float* __restrict__ W64){
  int i = threadIdx.x;
  if (i < 33){
    const float inv = 127.0f/33.0f;          // kernel_scale for downsample (antialias)
    float x = ((float)i + 0.5f)*inv - 0.5f;  // half-pixel sample position
    float s = 0.f;
    for (int j=0;j<127;++j){ float w = 1.0f - fabsf((float)j - x)/inv; w = fmaxf(w,0.f); W127[i*127+j]=w; s+=w; }
    float r = 1.0f/s;
    for (int j=0;j<127;++j) W127[i*127+j] *= r;
  } else if (i < 66){
    int ii = i-33;
    const float inv = 64.0f/33.0f;
    float x = ((float)ii + 0.5f)*inv - 0.5f;
    float s=0.f;
    for (int j=0;j<64;++j){ float w = 1.0f - fabsf((float)j - x)/inv; w=fmaxf(w,0.f); W64[ii*64+j]=w; s+=w; }
    float r=1.0f/s;
    for (int j=0;j<64;++j) W64[ii*64+j]*=r;
  }
}

// ---------------- generic 32x32-tiled transpose: dst[c*R+r] = src[r*C+c] ----------------
__global__ __launch_bounds__(256) void k_tr(const float* __restrict__ src, float* __restrict__ dst,
                                            int R, int C){
  __shared__ float T[32][33];
  int r0 = blockIdx.x*32, c0 = blockIdx.y*32;
  int tx = threadIdx.x&31, ty = threadIdx.x>>5;  // 32 x 8
  #pragma unroll
  for (int q=0;q<4;++q){ int r = ty + q*8; T[r][tx] = src[(r0+r)*C + c0+tx]; }
  __syncthreads();
  #pragma unroll
  for (int q=0;q<4;++q){ int c = ty + q*8; dst[(c0+c)*R + r0+tx] = T[tx][c]; }
}

// ---------------- x (N,C,H,W) -> xp (N*W, C, H): per-(n,c) 64x64 transpose ----------------
__global__ __launch_bounds__(256) void k_xt(const float* __restrict__ x, float* __restrict__ xp){
  __shared__ float T[64][65];
  int n = blockIdx.x>>7, c = blockIdx.x&127;
  const float* src = x + ((size_t)(n*128 + c))*4096;
  int tid = threadIdx.x;
  for (int e=tid;e<4096;e+=256){ int h=e>>6, w=e&63; T[h][w] = src[e]; }  // lanes along w: coalesced
  __syncthreads();
  for (int e=tid;e<4096;e+=256){
    int w=e>>6, h=e&63;                       // lanes along h: coalesced writes
    xp[((size_t)((n*64+w)*128 + c))*64 + h] = T[h][w];
  }
}

// ---------------- QKV projection GEMM -> TRANSPOSED out: qkvT[b][l][o] ----------------
__global__ __launch_bounds__(256) void k_qkv(const float* __restrict__ xp, const float* __restrict__ wT,
                                             float* __restrict__ qkvT){
  int b = blockIdx.x, o0 = blockIdx.y*64;
  int tid = threadIdx.x;
  int ot = tid&15, lt = tid>>4;
  __shared__ float4 LX[32][16];   // [kk][l/4]
  __shared__ float4 LW[32][16];   // [kk][o/4]
  const float4* xp4 = (const float4*)xp;
  const float4* wT4 = (const float4*)wT;
  float4 acc[4];                  // acc[j] = l=lt*4+j, float4 across o
  #pragma unroll
  for (int j=0;j<4;++j) acc[j] = make_float4(0.f,0.f,0.f,0.f);
  for (int c0=0;c0<128;c0+=32){
    __syncthreads();
    #pragma unroll
    for (int p=0;p<2;++p){
      int e = tid + p*256; int kk=e>>4, q=e&15;
      LX[kk][q] = xp4[(size_t)b*2048 + (c0+kk)*16 + q];
      LW[kk][q] = wT4[(c0+kk)*64 + (o0>>2) + q];
    }
    __syncthreads();
    #pragma unroll
    for (int kk=0;kk<32;++kk){
      float4 x4 = LX[kk][lt];
      float4 w4 = LW[kk][ot];
      fma4(acc[0], w4, x4.x); fma4(acc[1], w4, x4.y);
      fma4(acc[2], w4, x4.z); fma4(acc[3], w4, x4.w);
    }
  }
  float4* qkvT4 = (float4*)qkvT;
  #pragma unroll
  for (int j=0;j<4;++j)
    qkvT4[((size_t)b*16384 + (lt*4+j)*256 + o0 + ot*4)>>2] = acc[j];
}

// ---------------- BN partial sums over rows of qkvT [32768 rows][256 ch] ----------------
__global__ __launch_bounds__(256) void k_bnsum(const float* __restrict__ qkvT, float2* __restrict__ part){
  int chG = blockIdx.x, rowG = blockIdx.y;
  int cl = threadIdx.x&63;
  int ch = chG*64 + cl;
  int rs = threadIdx.x>>6;  // 0..3
  float s=0.f, s2=0.f;
  for (int r = rowG*1024 + rs; r < rowG*1024 + 1024; r += 4){
    float v = qkvT[(size_t)r*256 + ch]; s+=v; s2+=v*v;
  }
  __shared__ float S1[4][64], S2[4][64];
  S1[rs][cl]=s; S2[rs][cl]=s2; __syncthreads();
  if (rs==0){
    s  = S1[0][cl]+S1[1][cl]+S1[2][cl]+S1[3][cl];
    s2 = S2[0][cl]+S2[1][cl]+S2[2][cl]+S2[3][cl];
    part[rowG*256 + ch] = make_float2(s, s2);
  }
}
__global__ void k_stats2(const float2* __restrict__ part, const float* __restrict__ g,
                         const float* __restrict__ bta, float2* __restrict__ st){
  int ch = threadIdx.x;  // 256
  float s=0.f, s2=0.f;
  for (int r=0;r<32;++r){ float2 p = part[r*256 + ch]; s+=p.x; s2+=p.y; }
  float m = s*(1.0f/32768.0f);
  float var = s2*(1.0f/32768.0f) - m*m;
  float sc = g[ch]/sqrtf(var + EPSV);
  st[ch] = make_float2(sc, bta[ch] - m*sc);
}

// ---------------- qkvr: BN fold + resize 64->33, qkvT[b][t][ch] -> qkvrT[b][i][ch] ----------------
__global__ __launch_bounds__(256) void k_qkvr(const float* __restrict__ qkvT, const float* __restrict__ W64,
                                              const float2* __restrict__ st, float* __restrict__ qkvrT){
  int b = blockIdx.x, ch = threadIdx.x;
  const float* base = qkvT + (size_t)b*16384 + ch;
  float xr[64];
  #pragma unroll
  for (int t=0;t<64;++t) xr[t] = base[t*256];
  float2 sb = st[ch];
  float* ob = qkvrT + (size_t)b*8448 + ch;
  for (int i=0;i<33;++i){
    const float4* wr = (const float4*)(W64 + i*64);   // wave-uniform
    float a = 0.f;
    #pragma unroll
    for (int q=0;q<16;++q){
      float4 w4 = wr[q];
      a += w4.x*xr[4*q] + w4.y*xr[4*q+1] + w4.z*xr[4*q+2] + w4.w*xr[4*q+3];
    }
    ob[i*256] = a*sb.x + sb.y;
  }
}

// ---------------- pos = resize(base_relative, (32,33,33)) separable ----------------
__global__ void k_pos1(const float* __restrict__ base, const float* __restrict__ W127, float* __restrict__ tmp){
  int id = blockIdx.x*256 + threadIdx.x;
  if (id >= 32*33*127) return;
  int c = id / 4191; int r = id - c*4191; int i = r / 127; int xx = r - i*127;
  const float* wr = W127 + i*127;
  const float* bc = base + c*16129 + xx;
  float a=0.f;
  for (int y=0;y<127;++y) a += wr[y]*bc[y*127];
  tmp[id] = a;
}
__global__ void k_pos2(const float* __restrict__ tmp, const float* __restrict__ W127, float* __restrict__ pos){
  int id = blockIdx.x*256 + threadIdx.x;
  if (id >= 32*33*33) return;
  int c = id / 1089; int r = id - c*1089; int i = r / 33; int j = r - i*33;
  const float* wr = W127 + j*127;
  const float* tc = tmp + c*4191 + i*127;
  float a=0.f;
  for (int xx=0;xx<127;++xx) a += wr[xx]*tc[xx];
  pos[id] = a;
}

// ---------------- sim = concat([qk, qr, kr]) + per-block stats partials ----------------
__global__ __launch_bounds__(256) void k_sim(const float* __restrict__ qkvrT, const float* __restrict__ pos,
                                             float* __restrict__ sim, float* __restrict__ part6){
  int b = blockIdx.x, g = blockIdx.y;
  __shared__ float lqa[264], lka[264];  // [8 c][33 i]
  int tid = threadIdx.x;
  for (int e=tid;e<528;e+=256){
    int half = (e < 264) ? 0 : 1;
    int e2 = e - half*264;
    int c = e2/33, i = e2 - c*33;
    float v = qkvrT[(size_t)b*8448 + i*256 + (g*32 + half*8 + c)];
    if (half==0) lqa[e2]=v; else lka[e2]=v;
  }
  __syncthreads();
  float sqk=0.f,qqk=0.f,sqr=0.f,qqr=0.f,skr=0.f,qkr=0.f;
  for (int p=tid;p<1089;p+=256){
    int i = p/33, j = p - i*33;
    float qk=0.f, qr=0.f, kr=0.f;
    #pragma unroll
    for (int c=0;c<8;++c){
      float qa_ = lqa[c*33+i];
      float ka_ = lka[c*33+j];
      qk += qa_*ka_;
      qr += qa_*pos[c*1089 + i*33 + j];          // q_e = pos[0:8]
      kr += ka_*pos[(8+c)*1089 + j*33 + i];      // k_e = pos[8:16], transposed use
    }
    sim[(b*24 + g)*1089 + p] = qk;
    sim[(b*24 + 8 + g)*1089 + p] = qr;
    sim[(b*24 + 16 + g)*1089 + p] = kr;
    sqk+=qk; qqk+=qk*qk; sqr+=qr; qqr+=qr*qr; skr+=kr; qkr+=kr*kr;
  }
  __shared__ float red[6][256];
  red[0][tid]=sqk; red[1][tid]=qqk; red[2][tid]=sqr;
  red[3][tid]=qqr; red[4][tid]=skr; red[5][tid]=qkr;
  __syncthreads();
  for (int o=128;o>0;o>>=1){
    if (tid<o){
      #pragma unroll
      for (int c=0;c<6;++c) red[c][tid]+=red[c][tid+o];
    }
    __syncthreads();
  }
  if (tid<6) part6[(size_t)(b*8+g)*6 + tid] = red[tid][0];
}

// ---------------- simst from part6: 192 (n,ch24) entries ----------------
__global__ void k_sstB(const float* __restrict__ part6, const float* __restrict__ g,
                       const float* __restrict__ bta, float2* __restrict__ st){
  int nb = threadIdx.x;
  if (nb >= 192) return;
  int n = nb/24, ch = nb - n*24;
  int t3 = ch>>3, gg = ch&7;
  float s=0.f, s2=0.f;
  for (int w=0; w<64; ++w){
    const float* p = part6 + (size_t)((n*64+w)*8 + gg)*6 + 2*t3;
    s += p[0]; s2 += p[1];
  }
  float m = s*(1.0f/69696.0f);
  float var = s2*(1.0f/69696.0f) - m*m;
  float sc = g[ch]/sqrtf(var + EPSV);
  st[nb] = make_float2(sc, bta[ch] - m*sc);
}

// ---------------- VeLT[c][j33][i] = i-lerped v_e rows (j stays 33-wide) ----------------
__global__ void k_veL(const float* __restrict__ pos, float* __restrict__ VeLT){
  int id = blockIdx.x*256 + threadIdx.x;  // 16*33*64
  if (id >= 33792) return;
  int i = id&63; int r = id>>6; int c = r/33; int j = r - c*33;
  int i0; float fi; upfac(i, i0, fi);
  const float* P = pos + (16+c)*1089;
  VeLT[id] = (1.f-fi)*P[i0*33 + j] + fi*P[(i0+1)*33 + j];
}

// ---------------- fused attention: BN-normalize+3-sum on load, softmax fold on the fly ----------------
__global__ __launch_bounds__(256) void k_attn(const float* __restrict__ sim, const float2* __restrict__ simst,
                                              const float* __restrict__ qkvrT, const float* __restrict__ VeLT,
                                              float* __restrict__ so){
  int wv = threadIdx.x >> 6;
  int i  = threadIdx.x & 63;
  int bg = blockIdx.x*4 + wv;
  int b = bg>>3, g = bg&7;
  int n = b>>6;
  __shared__ float  S[4][1092];   // 33x33 fused-simsum tile per wave
  __shared__ float4 Va[4][136];   // [j33][c/4] va tile per wave
  float* Sw = S[wv];
  float2 sb0 = simst[n*24 + g], sb1 = simst[n*24 + 8 + g], sb2 = simst[n*24 + 16 + g];
  float badd = sb0.y + sb1.y + sb2.y;
  const float* s0 = sim + ((size_t)b*24 + g)*1089;
  for (int e=i;e<1089;e+=64)
    Sw[e] = s0[e]*sb0.x + s0[e+8712]*sb1.x + s0[e+17424]*sb2.x + badd;
  for (int e=i;e<132;e+=64){
    int j = e>>2, cq = e&3;
    Va[wv][e] = *(const float4*)(qkvrT + (size_t)b*8448 + j*256 + g*32 + 16 + cq*4);
  }
  __syncthreads();

  // phase A: single-pass exp of the bilinear-upsampled row (BN-normalized -> exp-safe)
  int i0; float fi; upfac(i, i0, fi);
  const float* R0 = Sw + i0*33;
  const float* R1 = R0 + 33;
  float p[64];
  float s = 0.f;
  #pragma unroll
  for (int j=0;j<64;++j){
    float fj = UT.fj[j]; int j0 = UT.j0[j];     // literal constants after unroll
    float v0 = (1.f-fj)*R0[j0] + fj*R0[j0+1];
    float v1 = (1.f-fj)*R1[j0] + fj*R1[j0+1];
    float e = expf((1.f-fi)*v0 + fi*v1);
    p[j] = e; s += e;
  }
  float inv = 1.f/s;

  // phase B: fold + both contractions in one k-sweep
  float av[16], ae[16];
  #pragma unroll
  for (int c=0;c<16;++c){ av[c]=0.f; ae[c]=0.f; }
  #pragma unroll
  for (int k=0;k<33;++k){
    float qk = 0.f;
    #pragma unroll
    for (int j=0;j<64;++j){
      if (UT.j0[j] == k)        qk += p[j]*(1.f-UT.fj[j]);
      else if (UT.j0[j] == k-1) qk += p[j]*UT.fj[j];
    }
    float4 a0 = Va[wv][k*4+0], a1 = Va[wv][k*4+1], a2 = Va[wv][k*4+2], a3 = Va[wv][k*4+3];
    av[0] += qk*a0.x; av[1] += qk*a0.y; av[2]  += qk*a0.z; av[3]  += qk*a0.w;
    av[4] += qk*a1.x; av[5] += qk*a1.y; av[6]  += qk*a1.z; av[7]  += qk*a1.w;
    av[8] += qk*a2.x; av[9] += qk*a2.y; av[10] += qk*a2.z; av[11] += qk*a2.w;
    av[12]+= qk*a3.x; av[13]+= qk*a3.y; av[14] += qk*a3.z; av[15] += qk*a3.w;
    const float* vr = VeLT + k*64 + i;
    #pragma unroll
    for (int c=0;c<16;++c) ae[c] += qk * vr[c*2112];
  }
  float* ob = so + (size_t)b*16384 + g*2048;   // channel 2*(g*16+c) at offset (g*16+c)*128
  #pragma unroll
  for (int c=0;c<16;++c) ob[c*128 + i]      = av[c]*inv;   // sv  -> even channel
  #pragma unroll
  for (int c=0;c<16;++c) ob[c*128 + 64 + i] = ae[c]*inv;   // sve -> odd channel
}

// ---------------- BN(so) + pair-sum + transpose -> o in (N,C,H,W) ----------------
__global__ void k_o(const float* __restrict__ so, const float2* __restrict__ st, float* __restrict__ o){
  int id = blockIdx.x*256 + threadIdx.x;  // ((n*128+oc)*64+h)*64+w
  int w = id&63, h=(id>>6)&63, oc=(id>>12)&127, n=id>>19;
  int b = n*64 + w;
  float2 s0 = st[2*oc], s1 = st[2*oc+1];
  float v0 = so[b*16384 + (2*oc)*64 + h];
  float v1 = so[b*16384 + (2*oc+1)*64 + h];
  o[id] = v0*s0.x + s0.y + v1*s1.x + s1.y;
}

// ---------------- BN stats over [512][256][64] rows (so layout) ----------------
__global__ __launch_bounds__(256) void k_bnstats(const float* __restrict__ src, const float* __restrict__ g,
                                                 const float* __restrict__ bta, float2* __restrict__ st){
  int ch = blockIdx.x, t = threadIdx.x;
  float s=0.f, s2=0.f;
  for (int e=t; e<512*64; e+=256){
    int r=e>>6, l=e&63;
    float v = src[(r*256+ch)*64 + l];
    s+=v; s2+=v*v;
  }
  __shared__ float rs[256], rq[256];
  rs[t]=s; rq[t]=s2; __syncthreads();
  for (int o=128;o>0;o>>=1){ if(t<o){ rs[t]+=rs[t+o]; rq[t]+=rq[t+o]; } __syncthreads(); }
  if (t==0){
    float m = rs[0]*(1.0f/32768.0f);
    float var = rq[0]*(1.0f/32768.0f) - m*m;
    float sc = g[ch]/sqrtf(var + EPSV);
    st[ch] = make_float2(sc, bta[ch] - m*sc);
  }
}

// ---------------- spatial block: shifted-channel construction ----------------
__device__ __forceinline__ float xo_val(const float* __restrict__ o, int n, int c, int h, int w){
  if (c >= 40) return o[((n*128 + c)*64 + h)*64 + w];
  int grp = c / 10;
  int cc = c - grp*10;
  int base = (n*128 + cc)*64;
  if (grp==0) return (w>=2) ? o[(base + h)*64 + (w-2)] : 0.f;      // r
  if (grp==1) return (w<62) ? o[(base + h)*64 + (w+2)] : 0.f;      // l
  if (grp==2) return (h>=2) ? o[(base + (h-2))*64 + w] : 0.f;      // d
  return (h<62) ? o[(base + (h+2))*64 + w] : 0.f;                  // u
}

__global__ __launch_bounds__(256) void k_instats(const float* __restrict__ o, const float* __restrict__ g,
                                                 const float* __restrict__ bta, float2* __restrict__ st){
  int nb = blockIdx.x; int n = nb>>7, c = nb&127;
  int t = threadIdx.x;
  float s=0.f,s2=0.f;
  for (int e=t;e<4096;e+=256){
    int h=e>>6, w=e&63;
    float v = xo_val(o,n,c,h,w);
    s+=v; s2+=v*v;
  }
  __shared__ float rs[256], rq[256];
  rs[t]=s; rq[t]=s2; __syncthreads();
  for (int oo=128;oo>0;oo>>=1){ if(t<oo){ rs[t]+=rs[t+oo]; rq[t]+=rq[t+oo]; } __syncthreads(); }
  if (t==0){
    float m = rs[0]*(1.0f/4096.0f);
    float var = rq[0]*(1.0f/4096.0f) - m*m;
    float sc = g[c]/sqrtf(var + EPSV);
    st[nb] = make_float2(sc, bta[c] - m*sc);
  }
}

__global__ void k_xn(const float* __restrict__ o, const float2* __restrict__ st, float* __restrict__ xn){
  int id = blockIdx.x*256+threadIdx.x;
  int w=id&63,h=(id>>6)&63,c=(id>>12)&127,n=id>>19;
  float2 sb = st[n*128+c];
  xn[id] = xo_val(o,n,c,h,w)*sb.x + sb.y;
}

// ---------------- MLP layer 1: h1 = gelu(w1T^T @ xn), 32hw x 128cout tile ----------------
__global__ __launch_bounds__(256) void k_mlp1(const float* __restrict__ xn, const float* __restrict__ w1T,
                                              float* __restrict__ h1){
  int hw0 = blockIdx.x*32, co0 = blockIdx.y*128, n = blockIdx.z;
  int tid = threadIdx.x;
  int hwt = tid&7, cot = tid>>3;
  __shared__ float4 LH[32][8];    // [kk][hw/4]
  __shared__ float4 LW[32][32];   // [kk][cout/4]
  const float4* xn4  = (const float4*)xn;
  const float4* w1T4 = (const float4*)w1T;
  float4 acc[4];
  #pragma unroll
  for (int j=0;j<4;++j) acc[j] = make_float4(0.f,0.f,0.f,0.f);
  for (int c0=0;c0<128;c0+=32){
    __syncthreads();
    { int kk=tid>>3, q=tid&7;
      LH[kk][q] = xn4[((size_t)(n*128 + c0+kk)*4096 + hw0)/4 + q]; }
    #pragma unroll
    for (int p=0;p<4;++p){
      int e = tid + p*256; int kk=e>>5, q=e&31;
      LW[kk][q] = w1T4[((size_t)(c0+kk)*512 + co0)/4 + q];
    }
    __syncthreads();
    #pragma unroll
    for (int kk=0;kk<32;++kk){
      float4 h = LH[kk][hwt];
      float4 w = LW[kk][cot];
      fma4(acc[0], h, w.x); fma4(acc[1], h, w.y);
      fma4(acc[2], h, w.z); fma4(acc[3], h, w.w);
    }
  }
  float4* h14 = (float4*)h1;
  #pragma unroll
  for (int j=0;j<4;++j){
    int cout = co0 + cot*4 + j;
    float4 v = acc[j];
    v.x = 0.5f*v.x*(1.0f + erff(v.x*0.70710678f));
    v.y = 0.5f*v.y*(1.0f + erff(v.y*0.70710678f));
    v.z = 0.5f*v.z*(1.0f + erff(v.z*0.70710678f));
    v.w = 0.5f*v.w*(1.0f + erff(v.w*0.70710678f));
    h14[((size_t)(n*512 + cout)*4096 + hw0)/4 + hwt] = v;
  }
}

// ---------------- MLP layer 2 + residual: 32hw x 128cout tile, K=512 ----------------
__global__ __launch_bounds__(256) void k_mlp2(const float* __restrict__ h1, const float* __restrict__ w2T,
                                              float* __restrict__ out){
  int hw0 = blockIdx.x*32, n = blockIdx.z;
  int tid = threadIdx.x;
  int hwt = tid&7, cot = tid>>3;
  __shared__ float4 LH[32][8];    // [kk][hw/4]
  __shared__ float4 LW[32][32];   // [kk][cout/4]
  const float4* h14  = (const float4*)h1;
  const float4* w2T4 = (const float4*)w2T;
  float4 acc[4];
  #pragma unroll
  for (int j=0;j<4;++j) acc[j] = make_float4(0.f,0.f,0.f,0.f);
  for (int k0=0;k0<512;k0+=32){
    __syncthreads();
    { int kk=tid>>3, q=tid&7;
      LH[kk][q] = h14[((size_t)(n*512 + k0+kk)*4096 + hw0)/4 + q]; }
    #pragma unroll
    for (int p=0;p<4;++p){
      int e = tid + p*256; int kk=e>>5, q=e&31;
      LW[kk][q] = w2T4[((size_t)(k0+kk)*128)/4 + q];
    }
    __syncthreads();
    #pragma unroll
    for (int kk=0;kk<32;++kk){
      float4 h = LH[kk][hwt];
      float4 w = LW[kk][cot];
      fma4(acc[0], h, w.x); fma4(acc[1], h, w.y);
      fma4(acc[2], h, w.z); fma4(acc[3], h, w.w);
    }
  }
  float4* out4 = (float4*)out;
  #pragma unroll
  for (int j=0;j<4;++j){
    int c = cot*4 + j;
    size_t idx = ((size_t)(n*128 + c)*4096 + hw0)/4 + hwt;
    float4 prev = out4[idx];
    prev.x += acc[j].x; prev.y += acc[j].y; prev.z += acc[j].z; prev.w += acc[j].w;
    out4[idx] = prev;    // residual: same-thread read-then-write
  }
}

extern "C" void kernel_launch(void* const* d_in, const int* in_sizes, int n_in,
                              void* d_out, int out_size, void* d_ws, size_t ws_size,
                              hipStream_t stream) {
  (void)in_sizes; (void)n_in; (void)out_size; (void)ws_size;
  const float* x       = (const float*)d_in[0];
  const float* qkvw    = (const float*)d_in[1];
  const float* bng     = (const float*)d_in[2];
  const float* bnb     = (const float*)d_in[3];
  const float* baserel = (const float*)d_in[4];
  const float* simg    = (const float*)d_in[5];
  const float* simb    = (const float*)d_in[6];
  const float* outg    = (const float*)d_in[7];
  const float* outb    = (const float*)d_in[8];
  const float* ing     = (const float*)d_in[9];
  const float* inb     = (const float*)d_in[10];
  const float* w1      = (const float*)d_in[11];
  const float* w2      = (const float*)d_in[12];

  float* ws = (float*)d_ws;
  float*  W127  = ws + F_W127;
  float*  W64   = ws + F_W64;
  float2* qkvst = (float2*)(ws + F_QKVST);
  float2* simst = (float2*)(ws + F_SIMST);
  float2* sost  = (float2*)(ws + F_SOST);
  float2* inst  = (float2*)(ws + F_INST);
  float*  postmp= ws + F_POSTMP;
  float*  pos   = ws + F_POS;
  float*  qkvT  = ws + F_QKV;
  float*  qkvrT = ws + F_QKVR;
  float*  sim   = ws + F_SIM;
  float*  part6 = ws + F_PART6;
  float*  veLT  = ws + F_VEH;
  float*  so    = ws + F_SO;     // aliases qkvT (dead)
  float*  xp    = ws + F_XP;     // aliases sim (dead until k_sim)
  float2* bnp   = (float2*)(ws + F_BNP);  // aliases xp (dead after k_qkv)
  float*  xn    = ws + F_XN;     // aliases sim (dead after k_attn)
  float*  h1    = ws + F_H1;     // aliases sim tail + part6 (dead)
  float*  wT    = ws + F_WT;     // aliases pos (dead until k_pos2)
  float*  w1T   = ws + F_W1T;    // aliases postmp (dead after k_pos2)
  float*  w2T   = ws + F_W2T;
  float*  out   = (float*)d_out;

  k_tables  <<<dim3(1),        dim3(128), 0, stream>>>(W127, W64);
  k_tr      <<<dim3(8,4),      dim3(256), 0, stream>>>(qkvw, wT, 256, 128);  // wT[c][o]
  k_xt      <<<dim3(1024),     dim3(256), 0, stream>>>(x, xp);
  k_qkv     <<<dim3(512,4),    dim3(256), 0, stream>>>(xp, wT, qkvT);
  k_bnsum   <<<dim3(4,32),     dim3(256), 0, stream>>>(qkvT, bnp);
  k_stats2  <<<dim3(1),        dim3(256), 0, stream>>>(bnp, bng, bnb, qkvst);
  k_qkvr    <<<dim3(512),      dim3(256), 0, stream>>>(qkvT, W64, qkvst, qkvrT);
  k_pos1    <<<dim3(524),      dim3(256), 0, stream>>>(baserel, W127, postmp);
  k_pos2    <<<dim3(137),      dim3(256), 0, stream>>>(postmp, W127, pos);
  k_tr      <<<dim3(16,4),     dim3(256), 0, stream>>>(w1, w1T, 512, 128);   // w1T[c][o512]
  k_tr      <<<dim3(4,16),     dim3(256), 0, stream>>>(w2, w2T, 128, 512);   // w2T[k][c128]
  k_sim     <<<dim3(512,8),    dim3(256), 0, stream>>>(qkvrT, pos, sim, part6);
  k_sstB    <<<dim3(1),        dim3(192), 0, stream>>>(part6, simg, simb, simst);
  k_veL     <<<dim3(132),      dim3(256), 0, stream>>>(pos, veLT);
  k_attn    <<<dim3(1024),     dim3(256), 0, stream>>>(sim, simst, qkvrT, veLT, so);
  k_bnstats <<<dim3(256),      dim3(256), 0, stream>>>(so, outg, outb, sost);
  k_o       <<<dim3(16384),    dim3(256), 0, stream>>>(so, sost, out);
  k_instats <<<dim3(1024),     dim3(256), 0, stream>>>(out, ing, inb, inst);
  k_xn      <<<dim3(16384),    dim3(256), 0, stream>>>(out, inst, xn);
  k_mlp1    <<<dim3(128,4,8),  dim3(256), 0, stream>>>(xn, w1T, h1);
  k_mlp2    <<<dim3(128,1,8),  dim3(256), 0, stream>>>(h1, w2T, out);
}

// Round 10
// 536.874 us; speedup vs baseline: 2.0922x; 1.1318x over previous
//
#include <hip/hip_runtime.h>
#include <math.h>

// Problem constants: N=8, C=128, H=64, W=64, B=N*W=512, ADJ=33, G=8, GP=16
constexpr float EPSV = 1e-5f;
typedef unsigned short u16;
using bf16x8 = __attribute__((ext_vector_type(8))) short;
using f32x4  = __attribute__((ext_vector_type(4))) float;

// ---------------- workspace layout (offsets in floats) ----------------
constexpr size_t F_W127  = 0;                      // 33*127 = 4191 (padded 4224)
constexpr size_t F_W64   = F_W127 + 4224;          // 33*64 = 2112
constexpr size_t F_QKVST = F_W64  + 2112;          // float2[256] -> 512 floats
constexpr size_t F_SIMST = F_QKVST+ 512;           // float2[192] -> 384
constexpr size_t F_SOST  = F_SIMST+ 384;           // float2[256] -> 512
constexpr size_t F_INST  = F_SOST + 512;           // float2[1024]-> 2048
constexpr size_t F_POSTMP= F_INST + 2048;          // 32*33*127 = 134112 (alias: w1b/w2b after pos2)
constexpr size_t F_POS   = F_POSTMP + 134112;      // 32*33*33 = 34848 (alias: wT before pos2)
constexpr size_t F_QKV   = F_POS  + 34848;         // qkvT [512][64][256] = 8388608 (alias: SO)
constexpr size_t F_QKVR  = F_QKV  + 8388608;       // qkvrT [512][33][256] = 4325376
constexpr size_t F_SIM   = F_QKVR + 4325376;       // 512*24*1089 = 13381632 (alias: XP early, BNP, XN late)
constexpr size_t F_PART6 = F_SIM  + 13381632;      // 4096*6
constexpr size_t F_VEH   = F_PART6 + 4460544;      // VeLT 16*33*64 = 33792
constexpr size_t F_XNT   = F_VEH  + 33792;         // xnT bf16 [8][4096][128] = 4194304 u16 = 2097152 f
constexpr size_t F_SO    = F_QKV;                  // qkvT dead after k_qkvr
constexpr size_t F_XP    = F_SIM;                  // xp (4194304) dead after k_qkv
constexpr size_t F_BNP   = F_SIM;                  // bn partials, after xp dead
constexpr size_t F_XN    = F_SIM;                  // sim dead after k_attn
constexpr size_t F_H1    = F_SIM + 4194304;        // h1T bf16 [8][4096][512] = 16777216 u16 = 8388608 f
constexpr size_t F_WT    = F_POS;                  // qkv_w^T (32768) dead before k_pos2
constexpr size_t F_W1B   = F_POSTMP;               // w1 bf16: 65536 u16 = 32768 floats
constexpr size_t F_W2B   = F_POSTMP + 32768;       // w2 bf16: 65536 u16 = 32768 floats (65536 total <= 134112)

__device__ __forceinline__ void fma4(float4& a, const float4& h, float s){
  a.x += h.x*s; a.y += h.y*s; a.z += h.z*s; a.w += h.w*s;
}
__device__ __forceinline__ u16 f2b(float x){      // fp32 -> bf16 RNE
  unsigned u = __float_as_uint(x);
  return (u16)((u + 0x7FFFu + ((u>>16)&1u)) >> 16);
}

// ---- compile-time 33->64 upsample tables (frontend constants: SROA/branch-fold safe) ----
struct UpT { int j0[64]; float fj[64]; };
constexpr UpT mkUp(){
  UpT t{};
  for (int o=0;o<64;++o){
    float x = ((float)o + 0.5f)*0.515625f - 0.5f;   // 33/64 exact
    if (x < 0.f) x = 0.f;
    if (x > 32.f) x = 32.f;
    int j = (int)x; if (j > 31) j = 31;
    t.j0[o] = j; t.fj[o] = x - (float)j;
  }
  return t;
}
constexpr UpT UT = mkUp();

__device__ __forceinline__ void upfac(int o, int& j0, float& f){
  float x = ((float)o + 0.5f)*0.515625f - 0.5f;
  x = fminf(fmaxf(x, 0.f), 32.f);
  int j = (int)x; j = j < 31 ? j : 31;
  j0 = j; f = x - (float)j;
}

// ---------------- resize weight tables ----------------
__global__ void k_tables(float* __restrict__ W127, float* __restrict__ W64){
  int i = threadIdx.x;
  if (i < 33){
    const float inv = 127.0f/33.0f;
    float x = ((float)i + 0.5f)*inv - 0.5f;
    float s = 0.f;
    for (int j=0;j<127;++j){ float w = 1.0f - fabsf((float)j - x)/inv; w = fmaxf(w,0.f); W127[i*127+j]=w; s+=w; }
    float r = 1.0f/s;
    for (int j=0;j<127;++j) W127[i*127+j] *= r;
  } else if (i < 66){
    int ii = i-33;
    const float inv = 64.0f/33.0f;
    float x = ((float)ii + 0.5f)*inv - 0.5f;
    float s=0.f;
    for (int j=0;j<64;++j){ float w = 1.0f - fabsf((float)j - x)/inv; w=fmaxf(w,0.f); W64[ii*64+j]=w; s+=w; }
    float r=1.0f/s;
    for (int j=0;j<64;++j) W64[ii*64+j]*=r;
  }
}

// ---------------- generic 32x32-tiled transpose ----------------
__global__ __launch_bounds__(256) void k_tr(const float* __restrict__ src, float* __restrict__ dst,
                                            int R, int C){
  __shared__ float T[32][33];
  int r0 = blockIdx.x*32, c0 = blockIdx.y*32;
  int tx = threadIdx.x&31, ty = threadIdx.x>>5;
  #pragma unroll
  for (int q=0;q<4;++q){ int r = ty + q*8; T[r][tx] = src[(r0+r)*C + c0+tx]; }
  __syncthreads();
  #pragma unroll
  for (int q=0;q<4;++q){ int c = ty + q*8; dst[(c0+c)*R + r0+tx] = T[tx][c]; }
}

// ---------------- fp32 -> bf16 elementwise convert ----------------
__global__ void k_cvtb(const float* __restrict__ src, u16* __restrict__ dst, int n){
  int id = blockIdx.x*256 + threadIdx.x;
  if (id < n) dst[id] = f2b(src[id]);
}

// ---------------- x (N,C,H,W) -> xp (N*W, C, H) ----------------
__global__ __launch_bounds__(256) void k_xt(const float* __restrict__ x, float* __restrict__ xp){
  __shared__ float T[64][65];
  int n = blockIdx.x>>7, c = blockIdx.x&127;
  const float* src = x + ((size_t)(n*128 + c))*4096;
  int tid = threadIdx.x;
  for (int e=tid;e<4096;e+=256){ int h=e>>6, w=e&63; T[h][w] = src[e]; }
  __syncthreads();
  for (int e=tid;e<4096;e+=256){
    int w=e>>6, h=e&63;
    xp[((size_t)((n*64+w)*128 + c))*64 + h] = T[h][w];
  }
}

// ---------------- QKV projection GEMM -> qkvT[b][l][o] ----------------
__global__ __launch_bounds__(256) void k_qkv(const float* __restrict__ xp, const float* __restrict__ wT,
                                             float* __restrict__ qkvT){
  int b = blockIdx.x, o0 = blockIdx.y*64;
  int tid = threadIdx.x;
  int ot = tid&15, lt = tid>>4;
  __shared__ float4 LX[32][16];
  __shared__ float4 LW[32][16];
  const float4* xp4 = (const float4*)xp;
  const float4* wT4 = (const float4*)wT;
  float4 acc[4];
  #pragma unroll
  for (int j=0;j<4;++j) acc[j] = make_float4(0.f,0.f,0.f,0.f);
  for (int c0=0;c0<128;c0+=32){
    __syncthreads();
    #pragma unroll
    for (int p=0;p<2;++p){
      int e = tid + p*256; int kk=e>>4, q=e&15;
      LX[kk][q] = xp4[(size_t)b*2048 + (c0+kk)*16 + q];
      LW[kk][q] = wT4[(c0+kk)*64 + (o0>>2) + q];
    }
    __syncthreads();
    #pragma unroll
    for (int kk=0;kk<32;++kk){
      float4 x4 = LX[kk][lt];
      float4 w4 = LW[kk][ot];
      fma4(acc[0], w4, x4.x); fma4(acc[1], w4, x4.y);
      fma4(acc[2], w4, x4.z); fma4(acc[3], w4, x4.w);
    }
  }
  float4* qkvT4 = (float4*)qkvT;
  #pragma unroll
  for (int j=0;j<4;++j)
    qkvT4[((size_t)b*16384 + (lt*4+j)*256 + o0 + ot*4)>>2] = acc[j];
}

// ---------------- BN partial sums over rows of qkvT ----------------
__global__ __launch_bounds__(256) void k_bnsum(const float* __restrict__ qkvT, float2* __restrict__ part){
  int chG = blockIdx.x, rowG = blockIdx.y;
  int cl = threadIdx.x&63;
  int ch = chG*64 + cl;
  int rs = threadIdx.x>>6;
  float s=0.f, s2=0.f;
  for (int r = rowG*1024 + rs; r < rowG*1024 + 1024; r += 4){
    float v = qkvT[(size_t)r*256 + ch]; s+=v; s2+=v*v;
  }
  __shared__ float S1[4][64], S2[4][64];
  S1[rs][cl]=s; S2[rs][cl]=s2; __syncthreads();
  if (rs==0){
    s  = S1[0][cl]+S1[1][cl]+S1[2][cl]+S1[3][cl];
    s2 = S2[0][cl]+S2[1][cl]+S2[2][cl]+S2[3][cl];
    part[rowG*256 + ch] = make_float2(s, s2);
  }
}
__global__ void k_stats2(const float2* __restrict__ part, const float* __restrict__ g,
                         const float* __restrict__ bta, float2* __restrict__ st){
  int ch = threadIdx.x;
  float s=0.f, s2=0.f;
  for (int r=0;r<32;++r){ float2 p = part[r*256 + ch]; s+=p.x; s2+=p.y; }
  float m = s*(1.0f/32768.0f);
  float var = s2*(1.0f/32768.0f) - m*m;
  float sc = g[ch]/sqrtf(var + EPSV);
  st[ch] = make_float2(sc, bta[ch] - m*sc);
}

// ---------------- qkvr: BN fold + resize 64->33 ----------------
__global__ __launch_bounds__(256) void k_qkvr(const float* __restrict__ qkvT, const float* __restrict__ W64,
                                              const float2* __restrict__ st, float* __restrict__ qkvrT){
  int b = blockIdx.x, ch = threadIdx.x;
  const float* base = qkvT + (size_t)b*16384 + ch;
  float xr[64];
  #pragma unroll
  for (int t=0;t<64;++t) xr[t] = base[t*256];
  float2 sb = st[ch];
  float* ob = qkvrT + (size_t)b*8448 + ch;
  for (int i=0;i<33;++i){
    const float4* wr = (const float4*)(W64 + i*64);
    float a = 0.f;
    #pragma unroll
    for (int q=0;q<16;++q){
      float4 w4 = wr[q];
      a += w4.x*xr[4*q] + w4.y*xr[4*q+1] + w4.z*xr[4*q+2] + w4.w*xr[4*q+3];
    }
    ob[i*256] = a*sb.x + sb.y;
  }
}

// ---------------- pos = resize(base_relative, (32,33,33)) separable ----------------
__global__ void k_pos1(const float* __restrict__ base, const float* __restrict__ W127, float* __restrict__ tmp){
  int id = blockIdx.x*256 + threadIdx.x;
  if (id >= 32*33*127) return;
  int c = id / 4191; int r = id - c*4191; int i = r / 127; int xx = r - i*127;
  const float* wr = W127 + i*127;
  const float* bc = base + c*16129 + xx;
  float a=0.f;
  for (int y=0;y<127;++y) a += wr[y]*bc[y*127];
  tmp[id] = a;
}
__global__ void k_pos2(const float* __restrict__ tmp, const float* __restrict__ W127, float* __restrict__ pos){
  int id = blockIdx.x*256 + threadIdx.x;
  if (id >= 32*33*33) return;
  int c = id / 1089; int r = id - c*1089; int i = r / 33; int j = r - i*33;
  const float* wr = W127 + j*127;
  const float* tc = tmp + c*4191 + i*127;
  float a=0.f;
  for (int xx=0;xx<127;++xx) a += wr[xx]*tc[xx];
  pos[id] = a;
}

// ---------------- sim = concat([qk, qr, kr]) + per-block stats partials ----------------
__global__ __launch_bounds__(256) void k_sim(const float* __restrict__ qkvrT, const float* __restrict__ pos,
                                             float* __restrict__ sim, float* __restrict__ part6){
  int b = blockIdx.x, g = blockIdx.y;
  __shared__ float lqa[264], lka[264];
  int tid = threadIdx.x;
  for (int e=tid;e<528;e+=256){
    int half = (e < 264) ? 0 : 1;
    int e2 = e - half*264;
    int c = e2/33, i = e2 - c*33;
    float v = qkvrT[(size_t)b*8448 + i*256 + (g*32 + half*8 + c)];
    if (half==0) lqa[e2]=v; else lka[e2]=v;
  }
  __syncthreads();
  float sqk=0.f,qqk=0.f,sqr=0.f,qqr=0.f,skr=0.f,qkr=0.f;
  for (int p=tid;p<1089;p+=256){
    int i = p/33, j = p - i*33;
    float qk=0.f, qr=0.f, kr=0.f;
    #pragma unroll
    for (int c=0;c<8;++c){
      float qa_ = lqa[c*33+i];
      float ka_ = lka[c*33+j];
      qk += qa_*ka_;
      qr += qa_*pos[c*1089 + i*33 + j];
      kr += ka_*pos[(8+c)*1089 + j*33 + i];
    }
    sim[(b*24 + g)*1089 + p] = qk;
    sim[(b*24 + 8 + g)*1089 + p] = qr;
    sim[(b*24 + 16 + g)*1089 + p] = kr;
    sqk+=qk; qqk+=qk*qk; sqr+=qr; qqr+=qr*qr; skr+=kr; qkr+=kr*kr;
  }
  __shared__ float red[6][256];
  red[0][tid]=sqk; red[1][tid]=qqk; red[2][tid]=sqr;
  red[3][tid]=qqr; red[4][tid]=skr; red[5][tid]=qkr;
  __syncthreads();
  for (int o=128;o>0;o>>=1){
    if (tid<o){
      #pragma unroll
      for (int c=0;c<6;++c) red[c][tid]+=red[c][tid+o];
    }
    __syncthreads();
  }
  if (tid<6) part6[(size_t)(b*8+g)*6 + tid] = red[tid][0];
}

// ---------------- simst from part6 ----------------
__global__ void k_sstB(const float* __restrict__ part6, const float* __restrict__ g,
                       const float* __restrict__ bta, float2* __restrict__ st){
  int nb = threadIdx.x;
  if (nb >= 192) return;
  int n = nb/24, ch = nb - n*24;
  int t3 = ch>>3, gg = ch&7;
  float s=0.f, s2=0.f;
  for (int w=0; w<64; ++w){
    const float* p = part6 + (size_t)((n*64+w)*8 + gg)*6 + 2*t3;
    s += p[0]; s2 += p[1];
  }
  float m = s*(1.0f/69696.0f);
  float var = s2*(1.0f/69696.0f) - m*m;
  float sc = g[ch]/sqrtf(var + EPSV);
  st[nb] = make_float2(sc, bta[ch] - m*sc);
}

// ---------------- VeLT[c][j33][i] ----------------
__global__ void k_veL(const float* __restrict__ pos, float* __restrict__ VeLT){
  int id = blockIdx.x*256 + threadIdx.x;
  if (id >= 33792) return;
  int i = id&63; int r = id>>6; int c = r/33; int j = r - c*33;
  int i0; float fi; upfac(i, i0, fi);
  const float* P = pos + (16+c)*1089;
  VeLT[id] = (1.f-fi)*P[i0*33 + j] + fi*P[(i0+1)*33 + j];
}

// ---------------- fused attention ----------------
__global__ __launch_bounds__(256) void k_attn(const float* __restrict__ sim, const float2* __restrict__ simst,
                                              const float* __restrict__ qkvrT, const float* __restrict__ VeLT,
                                              float* __restrict__ so){
  int wv = threadIdx.x >> 6;
  int i  = threadIdx.x & 63;
  int bg = blockIdx.x*4 + wv;
  int b = bg>>3, g = bg&7;
  int n = b>>6;
  __shared__ float  S[4][1092];
  __shared__ float4 Va[4][136];
  float* Sw = S[wv];
  float2 sb0 = simst[n*24 + g], sb1 = simst[n*24 + 8 + g], sb2 = simst[n*24 + 16 + g];
  float badd = sb0.y + sb1.y + sb2.y;
  const float* s0 = sim + ((size_t)b*24 + g)*1089;
  for (int e=i;e<1089;e+=64)
    Sw[e] = s0[e]*sb0.x + s0[e+8712]*sb1.x + s0[e+17424]*sb2.x + badd;
  for (int e=i;e<132;e+=64){
    int j = e>>2, cq = e&3;
    Va[wv][e] = *(const float4*)(qkvrT + (size_t)b*8448 + j*256 + g*32 + 16 + cq*4);
  }
  __syncthreads();

  int i0; float fi; upfac(i, i0, fi);
  const float* R0 = Sw + i0*33;
  const float* R1 = R0 + 33;
  float p[64];
  float s = 0.f;
  #pragma unroll
  for (int j=0;j<64;++j){
    float fj = UT.fj[j]; int j0 = UT.j0[j];
    float v0 = (1.f-fj)*R0[j0] + fj*R0[j0+1];
    float v1 = (1.f-fj)*R1[j0] + fj*R1[j0+1];
    float e = expf((1.f-fi)*v0 + fi*v1);
    p[j] = e; s += e;
  }
  float inv = 1.f/s;

  float av[16], ae[16];
  #pragma unroll
  for (int c=0;c<16;++c){ av[c]=0.f; ae[c]=0.f; }
  #pragma unroll
  for (int k=0;k<33;++k){
    float qk = 0.f;
    #pragma unroll
    for (int j=0;j<64;++j){
      if (UT.j0[j] == k)        qk += p[j]*(1.f-UT.fj[j]);
      else if (UT.j0[j] == k-1) qk += p[j]*UT.fj[j];
    }
    float4 a0 = Va[wv][k*4+0], a1 = Va[wv][k*4+1], a2 = Va[wv][k*4+2], a3 = Va[wv][k*4+3];
    av[0] += qk*a0.x; av[1] += qk*a0.y; av[2]  += qk*a0.z; av[3]  += qk*a0.w;
    av[4] += qk*a1.x; av[5] += qk*a1.y; av[6]  += qk*a1.z; av[7]  += qk*a1.w;
    av[8] += qk*a2.x; av[9] += qk*a2.y; av[10] += qk*a2.z; av[11] += qk*a2.w;
    av[12]+= qk*a3.x; av[13]+= qk*a3.y; av[14] += qk*a3.z; av[15] += qk*a3.w;
    const float* vr = VeLT + k*64 + i;
    #pragma unroll
    for (int c=0;c<16;++c) ae[c] += qk * vr[c*2112];
  }
  float* ob = so + (size_t)b*16384 + g*2048;
  #pragma unroll
  for (int c=0;c<16;++c) ob[c*128 + i]      = av[c]*inv;
  #pragma unroll
  for (int c=0;c<16;++c) ob[c*128 + 64 + i] = ae[c]*inv;
}

// ---------------- BN(so) + pair-sum + transpose -> o ----------------
__global__ void k_o(const float* __restrict__ so, const float2* __restrict__ st, float* __restrict__ o){
  int id = blockIdx.x*256 + threadIdx.x;
  int w = id&63, h=(id>>6)&63, oc=(id>>12)&127, n=id>>19;
  int b = n*64 + w;
  float2 s0 = st[2*oc], s1 = st[2*oc+1];
  float v0 = so[b*16384 + (2*oc)*64 + h];
  float v1 = so[b*16384 + (2*oc+1)*64 + h];
  o[id] = v0*s0.x + s0.y + v1*s1.x + s1.y;
}

// ---------------- BN stats over [512][256][64] rows ----------------
__global__ __launch_bounds__(256) void k_bnstats(const float* __restrict__ src, const float* __restrict__ g,
                                                 const float* __restrict__ bta, float2* __restrict__ st){
  int ch = blockIdx.x, t = threadIdx.x;
  float s=0.f, s2=0.f;
  for (int e=t; e<512*64; e+=256){
    int r=e>>6, l=e&63;
    float v = src[(r*256+ch)*64 + l];
    s+=v; s2+=v*v;
  }
  __shared__ float rs[256], rq[256];
  rs[t]=s; rq[t]=s2; __syncthreads();
  for (int o=128;o>0;o>>=1){ if(t<o){ rs[t]+=rs[t+o]; rq[t]+=rq[t+o]; } __syncthreads(); }
  if (t==0){
    float m = rs[0]*(1.0f/32768.0f);
    float var = rq[0]*(1.0f/32768.0f) - m*m;
    float sc = g[ch]/sqrtf(var + EPSV);
    st[ch] = make_float2(sc, bta[ch] - m*sc);
  }
}

// ---------------- spatial block ----------------
__device__ __forceinline__ float xo_val(const float* __restrict__ o, int n, int c, int h, int w){
  if (c >= 40) return o[((n*128 + c)*64 + h)*64 + w];
  int grp = c / 10;
  int cc = c - grp*10;
  int base = (n*128 + cc)*64;
  if (grp==0) return (w>=2) ? o[(base + h)*64 + (w-2)] : 0.f;
  if (grp==1) return (w<62) ? o[(base + h)*64 + (w+2)] : 0.f;
  if (grp==2) return (h>=2) ? o[(base + (h-2))*64 + w] : 0.f;
  return (h<62) ? o[(base + (h+2))*64 + w] : 0.f;
}

__global__ __launch_bounds__(256) void k_instats(const float* __restrict__ o, const float* __restrict__ g,
                                                 const float* __restrict__ bta, float2* __restrict__ st){
  int nb = blockIdx.x; int n = nb>>7, c = nb&127;
  int t = threadIdx.x;
  float s=0.f,s2=0.f;
  for (int e=t;e<4096;e+=256){
    int h=e>>6, w=e&63;
    float v = xo_val(o,n,c,h,w);
    s+=v; s2+=v*v;
  }
  __shared__ float rs[256], rq[256];
  rs[t]=s; rq[t]=s2; __syncthreads();
  for (int oo=128;oo>0;oo>>=1){ if(t<oo){ rs[t]+=rs[t+oo]; rq[t]+=rq[t+oo]; } __syncthreads(); }
  if (t==0){
    float m = rs[0]*(1.0f/4096.0f);
    float var = rq[0]*(1.0f/4096.0f) - m*m;
    float sc = g[c]/sqrtf(var + EPSV);
    st[nb] = make_float2(sc, bta[c] - m*sc);
  }
}

__global__ void k_xn(const float* __restrict__ o, const float2* __restrict__ st, float* __restrict__ xn){
  int id = blockIdx.x*256+threadIdx.x;
  int w=id&63,h=(id>>6)&63,c=(id>>12)&127,n=id>>19;
  float2 sb = st[n*128+c];
  xn[id] = xo_val(o,n,c,h,w)*sb.x + sb.y;
}

// ---------------- xn fp32 [n][c][hw] -> xnT bf16 [n][hw][c] ----------------
__global__ __launch_bounds__(256) void k_xtr(const float* __restrict__ xn, u16* __restrict__ xnT){
  __shared__ float T[64][65];
  int hw0 = (blockIdx.x&63)*64, c0 = ((blockIdx.x>>6)&1)*64, n = blockIdx.x>>7;
  int tid = threadIdx.x;
  for (int e=tid;e<4096;e+=256){
    int cL = e>>6, hwL = e&63;                 // lanes along hw: coalesced
    T[cL][hwL] = xn[((size_t)(n*128 + c0+cL))*4096 + hw0 + hwL];
  }
  __syncthreads();
  for (int e=tid;e<4096;e+=256){
    int hwL = e>>6, cL = e&63;                 // lanes along c: 128B contiguous stores
    xnT[((size_t)(n*4096 + hw0+hwL))*128 + c0 + cL] = f2b(T[cL][hwL]);
  }
}

// ---------------- MFMA bf16 GEMM core: D[128 m][128 nn] per block, 4 waves (2x2 of 64x64) ----
// A[m][K] and B[nn][K] both row-major k-contiguous bf16; D = A * B^T.
// a/b frag: lane l holds [l&15][k = 8*(l>>4)+j]; D: row=(l>>4)*4+reg, col=l&15.
__global__ __launch_bounds__(256) void k_mlp1(const u16* __restrict__ xnT, const u16* __restrict__ w1b,
                                              u16* __restrict__ h1T){
  int hw0 = blockIdx.x*128, co0 = blockIdx.y*128, n = blockIdx.z;
  int tid = threadIdx.x;
  int wv = tid>>6, l = tid&63;
  int wm = (wv>>1)*64, wn = (wv&1)*64;
  int lr = l&15, lq = l>>4;
  __shared__ u16 As[128*40];   // [m][k32] pad->40
  __shared__ u16 Bs[128*40];
  f32x4 acc[4][4];
  #pragma unroll
  for (int mi=0;mi<4;++mi)
    #pragma unroll
    for (int ni=0;ni<4;++ni) acc[mi][ni] = (f32x4){0.f,0.f,0.f,0.f};
  const u16* Ag = xnT + ((size_t)(n*4096 + hw0))*128;
  const u16* Bg = w1b + (size_t)co0*128;
  for (int ks=0; ks<128; ks+=32){
    __syncthreads();
    #pragma unroll
    for (int p=0;p<2;++p){
      int e = tid + p*256; int row = e>>2, q = e&3;
      *(uint4*)&As[row*40 + q*8] = *(const uint4*)&Ag[(size_t)row*128 + ks + q*8];
      *(uint4*)&Bs[row*40 + q*8] = *(const uint4*)&Bg[(size_t)row*128 + ks + q*8];
    }
    __syncthreads();
    bf16x8 af[4], bfr[4];
    #pragma unroll
    for (int mi=0;mi<4;++mi) af[mi] = *(const bf16x8*)&As[(wm + mi*16 + lr)*40 + lq*8];
    #pragma unroll
    for (int ni=0;ni<4;++ni) bfr[ni] = *(const bf16x8*)&Bs[(wn + ni*16 + lr)*40 + lq*8];
    #pragma unroll
    for (int mi=0;mi<4;++mi)
      #pragma unroll
      for (int ni=0;ni<4;++ni)
        acc[mi][ni] = __builtin_amdgcn_mfma_f32_16x16x32_bf16(af[mi], bfr[ni], acc[mi][ni], 0,0,0);
  }
  // epilogue: gelu -> bf16 -> h1T[n][hw][512]
  u16* ob = h1T + ((size_t)(n*4096 + hw0 + wm))*512 + co0 + wn;
  #pragma unroll
  for (int mi=0;mi<4;++mi)
    #pragma unroll
    for (int r=0;r<4;++r){
      int row = mi*16 + lq*4 + r;
      #pragma unroll
      for (int ni=0;ni<4;++ni){
        float v = acc[mi][ni][r];
        v = 0.5f*v*(1.0f + erff(v*0.70710678f));
        ob[(size_t)row*512 + ni*16 + lr] = f2b(v);
      }
    }
}

__global__ __launch_bounds__(256) void k_mlp2(const u16* __restrict__ w2b, const u16* __restrict__ h1T,
                                              float* __restrict__ out){
  int hw0 = blockIdx.x*128, n = blockIdx.z;
  int tid = threadIdx.x;
  int wv = tid>>6, l = tid&63;
  int wm = (wv>>1)*64, wn = (wv&1)*64;    // m=cout(128), nn=hw(128)
  int lr = l&15, lq = l>>4;
  __shared__ u16 As[128*40];   // A = w2b [cout][k]
  __shared__ u16 Bs[128*40];   // B = h1T [hw][k]
  f32x4 acc[4][4];
  #pragma unroll
  for (int mi=0;mi<4;++mi)
    #pragma unroll
    for (int ni=0;ni<4;++ni) acc[mi][ni] = (f32x4){0.f,0.f,0.f,0.f};
  const u16* Ag = w2b;
  const u16* Bg = h1T + ((size_t)(n*4096 + hw0))*512;
  for (int ks=0; ks<512; ks+=32){
    __syncthreads();
    #pragma unroll
    for (int p=0;p<2;++p){
      int e = tid + p*256; int row = e>>2, q = e&3;
      *(uint4*)&As[row*40 + q*8] = *(const uint4*)&Ag[(size_t)row*512 + ks + q*8];
      *(uint4*)&Bs[row*40 + q*8] = *(const uint4*)&Bg[(size_t)row*512 + ks + q*8];
    }
    __syncthreads();
    bf16x8 af[4], bfr[4];
    #pragma unroll
    for (int mi=0;mi<4;++mi) af[mi] = *(const bf16x8*)&As[(wm + mi*16 + lr)*40 + lq*8];
    #pragma unroll
    for (int ni=0;ni<4;++ni) bfr[ni] = *(const bf16x8*)&Bs[(wn + ni*16 + lr)*40 + lq*8];
    #pragma unroll
    for (int mi=0;mi<4;++mi)
      #pragma unroll
      for (int ni=0;ni<4;++ni)
        acc[mi][ni] = __builtin_amdgcn_mfma_f32_16x16x32_bf16(af[mi], bfr[ni], acc[mi][ni], 0,0,0);
  }
  // epilogue: out[n][cout][hw] += D (residual), 64B lane-contiguous stores
  #pragma unroll
  for (int mi=0;mi<4;++mi)
    #pragma unroll
    for (int r=0;r<4;++r){
      int cout = wm + mi*16 + lq*4 + r;
      #pragma unroll
      for (int ni=0;ni<4;++ni){
        size_t idx = ((size_t)(n*128 + cout))*4096 + hw0 + wn + ni*16 + lr;
        out[idx] = acc[mi][ni][r] + out[idx];
      }
    }
}

extern "C" void kernel_launch(void* const* d_in, const int* in_sizes, int n_in,
                              void* d_out, int out_size, void* d_ws, size_t ws_size,
                              hipStream_t stream) {
  (void)in_sizes; (void)n_in; (void)out_size; (void)ws_size;
  const float* x       = (const float*)d_in[0];
  const float* qkvw    = (const float*)d_in[1];
  const float* bng     = (const float*)d_in[2];
  const float* bnb     = (const float*)d_in[3];
  const float* baserel = (const float*)d_in[4];
  const float* simg    = (const float*)d_in[5];
  const float* simb    = (const float*)d_in[6];
  const float* outg    = (const float*)d_in[7];
  const float* outb    = (const float*)d_in[8];
  const float* ing     = (const float*)d_in[9];
  const float* inb     = (const float*)d_in[10];
  const float* w1      = (const float*)d_in[11];
  const float* w2      = (const float*)d_in[12];

  float* ws = (float*)d_ws;
  float*  W127  = ws + F_W127;
  float*  W64   = ws + F_W64;
  float2* qkvst = (float2*)(ws + F_QKVST);
  float2* simst = (float2*)(ws + F_SIMST);
  float2* sost  = (float2*)(ws + F_SOST);
  float2* inst  = (float2*)(ws + F_INST);
  float*  postmp= ws + F_POSTMP;
  float*  pos   = ws + F_POS;
  float*  qkvT  = ws + F_QKV;
  float*  qkvrT = ws + F_QKVR;
  float*  sim   = ws + F_SIM;
  float*  part6 = ws + F_PART6;
  float*  veLT  = ws + F_VEH;
  u16*    xnT   = (u16*)(ws + F_XNT);
  float*  so    = ws + F_SO;
  float*  xp    = ws + F_XP;
  float2* bnp   = (float2*)(ws + F_BNP);
  float*  xn    = ws + F_XN;
  u16*    h1T   = (u16*)(ws + F_H1);
  float*  wT    = ws + F_WT;
  u16*    w1b   = (u16*)(ws + F_W1B);
  u16*    w2b   = (u16*)(ws + F_W2B);
  float*  out   = (float*)d_out;

  k_tables  <<<dim3(1),        dim3(128), 0, stream>>>(W127, W64);
  k_tr      <<<dim3(8,4),      dim3(256), 0, stream>>>(qkvw, wT, 256, 128);
  k_xt      <<<dim3(1024),     dim3(256), 0, stream>>>(x, xp);
  k_qkv     <<<dim3(512,4),    dim3(256), 0, stream>>>(xp, wT, qkvT);
  k_bnsum   <<<dim3(4,32),     dim3(256), 0, stream>>>(qkvT, bnp);
  k_stats2  <<<dim3(1),        dim3(256), 0, stream>>>(bnp, bng, bnb, qkvst);
  k_qkvr    <<<dim3(512),      dim3(256), 0, stream>>>(qkvT, W64, qkvst, qkvrT);
  k_pos1    <<<dim3(524),      dim3(256), 0, stream>>>(baserel, W127, postmp);
  k_pos2    <<<dim3(137),      dim3(256), 0, stream>>>(postmp, W127, pos);
  k_cvtb    <<<dim3(256),      dim3(256), 0, stream>>>(w1, w1b, 65536);
  k_cvtb    <<<dim3(256),      dim3(256), 0, stream>>>(w2, w2b, 65536);
  k_sim     <<<dim3(512,8),    dim3(256), 0, stream>>>(qkvrT, pos, sim, part6);
  k_sstB    <<<dim3(1),        dim3(192), 0, stream>>>(part6, simg, simb, simst);
  k_veL     <<<dim3(132),      dim3(256), 0, stream>>>(pos, veLT);
  k_attn    <<<dim3(1024),     dim3(256), 0, stream>>>(sim, simst, qkvrT, veLT, so);
  k_bnstats <<<dim3(256),      dim3(256), 0, stream>>>(so, outg, outb, sost);
  k_o       <<<dim3(16384),    dim3(256), 0, stream>>>(so, sost, out);
  k_instats <<<dim3(1024),     dim3(256), 0, stream>>>(out, ing, inb, inst);
  k_xn      <<<dim3(16384),    dim3(256), 0, stream>>>(out, inst, xn);
  k_xtr     <<<dim3(1024),     dim3(256), 0, stream>>>(xn, xnT);
  k_mlp1    <<<dim3(32,4,8),   dim3(256), 0, stream>>>(xnT, w1b, h1T);
  k_mlp2    <<<dim3(32,1,8),   dim3(256), 0, stream>>>(w2b, h1T, out);
}

// Round 11
// 452.837 us; speedup vs baseline: 2.4805x; 1.1856x over previous
//
#include <hip/hip_runtime.h>
#include <math.h>

// Problem constants: N=8, C=128, H=64, W=64, B=N*W=512, ADJ=33, G=8, GP=16
constexpr float EPSV = 1e-5f;
typedef unsigned short u16;
using bf16x8 = __attribute__((ext_vector_type(8))) short;
using f32x4  = __attribute__((ext_vector_type(4))) float;

// ---------------- workspace layout (offsets in floats) ----------------
constexpr size_t F_W127  = 0;                      // 33*127 = 4191 (padded 4224)
constexpr size_t F_W64   = F_W127 + 4224;          // 33*64 = 2112
constexpr size_t F_QKVST = F_W64  + 2112;          // float2[256] -> 512 floats
constexpr size_t F_SIMST = F_QKVST+ 512;           // float2[192] -> 384
constexpr size_t F_SOST  = F_SIMST+ 384;           // float2[256] -> 512
constexpr size_t F_INST  = F_SOST + 512;           // float2[1024]-> 2048
constexpr size_t F_POSTMP= F_INST + 2048;          // 32*33*127 = 134112 (alias: w1b/w2b after pos2)
constexpr size_t F_POS   = F_POSTMP + 134112;      // 32*33*33 = 34848 (alias: wT before pos2)
constexpr size_t F_QKV   = F_POS  + 34848;         // qkvT [512][64][256] = 8388608 (alias: SO)
constexpr size_t F_QKVR  = F_QKV  + 8388608;       // qkvrT [512][33][256] = 4325376
constexpr size_t F_SIM   = F_QKVR + 4325376;       // 512*24*1089 = 13381632 (alias: XP early, BNP, XN late)
constexpr size_t F_PART6 = F_SIM  + 13381632;      // 4096*6
constexpr size_t F_VEH   = F_PART6 + 4460544;      // VeLT 16*33*64 = 33792
constexpr size_t F_XNT   = F_VEH  + 33792;         // xnT bf16 [8][4096][128] = 4194304 u16 = 2097152 f
constexpr size_t F_KET   = F_XNT  + 2097152;       // keT 8*33*33 = 8712
constexpr size_t F_SO    = F_QKV;                  // qkvT dead after k_qkvr
constexpr size_t F_XP    = F_SIM;                  // xp (4194304) dead after k_qkv
constexpr size_t F_BNP   = F_SIM;                  // bn partials [256 ch][256 rowG] float2 = 131072 f
constexpr size_t F_XN    = F_SIM;                  // sim dead after k_attn
constexpr size_t F_H1    = F_SIM + 4194304;        // h1T bf16 [8][4096][512] = 16777216 u16 = 8388608 f
constexpr size_t F_WT    = F_POS;                  // qkv_w^T (32768) dead before k_pos2
constexpr size_t F_W1B   = F_POSTMP;               // w1 bf16: 65536 u16 = 32768 floats
constexpr size_t F_W2B   = F_POSTMP + 32768;       // w2 bf16: 65536 u16 = 32768 floats

__device__ __forceinline__ void fma4(float4& a, const float4& h, float s){
  a.x += h.x*s; a.y += h.y*s; a.z += h.z*s; a.w += h.w*s;
}
__device__ __forceinline__ u16 f2b(float x){      // fp32 -> bf16 RNE
  unsigned u = __float_as_uint(x);
  return (u16)((u + 0x7FFFu + ((u>>16)&1u)) >> 16);
}

// ---- compile-time 33->64 upsample tables (frontend constants: SROA/branch-fold safe) ----
struct UpT { int j0[64]; float fj[64]; };
constexpr UpT mkUp(){
  UpT t{};
  for (int o=0;o<64;++o){
    float x = ((float)o + 0.5f)*0.515625f - 0.5f;   // 33/64 exact
    if (x < 0.f) x = 0.f;
    if (x > 32.f) x = 32.f;
    int j = (int)x; if (j > 31) j = 31;
    t.j0[o] = j; t.fj[o] = x - (float)j;
  }
  return t;
}
constexpr UpT UT = mkUp();

__device__ __forceinline__ void upfac(int o, int& j0, float& f){
  float x = ((float)o + 0.5f)*0.515625f - 0.5f;
  x = fminf(fmaxf(x, 0.f), 32.f);
  int j = (int)x; j = j < 31 ? j : 31;
  j0 = j; f = x - (float)j;
}

// ---------------- resize weight tables ----------------
__global__ void k_tables(float* __restrict__ W127, float* __restrict__ W64){
  int i = threadIdx.x;
  if (i < 33){
    const float inv = 127.0f/33.0f;
    float x = ((float)i + 0.5f)*inv - 0.5f;
    float s = 0.f;
    for (int j=0;j<127;++j){ float w = 1.0f - fabsf((float)j - x)/inv; w = fmaxf(w,0.f); W127[i*127+j]=w; s+=w; }
    float r = 1.0f/s;
    for (int j=0;j<127;++j) W127[i*127+j] *= r;
  } else if (i < 66){
    int ii = i-33;
    const float inv = 64.0f/33.0f;
    float x = ((float)ii + 0.5f)*inv - 0.5f;
    float s=0.f;
    for (int j=0;j<64;++j){ float w = 1.0f - fabsf((float)j - x)/inv; w=fmaxf(w,0.f); W64[ii*64+j]=w; s+=w; }
    float r=1.0f/s;
    for (int j=0;j<64;++j) W64[ii*64+j]*=r;
  }
}

// ---------------- generic 32x32-tiled transpose ----------------
__global__ __launch_bounds__(256) void k_tr(const float* __restrict__ src, float* __restrict__ dst,
                                            int R, int C){
  __shared__ float T[32][33];
  int r0 = blockIdx.x*32, c0 = blockIdx.y*32;
  int tx = threadIdx.x&31, ty = threadIdx.x>>5;
  #pragma unroll
  for (int q=0;q<4;++q){ int r = ty + q*8; T[r][tx] = src[(r0+r)*C + c0+tx]; }
  __syncthreads();
  #pragma unroll
  for (int q=0;q<4;++q){ int c = ty + q*8; dst[(c0+c)*R + r0+tx] = T[tx][c]; }
}

// ---------------- fp32 -> bf16 elementwise convert ----------------
__global__ void k_cvtb(const float* __restrict__ src, u16* __restrict__ dst, int n){
  int id = blockIdx.x*256 + threadIdx.x;
  if (id < n) dst[id] = f2b(src[id]);
}

// ---------------- x (N,C,H,W) -> xp (N*W, C, H) ----------------
__global__ __launch_bounds__(256) void k_xt(const float* __restrict__ x, float* __restrict__ xp){
  __shared__ float T[64][65];
  int n = blockIdx.x>>7, c = blockIdx.x&127;
  const float* src = x + ((size_t)(n*128 + c))*4096;
  int tid = threadIdx.x;
  for (int e=tid;e<4096;e+=256){ int h=e>>6, w=e&63; T[h][w] = src[e]; }
  __syncthreads();
  for (int e=tid;e<4096;e+=256){
    int w=e>>6, h=e&63;
    xp[((size_t)((n*64+w)*128 + c))*64 + h] = T[h][w];
  }
}

// ---------------- QKV projection GEMM -> qkvT[b][l][o] ----------------
__global__ __launch_bounds__(256) void k_qkv(const float* __restrict__ xp, const float* __restrict__ wT,
                                             float* __restrict__ qkvT){
  int b = blockIdx.x, o0 = blockIdx.y*64;
  int tid = threadIdx.x;
  int ot = tid&15, lt = tid>>4;
  __shared__ float4 LX[32][16];
  __shared__ float4 LW[32][16];
  const float4* xp4 = (const float4*)xp;
  const float4* wT4 = (const float4*)wT;
  float4 acc[4];
  #pragma unroll
  for (int j=0;j<4;++j) acc[j] = make_float4(0.f,0.f,0.f,0.f);
  for (int c0=0;c0<128;c0+=32){
    __syncthreads();
    #pragma unroll
    for (int p=0;p<2;++p){
      int e = tid + p*256; int kk=e>>4, q=e&15;
      LX[kk][q] = xp4[(size_t)b*2048 + (c0+kk)*16 + q];
      LW[kk][q] = wT4[(c0+kk)*64 + (o0>>2) + q];
    }
    __syncthreads();
    #pragma unroll
    for (int kk=0;kk<32;++kk){
      float4 x4 = LX[kk][lt];
      float4 w4 = LW[kk][ot];
      fma4(acc[0], w4, x4.x); fma4(acc[1], w4, x4.y);
      fma4(acc[2], w4, x4.z); fma4(acc[3], w4, x4.w);
    }
  }
  float4* qkvT4 = (float4*)qkvT;
  #pragma unroll
  for (int j=0;j<4;++j)
    qkvT4[((size_t)b*16384 + (lt*4+j)*256 + o0 + ot*4)>>2] = acc[j];
}

// ---------------- BN partial sums over rows of qkvT: grid (4 chG, 256 rowG) ----------------
// part stored TRANSPOSED: part[ch][rowG] so stage 2 reads are contiguous.
__global__ __launch_bounds__(256) void k_bnsum(const float* __restrict__ qkvT, float2* __restrict__ part){
  int chG = blockIdx.x, rowG = blockIdx.y;
  int cl = threadIdx.x&63;
  int ch = chG*64 + cl;
  int rs = threadIdx.x>>6;  // 0..3
  float s=0.f, s2=0.f;
  for (int r = rowG*128 + rs; r < rowG*128 + 128; r += 4){   // 32 iters
    float v = qkvT[(size_t)r*256 + ch]; s+=v; s2+=v*v;
  }
  __shared__ float S1[4][64], S2[4][64];
  S1[rs][cl]=s; S2[rs][cl]=s2; __syncthreads();
  if (rs==0){
    s  = S1[0][cl]+S1[1][cl]+S1[2][cl]+S1[3][cl];
    s2 = S2[0][cl]+S2[1][cl]+S2[2][cl]+S2[3][cl];
    part[(size_t)ch*256 + rowG] = make_float2(s, s2);
  }
}
// stage 2: grid(8) x 256 thr; 32 channels/block, 8 segments/channel
__global__ void k_stats2(const float2* __restrict__ part, const float* __restrict__ g,
                         const float* __restrict__ bta, float2* __restrict__ st){
  int t = threadIdx.x;
  int chL = t>>3, seg = t&7;
  int ch = blockIdx.x*32 + chL;
  float s=0.f, s2=0.f;
  const float2* p = part + (size_t)ch*256 + seg*32;
  #pragma unroll 8
  for (int r=0;r<32;++r){ float2 q = p[r]; s+=q.x; s2+=q.y; }
  __shared__ float A[32][9], Bq[32][9];
  A[chL][seg]=s; Bq[chL][seg]=s2; __syncthreads();
  if (seg==0){
    #pragma unroll
    for (int k=1;k<8;++k){ s += A[chL][k]; s2 += Bq[chL][k]; }
    float m = s*(1.0f/32768.0f);
    float var = s2*(1.0f/32768.0f) - m*m;
    float sc = g[ch]/sqrtf(var + EPSV);
    st[ch] = make_float2(sc, bta[ch] - m*sc);
  }
}

// ---------------- qkvr: BN fold + resize 64->33 ----------------
__global__ __launch_bounds__(256) void k_qkvr(const float* __restrict__ qkvT, const float* __restrict__ W64,
                                              const float2* __restrict__ st, float* __restrict__ qkvrT){
  int b = blockIdx.x, ch = threadIdx.x;
  const float* base = qkvT + (size_t)b*16384 + ch;
  float xr[64];
  #pragma unroll
  for (int t=0;t<64;++t) xr[t] = base[t*256];
  float2 sb = st[ch];
  float* ob = qkvrT + (size_t)b*8448 + ch;
  for (int i=0;i<33;++i){
    const float4* wr = (const float4*)(W64 + i*64);
    float a = 0.f;
    #pragma unroll
    for (int q=0;q<16;++q){
      float4 w4 = wr[q];
      a += w4.x*xr[4*q] + w4.y*xr[4*q+1] + w4.z*xr[4*q+2] + w4.w*xr[4*q+3];
    }
    ob[i*256] = a*sb.x + sb.y;
  }
}

// ---------------- pos = resize(base_relative, (32,33,33)) separable ----------------
__global__ void k_pos1(const float* __restrict__ base, const float* __restrict__ W127, float* __restrict__ tmp){
  int id = blockIdx.x*256 + threadIdx.x;
  if (id >= 32*33*127) return;
  int c = id / 4191; int r = id - c*4191; int i = r / 127; int xx = r - i*127;
  const float* wr = W127 + i*127;
  const float* bc = base + c*16129 + xx;
  float a=0.f;
  for (int y=0;y<127;++y) a += wr[y]*bc[y*127];
  tmp[id] = a;
}
__global__ void k_pos2(const float* __restrict__ tmp, const float* __restrict__ W127, float* __restrict__ pos){
  int id = blockIdx.x*256 + threadIdx.x;
  if (id >= 32*33*33) return;
  int c = id / 1089; int r = id - c*1089; int i = r / 33; int j = r - i*33;
  const float* wr = W127 + j*127;
  const float* tc = tmp + c*4191 + i*127;
  float a=0.f;
  for (int xx=0;xx<127;++xx) a += wr[xx]*tc[xx];
  pos[id] = a;
}

// ---------------- keT[c][i][j] = k_e[c][j][i] (transpose for coalesced kr loads) ----------------
__global__ void k_keT(const float* __restrict__ pos, float* __restrict__ keT){
  int id = blockIdx.x*256 + threadIdx.x;   // 8*33*33 = 8712
  if (id >= 8712) return;
  int c = id / 1089; int r = id - c*1089; int i = r / 33; int j = r - i*33;
  keT[id] = pos[(8+c)*1089 + j*33 + i];
}

// ---------------- sim = concat([qk, qr, kr]) + per-block stats partials ----------------
__global__ __launch_bounds__(256) void k_sim(const float* __restrict__ qkvrT, const float* __restrict__ pos,
                                             const float* __restrict__ keT,
                                             float* __restrict__ sim, float* __restrict__ part6){
  int b = blockIdx.x, g = blockIdx.y;
  __shared__ float lqa[264], lka[264];
  int tid = threadIdx.x;
  for (int e=tid;e<528;e+=256){
    int half = (e < 264) ? 0 : 1;
    int e2 = e - half*264;
    int c = e2/33, i = e2 - c*33;
    float v = qkvrT[(size_t)b*8448 + i*256 + (g*32 + half*8 + c)];
    if (half==0) lqa[e2]=v; else lka[e2]=v;
  }
  __syncthreads();
  float sqk=0.f,qqk=0.f,sqr=0.f,qqr=0.f,skr=0.f,qkr=0.f;
  for (int p=tid;p<1089;p+=256){
    int i = p/33, j = p - i*33;
    float qk=0.f, qr=0.f, kr=0.f;
    #pragma unroll
    for (int c=0;c<8;++c){
      float qa_ = lqa[c*33+i];
      float ka_ = lka[c*33+j];
      qk += qa_*ka_;
      qr += qa_*pos[c*1089 + i*33 + j];       // q_e = pos[0:8], coalesced
      kr += ka_*keT[c*1089 + i*33 + j];       // k_e transposed -> coalesced
    }
    sim[(b*24 + g)*1089 + p] = qk;
    sim[(b*24 + 8 + g)*1089 + p] = qr;
    sim[(b*24 + 16 + g)*1089 + p] = kr;
    sqk+=qk; qqk+=qk*qk; sqr+=qr; qqr+=qr*qr; skr+=kr; qkr+=kr*kr;
  }
  __shared__ float red[6][256];
  red[0][tid]=sqk; red[1][tid]=qqk; red[2][tid]=sqr;
  red[3][tid]=qqr; red[4][tid]=skr; red[5][tid]=qkr;
  __syncthreads();
  for (int o=128;o>0;o>>=1){
    if (tid<o){
      #pragma unroll
      for (int c=0;c<6;++c) red[c][tid]+=red[c][tid+o];
    }
    __syncthreads();
  }
  if (tid<6) part6[(size_t)(b*8+g)*6 + tid] = red[tid][0];
}

// ---------------- simst from part6 ----------------
__global__ void k_sstB(const float* __restrict__ part6, const float* __restrict__ g,
                       const float* __restrict__ bta, float2* __restrict__ st){
  int nb = threadIdx.x;
  if (nb >= 192) return;
  int n = nb/24, ch = nb - n*24;
  int t3 = ch>>3, gg = ch&7;
  float s=0.f, s2=0.f;
  for (int w=0; w<64; ++w){
    const float* p = part6 + (size_t)((n*64+w)*8 + gg)*6 + 2*t3;
    s += p[0]; s2 += p[1];
  }
  float m = s*(1.0f/69696.0f);
  float var = s2*(1.0f/69696.0f) - m*m;
  float sc = g[ch]/sqrtf(var + EPSV);
  st[nb] = make_float2(sc, bta[ch] - m*sc);
}

// ---------------- VeLT[c][j33][i] ----------------
__global__ void k_veL(const float* __restrict__ pos, float* __restrict__ VeLT){
  int id = blockIdx.x*256 + threadIdx.x;
  if (id >= 33792) return;
  int i = id&63; int r = id>>6; int c = r/33; int j = r - c*33;
  int i0; float fi; upfac(i, i0, fi);
  const float* P = pos + (16+c)*1089;
  VeLT[id] = (1.f-fi)*P[i0*33 + j] + fi*P[(i0+1)*33 + j];
}

// ---------------- fused attention ----------------
__global__ __launch_bounds__(256) void k_attn(const float* __restrict__ sim, const float2* __restrict__ simst,
                                              const float* __restrict__ qkvrT, const float* __restrict__ VeLT,
                                              float* __restrict__ so){
  int wv = threadIdx.x >> 6;
  int i  = threadIdx.x & 63;
  int bg = blockIdx.x*4 + wv;
  int b = bg>>3, g = bg&7;
  int n = b>>6;
  __shared__ float  S[4][1092];
  __shared__ float4 Va[4][136];
  float* Sw = S[wv];
  float2 sb0 = simst[n*24 + g], sb1 = simst[n*24 + 8 + g], sb2 = simst[n*24 + 16 + g];
  float badd = sb0.y + sb1.y + sb2.y;
  const float* s0 = sim + ((size_t)b*24 + g)*1089;
  for (int e=i;e<1089;e+=64)
    Sw[e] = s0[e]*sb0.x + s0[e+8712]*sb1.x + s0[e+17424]*sb2.x + badd;
  for (int e=i;e<132;e+=64){
    int j = e>>2, cq = e&3;
    Va[wv][e] = *(const float4*)(qkvrT + (size_t)b*8448 + j*256 + g*32 + 16 + cq*4);
  }
  __syncthreads();

  int i0; float fi; upfac(i, i0, fi);
  const float* R0 = Sw + i0*33;
  const float* R1 = R0 + 33;
  float p[64];
  float s = 0.f;
  #pragma unroll
  for (int j=0;j<64;++j){
    float fj = UT.fj[j]; int j0 = UT.j0[j];
    float v0 = (1.f-fj)*R0[j0] + fj*R0[j0+1];
    float v1 = (1.f-fj)*R1[j0] + fj*R1[j0+1];
    float e = expf((1.f-fi)*v0 + fi*v1);
    p[j] = e; s += e;
  }
  float inv = 1.f/s;

  float av[16], ae[16];
  #pragma unroll
  for (int c=0;c<16;++c){ av[c]=0.f; ae[c]=0.f; }
  #pragma unroll
  for (int k=0;k<33;++k){
    float qk = 0.f;
    #pragma unroll
    for (int j=0;j<64;++j){
      if (UT.j0[j] == k)        qk += p[j]*(1.f-UT.fj[j]);
      else if (UT.j0[j] == k-1) qk += p[j]*UT.fj[j];
    }
    float4 a0 = Va[wv][k*4+0], a1 = Va[wv][k*4+1], a2 = Va[wv][k*4+2], a3 = Va[wv][k*4+3];
    av[0] += qk*a0.x; av[1] += qk*a0.y; av[2]  += qk*a0.z; av[3]  += qk*a0.w;
    av[4] += qk*a1.x; av[5] += qk*a1.y; av[6]  += qk*a1.z; av[7]  += qk*a1.w;
    av[8] += qk*a2.x; av[9] += qk*a2.y; av[10] += qk*a2.z; av[11] += qk*a2.w;
    av[12]+= qk*a3.x; av[13]+= qk*a3.y; av[14] += qk*a3.z; av[15] += qk*a3.w;
    const float* vr = VeLT + k*64 + i;
    #pragma unroll
    for (int c=0;c<16;++c) ae[c] += qk * vr[c*2112];
  }
  float* ob = so + (size_t)b*16384 + g*2048;
  #pragma unroll
  for (int c=0;c<16;++c) ob[c*128 + i]      = av[c]*inv;
  #pragma unroll
  for (int c=0;c<16;++c) ob[c*128 + 64 + i] = ae[c]*inv;
}

// ---------------- BN(so) + pair-sum + transpose -> o ----------------
__global__ void k_o(const float* __restrict__ so, const float2* __restrict__ st, float* __restrict__ o){
  int id = blockIdx.x*256 + threadIdx.x;
  int w = id&63, h=(id>>6)&63, oc=(id>>12)&127, n=id>>19;
  int b = n*64 + w;
  float2 s0 = st[2*oc], s1 = st[2*oc+1];
  float v0 = so[b*16384 + (2*oc)*64 + h];
  float v1 = so[b*16384 + (2*oc+1)*64 + h];
  o[id] = v0*s0.x + s0.y + v1*s1.x + s1.y;
}

// ---------------- BN stats over [512][256][64] rows ----------------
__global__ __launch_bounds__(256) void k_bnstats(const float* __restrict__ src, const float* __restrict__ g,
                                                 const float* __restrict__ bta, float2* __restrict__ st){
  int ch = blockIdx.x, t = threadIdx.x;
  float s=0.f, s2=0.f;
  for (int e=t; e<512*64; e+=256){
    int r=e>>6, l=e&63;
    float v = src[(r*256+ch)*64 + l];
    s+=v; s2+=v*v;
  }
  __shared__ float rs[256], rq[256];
  rs[t]=s; rq[t]=s2; __syncthreads();
  for (int o=128;o>0;o>>=1){ if(t<o){ rs[t]+=rs[t+o]; rq[t]+=rq[t+o]; } __syncthreads(); }
  if (t==0){
    float m = rs[0]*(1.0f/32768.0f);
    float var = rq[0]*(1.0f/32768.0f) - m*m;
    float sc = g[ch]/sqrtf(var + EPSV);
    st[ch] = make_float2(sc, bta[ch] - m*sc);
  }
}

// ---------------- spatial block ----------------
__device__ __forceinline__ float xo_val(const float* __restrict__ o, int n, int c, int h, int w){
  if (c >= 40) return o[((n*128 + c)*64 + h)*64 + w];
  int grp = c / 10;
  int cc = c - grp*10;
  int base = (n*128 + cc)*64;
  if (grp==0) return (w>=2) ? o[(base + h)*64 + (w-2)] : 0.f;
  if (grp==1) return (w<62) ? o[(base + h)*64 + (w+2)] : 0.f;
  if (grp==2) return (h>=2) ? o[(base + (h-2))*64 + w] : 0.f;
  return (h<62) ? o[(base + (h+2))*64 + w] : 0.f;
}

__global__ __launch_bounds__(256) void k_instats(const float* __restrict__ o, const float* __restrict__ g,
                                                 const float* __restrict__ bta, float2* __restrict__ st){
  int nb = blockIdx.x; int n = nb>>7, c = nb&127;
  int t = threadIdx.x;
  float s=0.f,s2=0.f;
  for (int e=t;e<4096;e+=256){
    int h=e>>6, w=e&63;
    float v = xo_val(o,n,c,h,w);
    s+=v; s2+=v*v;
  }
  __shared__ float rs[256], rq[256];
  rs[t]=s; rq[t]=s2; __syncthreads();
  for (int oo=128;oo>0;oo>>=1){ if(t<oo){ rs[t]+=rs[t+oo]; rq[t]+=rq[t+oo]; } __syncthreads(); }
  if (t==0){
    float m = rs[0]*(1.0f/4096.0f);
    float var = rq[0]*(1.0f/4096.0f) - m*m;
    float sc = g[c]/sqrtf(var + EPSV);
    st[nb] = make_float2(sc, bta[c] - m*sc);
  }
}

__global__ void k_xn(const float* __restrict__ o, const float2* __restrict__ st, float* __restrict__ xn){
  int id = blockIdx.x*256+threadIdx.x;
  int w=id&63,h=(id>>6)&63,c=(id>>12)&127,n=id>>19;
  float2 sb = st[n*128+c];
  xn[id] = xo_val(o,n,c,h,w)*sb.x + sb.y;
}

// ---------------- xn fp32 [n][c][hw] -> xnT bf16 [n][hw][c] ----------------
__global__ __launch_bounds__(256) void k_xtr(const float* __restrict__ xn, u16* __restrict__ xnT){
  __shared__ float T[64][65];
  int hw0 = (blockIdx.x&63)*64, c0 = ((blockIdx.x>>6)&1)*64, n = blockIdx.x>>7;
  int tid = threadIdx.x;
  for (int e=tid;e<4096;e+=256){
    int cL = e>>6, hwL = e&63;
    T[cL][hwL] = xn[((size_t)(n*128 + c0+cL))*4096 + hw0 + hwL];
  }
  __syncthreads();
  for (int e=tid;e<4096;e+=256){
    int hwL = e>>6, cL = e&63;
    xnT[((size_t)(n*4096 + hw0+hwL))*128 + c0 + cL] = f2b(T[cL][hwL]);
  }
}

// ---------------- MFMA bf16 GEMM core: D[128 m][128 nn] per block, 4 waves (2x2 of 64x64) ----
__global__ __launch_bounds__(256) void k_mlp1(const u16* __restrict__ xnT, const u16* __restrict__ w1b,
                                              u16* __restrict__ h1T){
  int hw0 = blockIdx.x*128, co0 = blockIdx.y*128, n = blockIdx.z;
  int tid = threadIdx.x;
  int wv = tid>>6, l = tid&63;
  int wm = (wv>>1)*64, wn = (wv&1)*64;
  int lr = l&15, lq = l>>4;
  __shared__ u16 As[128*40];
  __shared__ u16 Bs[128*40];
  f32x4 acc[4][4];
  #pragma unroll
  for (int mi=0;mi<4;++mi)
    #pragma unroll
    for (int ni=0;ni<4;++ni) acc[mi][ni] = (f32x4){0.f,0.f,0.f,0.f};
  const u16* Ag = xnT + ((size_t)(n*4096 + hw0))*128;
  const u16* Bg = w1b + (size_t)co0*128;
  for (int ks=0; ks<128; ks+=32){
    __syncthreads();
    #pragma unroll
    for (int p=0;p<2;++p){
      int e = tid + p*256; int row = e>>2, q = e&3;
      *(uint4*)&As[row*40 + q*8] = *(const uint4*)&Ag[(size_t)row*128 + ks + q*8];
      *(uint4*)&Bs[row*40 + q*8] = *(const uint4*)&Bg[(size_t)row*128 + ks + q*8];
    }
    __syncthreads();
    bf16x8 af[4], bfr[4];
    #pragma unroll
    for (int mi=0;mi<4;++mi) af[mi] = *(const bf16x8*)&As[(wm + mi*16 + lr)*40 + lq*8];
    #pragma unroll
    for (int ni=0;ni<4;++ni) bfr[ni] = *(const bf16x8*)&Bs[(wn + ni*16 + lr)*40 + lq*8];
    #pragma unroll
    for (int mi=0;mi<4;++mi)
      #pragma unroll
      for (int ni=0;ni<4;++ni)
        acc[mi][ni] = __builtin_amdgcn_mfma_f32_16x16x32_bf16(af[mi], bfr[ni], acc[mi][ni], 0,0,0);
  }
  u16* ob = h1T + ((size_t)(n*4096 + hw0 + wm))*512 + co0 + wn;
  #pragma unroll
  for (int mi=0;mi<4;++mi)
    #pragma unroll
    for (int r=0;r<4;++r){
      int row = mi*16 + lq*4 + r;
      #pragma unroll
      for (int ni=0;ni<4;++ni){
        float v = acc[mi][ni][r];
        v = 0.5f*v*(1.0f + erff(v*0.70710678f));
        ob[(size_t)row*512 + ni*16 + lr] = f2b(v);
      }
    }
}

__global__ __launch_bounds__(256) void k_mlp2(const u16* __restrict__ w2b, const u16* __restrict__ h1T,
                                              float* __restrict__ out){
  int hw0 = blockIdx.x*128, n = blockIdx.z;
  int tid = threadIdx.x;
  int wv = tid>>6, l = tid&63;
  int wm = (wv>>1)*64, wn = (wv&1)*64;
  int lr = l&15, lq = l>>4;
  __shared__ u16 As[128*40];
  __shared__ u16 Bs[128*40];
  f32x4 acc[4][4];
  #pragma unroll
  for (int mi=0;mi<4;++mi)
    #pragma unroll
    for (int ni=0;ni<4;++ni) acc[mi][ni] = (f32x4){0.f,0.f,0.f,0.f};
  const u16* Ag = w2b;
  const u16* Bg = h1T + ((size_t)(n*4096 + hw0))*512;
  for (int ks=0; ks<512; ks+=32){
    __syncthreads();
    #pragma unroll
    for (int p=0;p<2;++p){
      int e = tid + p*256; int row = e>>2, q = e&3;
      *(uint4*)&As[row*40 + q*8] = *(const uint4*)&Ag[(size_t)row*512 + ks + q*8];
      *(uint4*)&Bs[row*40 + q*8] = *(const uint4*)&Bg[(size_t)row*512 + ks + q*8];
    }
    __syncthreads();
    bf16x8 af[4], bfr[4];
    #pragma unroll
    for (int mi=0;mi<4;++mi) af[mi] = *(const bf16x8*)&As[(wm + mi*16 + lr)*40 + lq*8];
    #pragma unroll
    for (int ni=0;ni<4;++ni) bfr[ni] = *(const bf16x8*)&Bs[(wn + ni*16 + lr)*40 + lq*8];
    #pragma unroll
    for (int mi=0;mi<4;++mi)
      #pragma unroll
      for (int ni=0;ni<4;++ni)
        acc[mi][ni] = __builtin_amdgcn_mfma_f32_16x16x32_bf16(af[mi], bfr[ni], acc[mi][ni], 0,0,0);
  }
  #pragma unroll
  for (int mi=0;mi<4;++mi)
    #pragma unroll
    for (int r=0;r<4;++r){
      int cout = wm + mi*16 + lq*4 + r;
      #pragma unroll
      for (int ni=0;ni<4;++ni){
        size_t idx = ((size_t)(n*128 + cout))*4096 + hw0 + wn + ni*16 + lr;
        out[idx] = acc[mi][ni][r] + out[idx];
      }
    }
}

extern "C" void kernel_launch(void* const* d_in, const int* in_sizes, int n_in,
                              void* d_out, int out_size, void* d_ws, size_t ws_size,
                              hipStream_t stream) {
  (void)in_sizes; (void)n_in; (void)out_size; (void)ws_size;
  const float* x       = (const float*)d_in[0];
  const float* qkvw    = (const float*)d_in[1];
  const float* bng     = (const float*)d_in[2];
  const float* bnb     = (const float*)d_in[3];
  const float* baserel = (const float*)d_in[4];
  const float* simg    = (const float*)d_in[5];
  const float* simb    = (const float*)d_in[6];
  const float* outg    = (const float*)d_in[7];
  const float* outb    = (const float*)d_in[8];
  const float* ing     = (const float*)d_in[9];
  const float* inb     = (const float*)d_in[10];
  const float* w1      = (const float*)d_in[11];
  const float* w2      = (const float*)d_in[12];

  float* ws = (float*)d_ws;
  float*  W127  = ws + F_W127;
  float*  W64   = ws + F_W64;
  float2* qkvst = (float2*)(ws + F_QKVST);
  float2* simst = (float2*)(ws + F_SIMST);
  float2* sost  = (float2*)(ws + F_SOST);
  float2* inst  = (float2*)(ws + F_INST);
  float*  postmp= ws + F_POSTMP;
  float*  pos   = ws + F_POS;
  float*  qkvT  = ws + F_QKV;
  float*  qkvrT = ws + F_QKVR;
  float*  sim   = ws + F_SIM;
  float*  part6 = ws + F_PART6;
  float*  veLT  = ws + F_VEH;
  u16*    xnT   = (u16*)(ws + F_XNT);
  float*  keT   = ws + F_KET;
  float*  so    = ws + F_SO;
  float*  xp    = ws + F_XP;
  float2* bnp   = (float2*)(ws + F_BNP);
  float*  xn    = ws + F_XN;
  u16*    h1T   = (u16*)(ws + F_H1);
  float*  wT    = ws + F_WT;
  u16*    w1b   = (u16*)(ws + F_W1B);
  u16*    w2b   = (u16*)(ws + F_W2B);
  float*  out   = (float*)d_out;

  k_tables  <<<dim3(1),        dim3(128), 0, stream>>>(W127, W64);
  k_tr      <<<dim3(8,4),      dim3(256), 0, stream>>>(qkvw, wT, 256, 128);
  k_xt      <<<dim3(1024),     dim3(256), 0, stream>>>(x, xp);
  k_qkv     <<<dim3(512,4),    dim3(256), 0, stream>>>(xp, wT, qkvT);
  k_bnsum   <<<dim3(4,256),    dim3(256), 0, stream>>>(qkvT, bnp);
  k_stats2  <<<dim3(8),        dim3(256), 0, stream>>>(bnp, bng, bnb, qkvst);
  k_qkvr    <<<dim3(512),      dim3(256), 0, stream>>>(qkvT, W64, qkvst, qkvrT);
  k_pos1    <<<dim3(524),      dim3(256), 0, stream>>>(baserel, W127, postmp);
  k_pos2    <<<dim3(137),      dim3(256), 0, stream>>>(postmp, W127, pos);
  k_keT     <<<dim3(35),       dim3(256), 0, stream>>>(pos, keT);
  k_cvtb    <<<dim3(256),      dim3(256), 0, stream>>>(w1, w1b, 65536);
  k_cvtb    <<<dim3(256),      dim3(256), 0, stream>>>(w2, w2b, 65536);
  k_sim     <<<dim3(512,8),    dim3(256), 0, stream>>>(qkvrT, pos, keT, sim, part6);
  k_sstB    <<<dim3(1),        dim3(192), 0, stream>>>(part6, simg, simb, simst);
  k_veL     <<<dim3(132),      dim3(256), 0, stream>>>(pos, veLT);
  k_attn    <<<dim3(1024),     dim3(256), 0, stream>>>(sim, simst, qkvrT, veLT, so);
  k_bnstats <<<dim3(256),      dim3(256), 0, stream>>>(so, outg, outb, sost);
  k_o       <<<dim3(16384),    dim3(256), 0, stream>>>(so, sost, out);
  k_instats <<<dim3(1024),     dim3(256), 0, stream>>>(out, ing, inb, inst);
  k_xn      <<<dim3(16384),    dim3(256), 0, stream>>>(out, inst, xn);
  k_xtr     <<<dim3(1024),     dim3(256), 0, stream>>>(xn, xnT);
  k_mlp1    <<<dim3(32,4,8),   dim3(256), 0, stream>>>(xnT, w1b, h1T);
  k_mlp2    <<<dim3(32,1,8),   dim3(256), 0, stream>>>(w2b, h1T, out);
}

// Round 12
// 415.357 us; speedup vs baseline: 2.7043x; 1.0902x over previous
//
#include <hip/hip_runtime.h>
#include <math.h>

// Problem constants: N=8, C=128, H=64, W=64, B=N*W=512, ADJ=33, G=8, GP=16
constexpr float EPSV = 1e-5f;
typedef unsigned short u16;
using bf16x8 = __attribute__((ext_vector_type(8))) short;
using f32x4  = __attribute__((ext_vector_type(4))) float;

// ---------------- workspace layout (offsets in floats) ----------------
constexpr size_t F_W127  = 0;
constexpr size_t F_W64   = F_W127 + 4224;
constexpr size_t F_QKVST = F_W64  + 2112;
constexpr size_t F_SIMST = F_QKVST+ 512;
constexpr size_t F_SOST  = F_SIMST+ 384;
constexpr size_t F_INST  = F_SOST + 512;
constexpr size_t F_POSTMP= F_INST + 2048;          // 134112 (alias: w1b/w2b after pos2)
constexpr size_t F_POS   = F_POSTMP + 134112;      // 34848 (alias: wT before pos2)
constexpr size_t F_QKV   = F_POS  + 34848;         // qkvT [512][64][256] = 8388608 (alias: SO)
constexpr size_t F_QKVR  = F_QKV  + 8388608;       // qkvrT [512][33][256] = 4325376
constexpr size_t F_SIM   = F_QKVR + 4325376;       // 13381632 (alias: XP early, BNP)
constexpr size_t F_PART6 = F_SIM  + 13381632;      // 24576 (alias: so-stats partials after k_sstB)
constexpr size_t F_VEH   = F_PART6 + 4460544;      // VeLT 33792
constexpr size_t F_XNT   = F_VEH  + 33792;         // xnT bf16 = 2097152 f
constexpr size_t F_KET   = F_XNT  + 2097152;       // keT 8712
constexpr size_t F_SO    = F_QKV;
constexpr size_t F_XP    = F_SIM;
constexpr size_t F_BNP   = F_SIM;
constexpr size_t F_H1    = F_SIM + 4194304;        // h1T bf16 = 8388608 f
constexpr size_t F_WT    = F_POS;
constexpr size_t F_W1B   = F_POSTMP;               // 32768 floats
constexpr size_t F_W2B   = F_POSTMP + 32768;       // 32768 floats

__device__ __forceinline__ void fma4(float4& a, const float4& h, float s){
  a.x += h.x*s; a.y += h.y*s; a.z += h.z*s; a.w += h.w*s;
}
__device__ __forceinline__ u16 f2b(float x){      // fp32 -> bf16 RNE
  unsigned u = __float_as_uint(x);
  return (u16)((u + 0x7FFFu + ((u>>16)&1u)) >> 16);
}

// ---- compile-time 33->64 upsample tables ----
struct UpT { int j0[64]; float fj[64]; };
constexpr UpT mkUp(){
  UpT t{};
  for (int o=0;o<64;++o){
    float x = ((float)o + 0.5f)*0.515625f - 0.5f;
    if (x < 0.f) x = 0.f;
    if (x > 32.f) x = 32.f;
    int j = (int)x; if (j > 31) j = 31;
    t.j0[o] = j; t.fj[o] = x - (float)j;
  }
  return t;
}
constexpr UpT UT = mkUp();

__device__ __forceinline__ void upfac(int o, int& j0, float& f){
  float x = ((float)o + 0.5f)*0.515625f - 0.5f;
  x = fminf(fmaxf(x, 0.f), 32.f);
  int j = (int)x; j = j < 31 ? j : 31;
  j0 = j; f = x - (float)j;
}

// ---------------- resize weight tables ----------------
__global__ void k_tables(float* __restrict__ W127, float* __restrict__ W64){
  int i = threadIdx.x;
  if (i < 33){
    const float inv = 127.0f/33.0f;
    float x = ((float)i + 0.5f)*inv - 0.5f;
    float s = 0.f;
    for (int j=0;j<127;++j){ float w = 1.0f - fabsf((float)j - x)/inv; w = fmaxf(w,0.f); W127[i*127+j]=w; s+=w; }
    float r = 1.0f/s;
    for (int j=0;j<127;++j) W127[i*127+j] *= r;
  } else if (i < 66){
    int ii = i-33;
    const float inv = 64.0f/33.0f;
    float x = ((float)ii + 0.5f)*inv - 0.5f;
    float s=0.f;
    for (int j=0;j<64;++j){ float w = 1.0f - fabsf((float)j - x)/inv; w=fmaxf(w,0.f); W64[ii*64+j]=w; s+=w; }
    float r=1.0f/s;
    for (int j=0;j<64;++j) W64[ii*64+j]*=r;
  }
}

// ---------------- generic 32x32-tiled transpose ----------------
__global__ __launch_bounds__(256) void k_tr(const float* __restrict__ src, float* __restrict__ dst,
                                            int R, int C){
  __shared__ float T[32][33];
  int r0 = blockIdx.x*32, c0 = blockIdx.y*32;
  int tx = threadIdx.x&31, ty = threadIdx.x>>5;
  #pragma unroll
  for (int q=0;q<4;++q){ int r = ty + q*8; T[r][tx] = src[(r0+r)*C + c0+tx]; }
  __syncthreads();
  #pragma unroll
  for (int q=0;q<4;++q){ int c = ty + q*8; dst[(c0+c)*R + r0+tx] = T[tx][c]; }
}

// ---------------- fp32 -> bf16 elementwise convert ----------------
__global__ void k_cvtb(const float* __restrict__ src, u16* __restrict__ dst, int n){
  int id = blockIdx.x*256 + threadIdx.x;
  if (id < n) dst[id] = f2b(src[id]);
}

// ---------------- x (N,C,H,W) -> xp (N*W, C, H) ----------------
__global__ __launch_bounds__(256) void k_xt(const float* __restrict__ x, float* __restrict__ xp){
  __shared__ float T[64][65];
  int n = blockIdx.x>>7, c = blockIdx.x&127;
  const float* src = x + ((size_t)(n*128 + c))*4096;
  int tid = threadIdx.x;
  for (int e=tid;e<4096;e+=256){ int h=e>>6, w=e&63; T[h][w] = src[e]; }
  __syncthreads();
  for (int e=tid;e<4096;e+=256){
    int w=e>>6, h=e&63;
    xp[((size_t)((n*64+w)*128 + c))*64 + h] = T[h][w];
  }
}

// ---------------- QKV projection GEMM -> qkvT[b][l][o] ----------------
__global__ __launch_bounds__(256) void k_qkv(const float* __restrict__ xp, const float* __restrict__ wT,
                                             float* __restrict__ qkvT){
  int b = blockIdx.x, o0 = blockIdx.y*64;
  int tid = threadIdx.x;
  int ot = tid&15, lt = tid>>4;
  __shared__ float4 LX[32][16];
  __shared__ float4 LW[32][16];
  const float4* xp4 = (const float4*)xp;
  const float4* wT4 = (const float4*)wT;
  float4 acc[4];
  #pragma unroll
  for (int j=0;j<4;++j) acc[j] = make_float4(0.f,0.f,0.f,0.f);
  for (int c0=0;c0<128;c0+=32){
    __syncthreads();
    #pragma unroll
    for (int p=0;p<2;++p){
      int e = tid + p*256; int kk=e>>4, q=e&15;
      LX[kk][q] = xp4[(size_t)b*2048 + (c0+kk)*16 + q];
      LW[kk][q] = wT4[(c0+kk)*64 + (o0>>2) + q];
    }
    __syncthreads();
    #pragma unroll
    for (int kk=0;kk<32;++kk){
      float4 x4 = LX[kk][lt];
      float4 w4 = LW[kk][ot];
      fma4(acc[0], w4, x4.x); fma4(acc[1], w4, x4.y);
      fma4(acc[2], w4, x4.z); fma4(acc[3], w4, x4.w);
    }
  }
  float4* qkvT4 = (float4*)qkvT;
  #pragma unroll
  for (int j=0;j<4;++j)
    qkvT4[((size_t)b*16384 + (lt*4+j)*256 + o0 + ot*4)>>2] = acc[j];
}

// ---------------- BN partial sums over rows of qkvT: grid (4 chG, 256 rowG) ----------------
__global__ __launch_bounds__(256) void k_bnsum(const float* __restrict__ qkvT, float2* __restrict__ part){
  int chG = blockIdx.x, rowG = blockIdx.y;
  int cl = threadIdx.x&63;
  int ch = chG*64 + cl;
  int rs = threadIdx.x>>6;
  float s=0.f, s2=0.f;
  for (int r = rowG*128 + rs; r < rowG*128 + 128; r += 4){
    float v = qkvT[(size_t)r*256 + ch]; s+=v; s2+=v*v;
  }
  __shared__ float S1[4][64], S2[4][64];
  S1[rs][cl]=s; S2[rs][cl]=s2; __syncthreads();
  if (rs==0){
    s  = S1[0][cl]+S1[1][cl]+S1[2][cl]+S1[3][cl];
    s2 = S2[0][cl]+S2[1][cl]+S2[2][cl]+S2[3][cl];
    part[(size_t)ch*256 + rowG] = make_float2(s, s2);
  }
}
__global__ void k_stats2(const float2* __restrict__ part, const float* __restrict__ g,
                         const float* __restrict__ bta, float2* __restrict__ st){
  int t = threadIdx.x;
  int chL = t>>3, seg = t&7;
  int ch = blockIdx.x*32 + chL;
  float s=0.f, s2=0.f;
  const float2* p = part + (size_t)ch*256 + seg*32;
  #pragma unroll 8
  for (int r=0;r<32;++r){ float2 q = p[r]; s+=q.x; s2+=q.y; }
  __shared__ float A[32][9], Bq[32][9];
  A[chL][seg]=s; Bq[chL][seg]=s2; __syncthreads();
  if (seg==0){
    #pragma unroll
    for (int k=1;k<8;++k){ s += A[chL][k]; s2 += Bq[chL][k]; }
    float m = s*(1.0f/32768.0f);
    float var = s2*(1.0f/32768.0f) - m*m;
    float sc = g[ch]/sqrtf(var + EPSV);
    st[ch] = make_float2(sc, bta[ch] - m*sc);
  }
}

// ---------------- qkvr: BN fold + resize 64->33 ----------------
__global__ __launch_bounds__(256) void k_qkvr(const float* __restrict__ qkvT, const float* __restrict__ W64,
                                              const float2* __restrict__ st, float* __restrict__ qkvrT){
  int b = blockIdx.x, ch = threadIdx.x;
  const float* base = qkvT + (size_t)b*16384 + ch;
  float xr[64];
  #pragma unroll
  for (int t=0;t<64;++t) xr[t] = base[t*256];
  float2 sb = st[ch];
  float* ob = qkvrT + (size_t)b*8448 + ch;
  for (int i=0;i<33;++i){
    const float4* wr = (const float4*)(W64 + i*64);
    float a = 0.f;
    #pragma unroll
    for (int q=0;q<16;++q){
      float4 w4 = wr[q];
      a += w4.x*xr[4*q] + w4.y*xr[4*q+1] + w4.z*xr[4*q+2] + w4.w*xr[4*q+3];
    }
    ob[i*256] = a*sb.x + sb.y;
  }
}

// ---------------- pos = resize(base_relative, (32,33,33)) separable ----------------
__global__ void k_pos1(const float* __restrict__ base, const float* __restrict__ W127, float* __restrict__ tmp){
  int id = blockIdx.x*256 + threadIdx.x;
  if (id >= 32*33*127) return;
  int c = id / 4191; int r = id - c*4191; int i = r / 127; int xx = r - i*127;
  const float* wr = W127 + i*127;
  const float* bc = base + c*16129 + xx;
  float a=0.f;
  for (int y=0;y<127;++y) a += wr[y]*bc[y*127];
  tmp[id] = a;
}
__global__ void k_pos2(const float* __restrict__ tmp, const float* __restrict__ W127, float* __restrict__ pos){
  int id = blockIdx.x*256 + threadIdx.x;
  if (id >= 32*33*33) return;
  int c = id / 1089; int r = id - c*1089; int i = r / 33; int j = r - i*33;
  const float* wr = W127 + j*127;
  const float* tc = tmp + c*4191 + i*127;
  float a=0.f;
  for (int xx=0;xx<127;++xx) a += wr[xx]*tc[xx];
  pos[id] = a;
}

// ---------------- keT[c][i][j] = k_e[c][j][i] ----------------
__global__ void k_keT(const float* __restrict__ pos, float* __restrict__ keT){
  int id = blockIdx.x*256 + threadIdx.x;
  if (id >= 8712) return;
  int c = id / 1089; int r = id - c*1089; int i = r / 33; int j = r - i*33;
  keT[id] = pos[(8+c)*1089 + j*33 + i];
}

// ---------------- sim = concat([qk, qr, kr]) + per-block stats partials ----------------
__global__ __launch_bounds__(256) void k_sim(const float* __restrict__ qkvrT, const float* __restrict__ pos,
                                             const float* __restrict__ keT,
                                             float* __restrict__ sim, float* __restrict__ part6){
  int b = blockIdx.x, g = blockIdx.y;
  __shared__ float lqa[264], lka[264];
  int tid = threadIdx.x;
  for (int e=tid;e<528;e+=256){
    int half = (e < 264) ? 0 : 1;
    int e2 = e - half*264;
    int c = e2/33, i = e2 - c*33;
    float v = qkvrT[(size_t)b*8448 + i*256 + (g*32 + half*8 + c)];
    if (half==0) lqa[e2]=v; else lka[e2]=v;
  }
  __syncthreads();
  float sqk=0.f,qqk=0.f,sqr=0.f,qqr=0.f,skr=0.f,qkr=0.f;
  for (int p=tid;p<1089;p+=256){
    int i = p/33, j = p - i*33;
    float qk=0.f, qr=0.f, kr=0.f;
    #pragma unroll
    for (int c=0;c<8;++c){
      float qa_ = lqa[c*33+i];
      float ka_ = lka[c*33+j];
      qk += qa_*ka_;
      qr += qa_*pos[c*1089 + i*33 + j];
      kr += ka_*keT[c*1089 + i*33 + j];
    }
    sim[(b*24 + g)*1089 + p] = qk;
    sim[(b*24 + 8 + g)*1089 + p] = qr;
    sim[(b*24 + 16 + g)*1089 + p] = kr;
    sqk+=qk; qqk+=qk*qk; sqr+=qr; qqr+=qr*qr; skr+=kr; qkr+=kr*kr;
  }
  __shared__ float red[6][256];
  red[0][tid]=sqk; red[1][tid]=qqk; red[2][tid]=sqr;
  red[3][tid]=qqr; red[4][tid]=skr; red[5][tid]=qkr;
  __syncthreads();
  for (int o=128;o>0;o>>=1){
    if (tid<o){
      #pragma unroll
      for (int c=0;c<6;++c) red[c][tid]+=red[c][tid+o];
    }
    __syncthreads();
  }
  if (tid<6) part6[(size_t)(b*8+g)*6 + tid] = red[tid][0];
}

// ---------------- simst from part6 ----------------
__global__ void k_sstB(const float* __restrict__ part6, const float* __restrict__ g,
                       const float* __restrict__ bta, float2* __restrict__ st){
  int nb = threadIdx.x;
  if (nb >= 192) return;
  int n = nb/24, ch = nb - n*24;
  int t3 = ch>>3, gg = ch&7;
  float s=0.f, s2=0.f;
  for (int w=0; w<64; ++w){
    const float* p = part6 + (size_t)((n*64+w)*8 + gg)*6 + 2*t3;
    s += p[0]; s2 += p[1];
  }
  float m = s*(1.0f/69696.0f);
  float var = s2*(1.0f/69696.0f) - m*m;
  float sc = g[ch]/sqrtf(var + EPSV);
  st[nb] = make_float2(sc, bta[ch] - m*sc);
}

// ---------------- VeLT[c][j33][i] ----------------
__global__ void k_veL(const float* __restrict__ pos, float* __restrict__ VeLT){
  int id = blockIdx.x*256 + threadIdx.x;
  if (id >= 33792) return;
  int i = id&63; int r = id>>6; int c = r/33; int j = r - c*33;
  int i0; float fi; upfac(i, i0, fi);
  const float* P = pos + (16+c)*1089;
  VeLT[id] = (1.f-fi)*P[i0*33 + j] + fi*P[(i0+1)*33 + j];
}

// ---------------- fused attention: 2 waves per (b,g) (channel halves), 2 bg per block ----------------
__global__ __launch_bounds__(256) void k_attn(const float* __restrict__ sim, const float2* __restrict__ simst,
                                              const float* __restrict__ qkvrT, const float* __restrict__ VeLT,
                                              float* __restrict__ so){
  int tid = threadIdx.x;
  int wv = tid >> 6;
  int i  = tid & 63;
  int pr = wv >> 1;          // bg pair slot within block
  int chh = wv & 1;          // channel half (c 0-7 / 8-15)
  int bg = blockIdx.x*2 + pr;
  int b = bg>>3, g = bg&7;
  int n = b>>6;
  __shared__ float  S[2][1092];
  __shared__ float4 Va[2][136];
  float* Sw = S[pr];
  float2 sb0 = simst[n*24 + g], sb1 = simst[n*24 + 8 + g], sb2 = simst[n*24 + 16 + g];
  float badd = sb0.y + sb1.y + sb2.y;
  const float* s0 = sim + ((size_t)b*24 + g)*1089;
  int tl = (chh<<6) | i;     // 0..127 within the bg pair-group
  for (int e=tl;e<1089;e+=128)
    Sw[e] = s0[e]*sb0.x + s0[e+8712]*sb1.x + s0[e+17424]*sb2.x + badd;
  for (int e=tl;e<132;e+=128){
    int j = e>>2, cq = e&3;
    Va[pr][e] = *(const float4*)(qkvrT + (size_t)b*8448 + j*256 + g*32 + 16 + cq*4);
  }
  __syncthreads();

  // phase A: exp of the bilinear-upsampled row (duplicated within the pair)
  int i0; float fi; upfac(i, i0, fi);
  const float* R0 = Sw + i0*33;
  const float* R1 = R0 + 33;
  float p[64];
  float s = 0.f;
  #pragma unroll
  for (int j=0;j<64;++j){
    float fj = UT.fj[j]; int j0 = UT.j0[j];
    float v0 = (1.f-fj)*R0[j0] + fj*R0[j0+1];
    float v1 = (1.f-fj)*R1[j0] + fj*R1[j0+1];
    float e = expf((1.f-fi)*v0 + fi*v1);
    p[j] = e; s += e;
  }
  float inv = 1.f/s;

  // phase B: fold + contractions for this wave's 8 channels
  float av[8], ae[8];
  #pragma unroll
  for (int c=0;c<8;++c){ av[c]=0.f; ae[c]=0.f; }
  const float* veb = VeLT + (size_t)(chh*8)*2112;
  #pragma unroll
  for (int k=0;k<33;++k){
    float qk = 0.f;
    #pragma unroll
    for (int j=0;j<64;++j){
      if (UT.j0[j] == k)        qk += p[j]*(1.f-UT.fj[j]);
      else if (UT.j0[j] == k-1) qk += p[j]*UT.fj[j];
    }
    float4 a0 = Va[pr][k*4 + chh*2], a1 = Va[pr][k*4 + chh*2 + 1];
    av[0] += qk*a0.x; av[1] += qk*a0.y; av[2] += qk*a0.z; av[3] += qk*a0.w;
    av[4] += qk*a1.x; av[5] += qk*a1.y; av[6] += qk*a1.z; av[7] += qk*a1.w;
    const float* vr = veb + k*64 + i;
    #pragma unroll
    for (int c=0;c<8;++c) ae[c] += qk * vr[c*2112];
  }
  float* ob = so + (size_t)b*16384 + g*2048 + (chh*8)*128;
  #pragma unroll
  for (int c=0;c<8;++c) ob[c*128 + i]      = av[c]*inv;
  #pragma unroll
  for (int c=0;c<8;++c) ob[c*128 + 64 + i] = ae[c]*inv;
}

// ---------------- so BN stats, 2-stage ----------------
__global__ __launch_bounds__(256) void k_sost1(const float* __restrict__ so, float2* __restrict__ part){
  int ch = blockIdx.x, rowG = blockIdx.y;   // 256 x 8
  int tid = threadIdx.x;
  int rs = tid>>6, l = tid&63;
  float s=0.f, s2=0.f;
  for (int r = rowG*64 + rs; r < rowG*64 + 64; r += 4){
    float v = so[((size_t)r*256 + ch)*64 + l]; s+=v; s2+=v*v;
  }
  __shared__ float S1[256], S2[256];
  S1[tid]=s; S2[tid]=s2; __syncthreads();
  for (int o=128;o>0;o>>=1){ if(tid<o){ S1[tid]+=S1[tid+o]; S2[tid]+=S2[tid+o]; } __syncthreads(); }
  if (tid==0) part[ch*8 + rowG] = make_float2(S1[0], S2[0]);
}
__global__ void k_sost2(const float2* __restrict__ part, const float* __restrict__ g,
                        const float* __restrict__ bta, float2* __restrict__ st){
  int ch = threadIdx.x;   // 256
  float s=0.f, s2=0.f;
  #pragma unroll
  for (int r=0;r<8;++r){ float2 p = part[ch*8 + r]; s+=p.x; s2+=p.y; }
  float m = s*(1.0f/32768.0f);
  float var = s2*(1.0f/32768.0f) - m*m;
  float sc = g[ch]/sqrtf(var + EPSV);
  st[ch] = make_float2(sc, bta[ch] - m*sc);
}

// ---------------- BN(so) + pair-sum + transpose -> o ----------------
__global__ void k_o(const float* __restrict__ so, const float2* __restrict__ st, float* __restrict__ o){
  int id = blockIdx.x*256 + threadIdx.x;
  int w = id&63, h=(id>>6)&63, oc=(id>>12)&127, n=id>>19;
  int b = n*64 + w;
  float2 s0 = st[2*oc], s1 = st[2*oc+1];
  float v0 = so[b*16384 + (2*oc)*64 + h];
  float v1 = so[b*16384 + (2*oc+1)*64 + h];
  o[id] = v0*s0.x + s0.y + v1*s1.x + s1.y;
}

// ---------------- spatial block ----------------
__device__ __forceinline__ float xo_val(const float* __restrict__ o, int n, int c, int h, int w){
  if (c >= 40) return o[((n*128 + c)*64 + h)*64 + w];
  int grp = c / 10;
  int cc = c - grp*10;
  int base = (n*128 + cc)*64;
  if (grp==0) return (w>=2) ? o[(base + h)*64 + (w-2)] : 0.f;
  if (grp==1) return (w<62) ? o[(base + h)*64 + (w+2)] : 0.f;
  if (grp==2) return (h>=2) ? o[(base + (h-2))*64 + w] : 0.f;
  return (h<62) ? o[(base + (h+2))*64 + w] : 0.f;
}

__global__ __launch_bounds__(256) void k_instats(const float* __restrict__ o, const float* __restrict__ g,
                                                 const float* __restrict__ bta, float2* __restrict__ st){
  int nb = blockIdx.x; int n = nb>>7, c = nb&127;
  int t = threadIdx.x;
  float s=0.f,s2=0.f;
  for (int e=t;e<4096;e+=256){
    int h=e>>6, w=e&63;
    float v = xo_val(o,n,c,h,w);
    s+=v; s2+=v*v;
  }
  __shared__ float rs[256], rq[256];
  rs[t]=s; rq[t]=s2; __syncthreads();
  for (int oo=128;oo>0;oo>>=1){ if(t<oo){ rs[t]+=rs[t+oo]; rq[t]+=rq[t+oo]; } __syncthreads(); }
  if (t==0){
    float m = rs[0]*(1.0f/4096.0f);
    float var = rq[0]*(1.0f/4096.0f) - m*m;
    float sc = g[c]/sqrtf(var + EPSV);
    st[nb] = make_float2(sc, bta[c] - m*sc);
  }
}

// ---------------- fused: instance-norm(xo) + transpose -> xnT bf16 [n][hw][c] ----------------
// replaces k_xn + k_xtr (xn was consumed only by the transpose)
__global__ __launch_bounds__(256) void k_xnt(const float* __restrict__ o, const float2* __restrict__ st,
                                             u16* __restrict__ xnT){
  __shared__ float T[64][65];
  int h = blockIdx.x&63, c0 = ((blockIdx.x>>6)&1)*64, n = blockIdx.x>>7;
  int tid = threadIdx.x;
  for (int e=tid;e<4096;e+=256){
    int cL = e>>6, w = e&63;                 // lanes along w: coalesced xo_val reads
    float2 sb = st[n*128 + c0+cL];           // wave-uniform
    T[cL][w] = xo_val(o, n, c0+cL, h, w)*sb.x + sb.y;
  }
  __syncthreads();
  for (int e=tid;e<4096;e+=256){
    int wL = e>>6, cL = e&63;                // lanes along c: 128B contiguous stores
    xnT[((size_t)(n*4096 + h*64 + wL))*128 + c0 + cL] = f2b(T[cL][wL]);
  }
}

// ---------------- MFMA bf16 GEMM core: D[128 m][128 nn] per block, 4 waves (2x2 of 64x64) ----
__global__ __launch_bounds__(256) void k_mlp1(const u16* __restrict__ xnT, const u16* __restrict__ w1b,
                                              u16* __restrict__ h1T){
  int hw0 = blockIdx.x*128, co0 = blockIdx.y*128, n = blockIdx.z;
  int tid = threadIdx.x;
  int wv = tid>>6, l = tid&63;
  int wm = (wv>>1)*64, wn = (wv&1)*64;
  int lr = l&15, lq = l>>4;
  __shared__ u16 As[128*40];
  __shared__ u16 Bs[128*40];
  f32x4 acc[4][4];
  #pragma unroll
  for (int mi=0;mi<4;++mi)
    #pragma unroll
    for (int ni=0;ni<4;++ni) acc[mi][ni] = (f32x4){0.f,0.f,0.f,0.f};
  const u16* Ag = xnT + ((size_t)(n*4096 + hw0))*128;
  const u16* Bg = w1b + (size_t)co0*128;
  for (int ks=0; ks<128; ks+=32){
    __syncthreads();
    #pragma unroll
    for (int p=0;p<2;++p){
      int e = tid + p*256; int row = e>>2, q = e&3;
      *(uint4*)&As[row*40 + q*8] = *(const uint4*)&Ag[(size_t)row*128 + ks + q*8];
      *(uint4*)&Bs[row*40 + q*8] = *(const uint4*)&Bg[(size_t)row*128 + ks + q*8];
    }
    __syncthreads();
    bf16x8 af[4], bfr[4];
    #pragma unroll
    for (int mi=0;mi<4;++mi) af[mi] = *(const bf16x8*)&As[(wm + mi*16 + lr)*40 + lq*8];
    #pragma unroll
    for (int ni=0;ni<4;++ni) bfr[ni] = *(const bf16x8*)&Bs[(wn + ni*16 + lr)*40 + lq*8];
    #pragma unroll
    for (int mi=0;mi<4;++mi)
      #pragma unroll
      for (int ni=0;ni<4;++ni)
        acc[mi][ni] = __builtin_amdgcn_mfma_f32_16x16x32_bf16(af[mi], bfr[ni], acc[mi][ni], 0,0,0);
  }
  u16* ob = h1T + ((size_t)(n*4096 + hw0 + wm))*512 + co0 + wn;
  #pragma unroll
  for (int mi=0;mi<4;++mi)
    #pragma unroll
    for (int r=0;r<4;++r){
      int row = mi*16 + lq*4 + r;
      #pragma unroll
      for (int ni=0;ni<4;++ni){
        float v = acc[mi][ni][r];
        v = 0.5f*v*(1.0f + erff(v*0.70710678f));
        ob[(size_t)row*512 + ni*16 + lr] = f2b(v);
      }
    }
}

__global__ __launch_bounds__(256) void k_mlp2(const u16* __restrict__ w2b, const u16* __restrict__ h1T,
                                              float* __restrict__ out){
  int hw0 = blockIdx.x*128, n = blockIdx.z;
  int tid = threadIdx.x;
  int wv = tid>>6, l = tid&63;
  int wm = (wv>>1)*64, wn = (wv&1)*64;
  int lr = l&15, lq = l>>4;
  __shared__ u16 As[128*40];
  __shared__ u16 Bs[128*40];
  f32x4 acc[4][4];
  #pragma unroll
  for (int mi=0;mi<4;++mi)
    #pragma unroll
    for (int ni=0;ni<4;++ni) acc[mi][ni] = (f32x4){0.f,0.f,0.f,0.f};
  const u16* Ag = w2b;
  const u16* Bg = h1T + ((size_t)(n*4096 + hw0))*512;
  for (int ks=0; ks<512; ks+=32){
    __syncthreads();
    #pragma unroll
    for (int p=0;p<2;++p){
      int e = tid + p*256; int row = e>>2, q = e&3;
      *(uint4*)&As[row*40 + q*8] = *(const uint4*)&Ag[(size_t)row*512 + ks + q*8];
      *(uint4*)&Bs[row*40 + q*8] = *(const uint4*)&Bg[(size_t)row*512 + ks + q*8];
    }
    __syncthreads();
    bf16x8 af[4], bfr[4];
    #pragma unroll
    for (int mi=0;mi<4;++mi) af[mi] = *(const bf16x8*)&As[(wm + mi*16 + lr)*40 + lq*8];
    #pragma unroll
    for (int ni=0;ni<4;++ni) bfr[ni] = *(const bf16x8*)&Bs[(wn + ni*16 + lr)*40 + lq*8];
    #pragma unroll
    for (int mi=0;mi<4;++mi)
      #pragma unroll
      for (int ni=0;ni<4;++ni)
        acc[mi][ni] = __builtin_amdgcn_mfma_f32_16x16x32_bf16(af[mi], bfr[ni], acc[mi][ni], 0,0,0);
  }
  #pragma unroll
  for (int mi=0;mi<4;++mi)
    #pragma unroll
    for (int r=0;r<4;++r){
      int cout = wm + mi*16 + lq*4 + r;
      #pragma unroll
      for (int ni=0;ni<4;++ni){
        size_t idx = ((size_t)(n*128 + cout))*4096 + hw0 + wn + ni*16 + lr;
        out[idx] = acc[mi][ni][r] + out[idx];
      }
    }
}

extern "C" void kernel_launch(void* const* d_in, const int* in_sizes, int n_in,
                              void* d_out, int out_size, void* d_ws, size_t ws_size,
                              hipStream_t stream) {
  (void)in_sizes; (void)n_in; (void)out_size; (void)ws_size;
  const float* x       = (const float*)d_in[0];
  const float* qkvw    = (const float*)d_in[1];
  const float* bng     = (const float*)d_in[2];
  const float* bnb     = (const float*)d_in[3];
  const float* baserel = (const float*)d_in[4];
  const float* simg    = (const float*)d_in[5];
  const float* simb    = (const float*)d_in[6];
  const float* outg    = (const float*)d_in[7];
  const float* outb    = (const float*)d_in[8];
  const float* ing     = (const float*)d_in[9];
  const float* inb     = (const float*)d_in[10];
  const float* w1      = (const float*)d_in[11];
  const float* w2      = (const float*)d_in[12];

  float* ws = (float*)d_ws;
  float*  W127  = ws + F_W127;
  float*  W64   = ws + F_W64;
  float2* qkvst = (float2*)(ws + F_QKVST);
  float2* simst = (float2*)(ws + F_SIMST);
  float2* sost  = (float2*)(ws + F_SOST);
  float2* inst  = (float2*)(ws + F_INST);
  float*  postmp= ws + F_POSTMP;
  float*  pos   = ws + F_POS;
  float*  qkvT  = ws + F_QKV;
  float*  qkvrT = ws + F_QKVR;
  float*  sim   = ws + F_SIM;
  float*  part6 = ws + F_PART6;
  float2* sopart= (float2*)(ws + F_PART6);   // reuse after k_sstB (part6 dead)
  float*  veLT  = ws + F_VEH;
  u16*    xnT   = (u16*)(ws + F_XNT);
  float*  keT   = ws + F_KET;
  float*  so    = ws + F_SO;
  float*  xp    = ws + F_XP;
  float2* bnp   = (float2*)(ws + F_BNP);
  u16*    h1T   = (u16*)(ws + F_H1);
  float*  wT    = ws + F_WT;
  u16*    w1b   = (u16*)(ws + F_W1B);
  u16*    w2b   = (u16*)(ws + F_W2B);
  float*  out   = (float*)d_out;

  k_tables  <<<dim3(1),        dim3(128), 0, stream>>>(W127, W64);
  k_tr      <<<dim3(8,4),      dim3(256), 0, stream>>>(qkvw, wT, 256, 128);
  k_xt      <<<dim3(1024),     dim3(256), 0, stream>>>(x, xp);
  k_qkv     <<<dim3(512,4),    dim3(256), 0, stream>>>(xp, wT, qkvT);
  k_bnsum   <<<dim3(4,256),    dim3(256), 0, stream>>>(qkvT, bnp);
  k_stats2  <<<dim3(8),        dim3(256), 0, stream>>>(bnp, bng, bnb, qkvst);
  k_qkvr    <<<dim3(512),      dim3(256), 0, stream>>>(qkvT, W64, qkvst, qkvrT);
  k_pos1    <<<dim3(524),      dim3(256), 0, stream>>>(baserel, W127, postmp);
  k_pos2    <<<dim3(137),      dim3(256), 0, stream>>>(postmp, W127, pos);
  k_keT     <<<dim3(35),       dim3(256), 0, stream>>>(pos, keT);
  k_cvtb    <<<dim3(256),      dim3(256), 0, stream>>>(w1, w1b, 65536);
  k_cvtb    <<<dim3(256),      dim3(256), 0, stream>>>(w2, w2b, 65536);
  k_sim     <<<dim3(512,8),    dim3(256), 0, stream>>>(qkvrT, pos, keT, sim, part6);
  k_sstB    <<<dim3(1),        dim3(192), 0, stream>>>(part6, simg, simb, simst);
  k_veL     <<<dim3(132),      dim3(256), 0, stream>>>(pos, veLT);
  k_attn    <<<dim3(2048),     dim3(256), 0, stream>>>(sim, simst, qkvrT, veLT, so);
  k_sost1   <<<dim3(256,8),    dim3(256), 0, stream>>>(so, sopart);
  k_sost2   <<<dim3(1),        dim3(256), 0, stream>>>(sopart, outg, outb, sost);
  k_o       <<<dim3(16384),    dim3(256), 0, stream>>>(so, sost, out);
  k_instats <<<dim3(1024),     dim3(256), 0, stream>>>(out, ing, inb, inst);
  k_xnt     <<<dim3(1024),     dim3(256), 0, stream>>>(out, inst, xnT);
  k_mlp1    <<<dim3(32,4,8),   dim3(256), 0, stream>>>(xnT, w1b, h1T);
  k_mlp2    <<<dim3(32,1,8),   dim3(256), 0, stream>>>(w2b, h1T, out);
}